// Round 2
// baseline (1307.151 us; speedup 1.0000x reference)
//
#include <hip/hip_runtime.h>
#include <cstdint>
#include <cstddef>

#define BATCH 8
#define SEQ   256
#define DIM   768
#define NSPAN 2020
#define HID   1024
#define NZ    64

typedef unsigned short u16;
typedef unsigned int   u32;

typedef __bf16 bf16x8 __attribute__((ext_vector_type(8)));
typedef float  f32x4  __attribute__((ext_vector_type(4)));

__device__ __forceinline__ u16 f2bf(float f) {
    union { float f; u32 u; } x; x.f = f;
    u32 r = x.u + 0x7fffu + ((x.u >> 16) & 1u);
    return (u16)(r >> 16);
}
__device__ __forceinline__ float bf2f(u16 b) {
    union { u32 u; float f; } x; x.u = ((u32)b) << 16;
    return x.f;
}

// span s -> (start, end, width); spans enumerated width-major: w=1..8, starts 0..L-w
__device__ __forceinline__ void span_decode(int s, int& start, int& end, int& w) {
    int off = 0;
#pragma unroll
    for (int wi = 1; wi <= 8; ++wi) {
        int cnt = SEQ - wi + 1;
        if (s < off + cnt) { w = wi; start = s - off; end = start + wi; return; }
        off += cnt;
    }
    w = 8; start = 0; end = 8;
}

// searchsorted(BUCKET_BINS, d, 'right') - 1
__device__ __forceinline__ int dbucket(int d) {
    int b = 0;
    b += (d >= 1);  b += (d >= 2);  b += (d >= 3);  b += (d >= 4);
    b += (d >= 5);  b += (d >= 7);  b += (d >= 8);  b += (d >= 15);
    b += (d >= 16); b += (d >= 31); b += (d >= 32); b += (d >= 63);
    b += (d >= 64);
    return b;
}

// ---------------------------------------------------------------------------
// Tiny per-bucket tables: width/dist embeddings only ever hit 14 rows.
// wtabS[w-1]  = width_emb[bucket(w)] @ Ws1[1536:1561] + bs1
// wtabPt[w-1] = width_emb[bucket(w)] @ Wp1[1536:1561]
// wtabPo[w-1] = width_emb[bucket(w)] @ Wp1[3097:3122]
// dtab[t]     = dist_emb[t] @ Wp1[3122:3147] + bp1
// ---------------------------------------------------------------------------
__global__ __launch_bounds__(256) void k_tables(
    const float* __restrict__ wemb, const float* __restrict__ demb,
    const float* __restrict__ Ws1, const float* __restrict__ bs1,
    const float* __restrict__ Wp1, const float* __restrict__ bp1,
    float* __restrict__ wtabS, float* __restrict__ wtabPt,
    float* __restrict__ wtabPo, float* __restrict__ dtab)
{
    int h = blockIdx.x * 256 + threadIdx.x;   // 0..1023
    int row = blockIdx.y;                     // 0..37
    const int wb[8] = {1,2,3,4,5,5,6,7};      // width 1..8 -> bucket
    if (row < 8) {
        int bk = wb[row];
        float acc = bs1[h];
        for (int j = 0; j < 25; ++j) acc = fmaf(wemb[bk*25+j], Ws1[(size_t)(1536+j)*HID + h], acc);
        wtabS[row*HID + h] = acc;
    } else if (row < 16) {
        int bk = wb[row-8];
        float acc = 0.f;
        for (int j = 0; j < 25; ++j) acc = fmaf(wemb[bk*25+j], Wp1[(size_t)(1536+j)*HID + h], acc);
        wtabPt[(row-8)*HID + h] = acc;
    } else if (row < 24) {
        int bk = wb[row-16];
        float acc = 0.f;
        for (int j = 0; j < 25; ++j) acc = fmaf(wemb[bk*25+j], Wp1[(size_t)(3097+j)*HID + h], acc);
        wtabPo[(row-16)*HID + h] = acc;
    } else {
        int t = row - 24;                     // 0..13
        float acc = bp1[h];
        for (int j = 0; j < 25; ++j) acc = fmaf(demb[t*25+j], Wp1[(size_t)(3122+j)*HID + h], acc);
        dtab[t*HID + h] = acc;
    }
}

// ---------------------------------------------------------------------------
// fp32 SIMT GEMM, 128x128 tile, BK=8, 256 threads, 8x8 per thread.
// C[M,N=128*gridDim.x] = A[M,K](lda) @ Bm[K, ...](ldb, col window via blockIdx.x)
// ---------------------------------------------------------------------------
__global__ __launch_bounds__(256) void k_sgemm128(
    const float* __restrict__ A, int lda,
    const float* __restrict__ Bm, int ldb,
    float* __restrict__ C, int ldc,
    int M, int K,
    const float* __restrict__ bias, int relu)
{
    __shared__ float As[8][132];
    __shared__ float Bs[8][132];
    const int tid = threadIdx.x;
    const int tx = tid & 15, ty = tid >> 4;
    const int bm = blockIdx.y * 128, bn = blockIdx.x * 128;

    float acc[8][8];
#pragma unroll
    for (int i = 0; i < 8; ++i)
#pragma unroll
        for (int j = 0; j < 8; ++j) acc[i][j] = 0.f;

    const int ar = tid >> 1, ak = (tid & 1) * 4;     // A tile 128x8
    const int br = tid >> 5, bc = (tid & 31) * 4;    // B tile 8x128
    const int garow = bm + ar;
    const bool aok = garow < M;
    const float* Aptr = A + (size_t)(aok ? garow : 0) * lda;

    for (int k0 = 0; k0 < K; k0 += 8) {
        float4 av = make_float4(0.f, 0.f, 0.f, 0.f);
        if (aok) av = *(const float4*)(Aptr + k0 + ak);
        As[ak+0][ar] = av.x; As[ak+1][ar] = av.y; As[ak+2][ar] = av.z; As[ak+3][ar] = av.w;
        float4 bv = *(const float4*)(Bm + (size_t)(k0 + br) * ldb + bn + bc);
        *(float4*)&Bs[br][bc] = bv;
        __syncthreads();
#pragma unroll
        for (int kk = 0; kk < 8; ++kk) {
            float a[8], b[8];
#pragma unroll
            for (int i = 0; i < 8; ++i) a[i] = As[kk][ty*8 + i];
#pragma unroll
            for (int j = 0; j < 8; ++j) b[j] = Bs[kk][tx*8 + j];
#pragma unroll
            for (int i = 0; i < 8; ++i)
#pragma unroll
                for (int j = 0; j < 8; ++j) acc[i][j] = fmaf(a[i], b[j], acc[i][j]);
        }
        __syncthreads();
    }
#pragma unroll
    for (int i = 0; i < 8; ++i) {
        int r = bm + ty*8 + i;
        if (r >= M) continue;
        float* crow = C + (size_t)r * ldc + bn + tx*8;
#pragma unroll
        for (int j0 = 0; j0 < 8; j0 += 4) {
            float4 v = make_float4(acc[i][j0], acc[i][j0+1], acc[i][j0+2], acc[i][j0+3]);
            if (bias) {
                const float* bp = bias + bn + tx*8 + j0;
                v.x += bp[0]; v.y += bp[1]; v.z += bp[2]; v.w += bp[3];
            }
            if (relu) {
                v.x = fmaxf(v.x, 0.f); v.y = fmaxf(v.y, 0.f);
                v.z = fmaxf(v.z, 0.f); v.w = fmaxf(v.w, 0.f);
            }
            *(float4*)(crow + j0) = v;
        }
    }
}

// ---------------------------------------------------------------------------
// fp32 SIMT GEMM, 64x64 tile, BK=8, 4x4/thread, with A-row gather (rowmap)
// and a second B pointer for rows >= o_row_start (T/O share one launch).
// ---------------------------------------------------------------------------
__global__ __launch_bounds__(256) void k_sgemm64(
    const float* __restrict__ A, int lda,
    const float* __restrict__ Bm, const float* __restrict__ BmO, int o_row_start, int ldb,
    float* __restrict__ C, int ldc,
    int M, int K, int accum,
    const int* __restrict__ rowmap)
{
    __shared__ float As[8][68];
    __shared__ float Bs[8][68];
    const int tid = threadIdx.x;
    const int tx = tid & 15, ty = tid >> 4;
    const int bm = blockIdx.y * 64, bn = blockIdx.x * 64;
    const float* Bp = (bm >= o_row_start) ? BmO : Bm;

    float acc[4][4];
#pragma unroll
    for (int i = 0; i < 4; ++i)
#pragma unroll
        for (int j = 0; j < 4; ++j) acc[i][j] = 0.f;

    const int ar = tid >> 2, ak = (tid & 3) * 2;     // A tile 64x8
    const int br = tid >> 5, bc = (tid & 31) * 2;    // B tile 8x64
    const int garow = bm + ar;
    const bool aok = garow < M;
    int aphys = 0;
    if (aok) aphys = rowmap ? rowmap[garow] : garow;
    const float* Aptr = A + (size_t)aphys * lda;

    for (int k0 = 0; k0 < K; k0 += 8) {
        float2 av = make_float2(0.f, 0.f);
        if (aok) av = *(const float2*)(Aptr + k0 + ak);
        As[ak][ar] = av.x; As[ak+1][ar] = av.y;
        float2 bv = *(const float2*)(Bp + (size_t)(k0 + br) * ldb + bn + bc);
        Bs[br][bc] = bv.x; Bs[br][bc+1] = bv.y;
        __syncthreads();
#pragma unroll
        for (int kk = 0; kk < 8; ++kk) {
            float a[4], b[4];
#pragma unroll
            for (int i = 0; i < 4; ++i) a[i] = As[kk][ty*4 + i];
#pragma unroll
            for (int j = 0; j < 4; ++j) b[j] = Bs[kk][tx*4 + j];
#pragma unroll
            for (int i = 0; i < 4; ++i)
#pragma unroll
                for (int j = 0; j < 4; ++j) acc[i][j] = fmaf(a[i], b[j], acc[i][j]);
        }
        __syncthreads();
    }
#pragma unroll
    for (int i = 0; i < 4; ++i) {
        int r = bm + ty*4 + i;
        if (r >= M) continue;
        float* crow = C + (size_t)r * ldc + bn + tx*4;
        float4 v = make_float4(acc[i][0], acc[i][1], acc[i][2], acc[i][3]);
        if (accum) {
            float4 o = *(const float4*)crow;
            v.x += o.x; v.y += o.y; v.z += o.z; v.w += o.w;
        }
        *(float4*)crow = v;
    }
}

// h1_span[r] = relu(XALL[b,start, 0:1024] + XALL[b,end-1, 1024:2048] + wtabS[w-1])
__global__ __launch_bounds__(256) void k_build_h1s(
    const float* __restrict__ XALL, const float* __restrict__ wtabS,
    float* __restrict__ h1s)
{
    int r = blockIdx.x;                 // 0..16159
    int b = r / NSPAN, s = r - b * NSPAN;
    int st, en, w; span_decode(s, st, en, w);
    const float4* xs = (const float4*)(XALL + (size_t)(b*SEQ + st) * 2048);
    const float4* xe = (const float4*)(XALL + (size_t)(b*SEQ + en - 1) * 2048 + 1024);
    const float4* wt = (const float4*)(wtabS + (size_t)(w-1) * HID);
    float4* dst = (float4*)(h1s + (size_t)r * HID);
    int t = threadIdx.x;
    float4 a = xs[t], bz = xe[t], c = wt[t], v;
    v.x = fmaxf(a.x + bz.x + c.x, 0.f);
    v.y = fmaxf(a.y + bz.y + c.y, 0.f);
    v.z = fmaxf(a.z + bz.z + c.z, 0.f);
    v.w = fmaxf(a.w + bz.w + c.w, 0.f);
    dst[t] = v;
}

// span layer3 + softmax -> out[r*3 + c]. One wave per row, 4 rows/block.
__global__ __launch_bounds__(256) void k_span_l3(
    const float* __restrict__ h2s, const float* __restrict__ Ws3,
    const float* __restrict__ bs3, float* __restrict__ out)
{
    int wave = threadIdx.x >> 6, lane = threadIdx.x & 63;
    int r = blockIdx.x * 4 + wave;      // 16160 = 4040*4 exact
    const float* hr = h2s + (size_t)r * HID;
    float s0 = 0.f, s1 = 0.f, s2 = 0.f;
    for (int h = lane; h < HID; h += 64) {
        float v = hr[h];
        const float* wrow = Ws3 + h * 3;
        s0 = fmaf(v, wrow[0], s0);
        s1 = fmaf(v, wrow[1], s1);
        s2 = fmaf(v, wrow[2], s2);
    }
#pragma unroll
    for (int off = 32; off > 0; off >>= 1) {
        s0 += __shfl_down(s0, off, 64);
        s1 += __shfl_down(s1, off, 64);
        s2 += __shfl_down(s2, off, 64);
    }
    if (lane == 0) {
        s0 += bs3[0]; s1 += bs3[1]; s2 += bs3[2];
        float m = fmaxf(s0, fmaxf(s1, s2));
        float e0 = expf(s0 - m), e1 = expf(s1 - m), e2 = expf(s2 - m);
        float inv = 1.f / (e0 + e1 + e2);
        float* o = out + (size_t)r * 3;
        o[0] = e0 * inv; o[1] = e1 * inv; o[2] = e2 * inv;
    }
}

// top-64 (descending, ties -> lower index) of span_prob[b,:,head]. 1 wave/block.
__global__ __launch_bounds__(64) void k_topk(
    const float* __restrict__ sp, int* __restrict__ t_idx, int* __restrict__ o_idx)
{
    int b = blockIdx.x >> 1;
    int head = 1 + (blockIdx.x & 1);
    int* outp = (head == 1 ? t_idx : o_idx) + b * NZ;
    __shared__ float sc[NSPAN];
    int lane = threadIdx.x;
    for (int s = lane; s < NSPAN; s += 64)
        sc[s] = sp[((size_t)b * NSPAN + s) * 3 + head];
    __syncthreads();
    for (int it = 0; it < NZ; ++it) {
        float bv = -1e30f; int bi = 0;
        for (int s = lane; s < NSPAN; s += 64) {
            float v = sc[s];
            if (v > bv || (v == bv && s < bi)) { bv = v; bi = s; }
        }
#pragma unroll
        for (int off = 32; off > 0; off >>= 1) {
            float ov = __shfl_down(bv, off, 64);
            int   oi = __shfl_down(bi, off, 64);
            if (ov > bv || (ov == bv && oi < bi)) { bv = ov; bi = oi; }
        }
        if (lane == 0) {
            if (bi < 0 || bi >= NSPAN) bi = 0;   // paranoia (NaN shield)
            outp[it] = bi; sc[bi] = -1e30f;
        }
        __syncthreads();
    }
}

// token rowmaps for the gathered T/O GEMMs.
// toks[r]       = x2d row of start-token, toks[1024+r] = row of (end-1)-token.
// rows 0..511: (b,i) over t_idx; rows 512..1023: (b,j) over o_idx.
__global__ void k_toks(const int* __restrict__ t_idx, const int* __restrict__ o_idx,
                       int* __restrict__ toks)
{
    int r = blockIdx.x * 256 + threadIdx.x;
    if (r >= 1024) return;
    int b, sidx;
    if (r < 512) { b = r >> 6; sidx = t_idx[r]; }
    else { int q = r - 512; b = q >> 6; sidx = o_idx[q]; }
    int st, en, w; span_decode(sidx, st, en, w);
    toks[r] = b * SEQ + st;
    toks[1024 + r] = b * SEQ + en - 1;
}

// h1_pair[row] = relu(T[b,i] + O[b,j] + wtabPt[wt-1] + wtabPo[wo-1] + dtab[db]) -> bf16
__global__ __launch_bounds__(256) void k_build_h1p(
    const float* __restrict__ TO, const int* __restrict__ t_idx, const int* __restrict__ o_idx,
    const float* __restrict__ wtabPt, const float* __restrict__ wtabPo,
    const float* __restrict__ dtab, u16* __restrict__ h1p)
{
    int row = blockIdx.x;               // b*4096 + i*64 + j
    int b = row >> 12, i = (row >> 6) & 63, j = row & 63;
    int ts = t_idx[b*64 + i], os = o_idx[b*64 + j];
    int ta, tb, wt, oc, od, wo;
    span_decode(ts, ta, tb, wt);
    span_decode(os, oc, od, wo);
    int d1 = tb - oc; d1 = d1 < 0 ? -d1 : d1;
    int d2 = ta - od; d2 = d2 < 0 ? -d2 : d2;
    int dist = d1 < d2 ? d1 : d2;
    int db = dbucket(dist);
    const float4* T4 = (const float4*)(TO + (size_t)(b*64 + i) * HID);
    const float4* O4 = (const float4*)(TO + (size_t)(512 + b*64 + j) * HID);
    const float4* P4 = (const float4*)(wtabPt + (size_t)(wt-1) * HID);
    const float4* Q4 = (const float4*)(wtabPo + (size_t)(wo-1) * HID);
    const float4* D4 = (const float4*)(dtab + (size_t)db * HID);
    int t = threadIdx.x;
    float4 a = T4[t], c = O4[t], p = P4[t], q = Q4[t], d = D4[t];
    float vx = fmaxf(a.x + c.x + p.x + q.x + d.x, 0.f);
    float vy = fmaxf(a.y + c.y + p.y + q.y + d.y, 0.f);
    float vz = fmaxf(a.z + c.z + p.z + q.z + d.z, 0.f);
    float vw = fmaxf(a.w + c.w + p.w + q.w + d.w, 0.f);
    u32 p0 = (u32)f2bf(vx) | ((u32)f2bf(vy) << 16);
    u32 p1 = (u32)f2bf(vz) | ((u32)f2bf(vw) << 16);
    *(uint2*)(h1p + (size_t)row * HID + t * 4) = make_uint2(p0, p1);
}

// Wp2 [K][N] fp32 -> Wp2T [N][K] bf16
__global__ void k_wp2t(const float* __restrict__ Wp2, u16* __restrict__ Wp2T)
{
    int idx = blockIdx.x * 256 + threadIdx.x;   // over 1024*1024
    int k = idx >> 10, n = idx & 1023;
    Wp2T[(size_t)n * 1024 + k] = f2bf(Wp2[idx]);
}

// pair layer2: h2p = relu(h1p @ Wp2 + bp2), bf16 MFMA 16x16x32, 128x128 tile.
__global__ __launch_bounds__(256) void k_pair_l2(
    const u16* __restrict__ Abf,   // h1p [32768][1024] bf16 bits
    const u16* __restrict__ BT,    // Wp2T [1024(n)][1024(k)]
    const float* __restrict__ bias,
    u16* __restrict__ Cbf)         // h2p [32768][1024]
{
    constexpr int LD = 40;         // bf16 elems per LDS row (80B, 16B-aligned, 2-way banks)
    __shared__ __align__(16) u16 As[128 * LD];
    __shared__ __align__(16) u16 Bs[128 * LD];
    const int tid = threadIdx.x;
    const int bm = blockIdx.y * 128, bn = blockIdx.x * 128;
    const int wave = tid >> 6, lane = tid & 63;
    const int wr = wave >> 1, wc = wave & 1;
    const int q = lane >> 4, tl = lane & 15;

    f32x4 zero = {0.f, 0.f, 0.f, 0.f};
    f32x4 acc[4][4];
#pragma unroll
    for (int i = 0; i < 4; ++i)
#pragma unroll
        for (int j = 0; j < 4; ++j) acc[i][j] = zero;

    // staging: 128 rows x 32 bf16 per tile = 512 16B-chunks; 2 chunks/thread
    const int c0 = tid, c1 = tid + 256;
    const int r0 = c0 >> 2, o0 = (c0 & 3) * 8;
    const int r1 = c1 >> 2, o1 = (c1 & 3) * 8;

    for (int k0 = 0; k0 < 1024; k0 += 32) {
        *(float4*)(&As[r0 * LD + o0]) = *(const float4*)(Abf + (size_t)(bm + r0) * 1024 + k0 + o0);
        *(float4*)(&As[r1 * LD + o1]) = *(const float4*)(Abf + (size_t)(bm + r1) * 1024 + k0 + o1);
        *(float4*)(&Bs[r0 * LD + o0]) = *(const float4*)(BT + (size_t)(bn + r0) * 1024 + k0 + o0);
        *(float4*)(&Bs[r1 * LD + o1]) = *(const float4*)(BT + (size_t)(bn + r1) * 1024 + k0 + o1);
        __syncthreads();
        bf16x8 af[4], bf[4];
#pragma unroll
        for (int t = 0; t < 4; ++t) {
            af[t] = *(const bf16x8*)(&As[(wr*64 + t*16 + tl) * LD + q*8]);
            bf[t] = *(const bf16x8*)(&Bs[(wc*64 + t*16 + tl) * LD + q*8]);
        }
#pragma unroll
        for (int ti = 0; ti < 4; ++ti)
#pragma unroll
            for (int tj = 0; tj < 4; ++tj)
                acc[ti][tj] = __builtin_amdgcn_mfma_f32_16x16x32_bf16(af[ti], bf[tj], acc[ti][tj], 0, 0, 0);
        __syncthreads();
    }
    // C/D layout: col = lane&15, row = (lane>>4)*4 + reg   [measured m89/m91]
#pragma unroll
    for (int ti = 0; ti < 4; ++ti) {
#pragma unroll
        for (int tj = 0; tj < 4; ++tj) {
            int gcol = bn + wc*64 + tj*16 + tl;
            float bsv = bias[gcol];
#pragma unroll
            for (int r = 0; r < 4; ++r) {
                int grow = bm + wr*64 + ti*16 + q*4 + r;
                float v = acc[ti][tj][r] + bsv;
                v = fmaxf(v, 0.f);
                Cbf[(size_t)grow * 1024 + gcol] = f2bf(v);
            }
        }
    }
}

// pair layer3 + softmax -> out[48480 + r*4 + c]
__global__ __launch_bounds__(256) void k_pair_l3(
    const u16* __restrict__ h2p, const float* __restrict__ Wp3,
    const float* __restrict__ bp3, float* __restrict__ out)
{
    int wave = threadIdx.x >> 6, lane = threadIdx.x & 63;
    int r = blockIdx.x * 4 + wave;      // 32768 = 8192*4 exact
    const u16* hr = h2p + (size_t)r * HID;
    float s0 = 0.f, s1 = 0.f, s2 = 0.f, s3 = 0.f;
    for (int h = lane; h < HID; h += 64) {
        float v = bf2f(hr[h]);
        const float4 w = *(const float4*)(Wp3 + h * 4);
        s0 = fmaf(v, w.x, s0); s1 = fmaf(v, w.y, s1);
        s2 = fmaf(v, w.z, s2); s3 = fmaf(v, w.w, s3);
    }
#pragma unroll
    for (int off = 32; off > 0; off >>= 1) {
        s0 += __shfl_down(s0, off, 64);
        s1 += __shfl_down(s1, off, 64);
        s2 += __shfl_down(s2, off, 64);
        s3 += __shfl_down(s3, off, 64);
    }
    if (lane == 0) {
        s0 += bp3[0]; s1 += bp3[1]; s2 += bp3[2]; s3 += bp3[3];
        float m = fmaxf(fmaxf(s0, s1), fmaxf(s2, s3));
        float e0 = expf(s0 - m), e1 = expf(s1 - m), e2 = expf(s2 - m), e3 = expf(s3 - m);
        float inv = 1.f / (e0 + e1 + e2 + e3);
        float* o = out + (size_t)r * 4;
        o[0] = e0 * inv; o[1] = e1 * inv; o[2] = e2 * inv; o[3] = e3 * inv;
    }
}

extern "C" void kernel_launch(void* const* d_in, const int* in_sizes, int n_in,
                              void* d_out, int out_size, void* d_ws, size_t ws_size,
                              hipStream_t stream)
{
    const float* x    = (const float*)d_in[0];
    const float* wemb = (const float*)d_in[1];
    const float* demb = (const float*)d_in[2];
    const float* Ws1  = (const float*)d_in[3];
    const float* bs1  = (const float*)d_in[4];
    const float* Ws2  = (const float*)d_in[5];
    const float* bs2  = (const float*)d_in[6];
    const float* Ws3  = (const float*)d_in[7];
    const float* bs3  = (const float*)d_in[8];
    const float* Wp1  = (const float*)d_in[9];
    const float* bp1  = (const float*)d_in[10];
    const float* Wp2  = (const float*)d_in[11];
    const float* bp2  = (const float*)d_in[12];
    const float* Wp3  = (const float*)d_in[13];
    const float* bp3  = (const float*)d_in[14];
    float* out = (float*)d_out;
    char* ws = (char*)d_ws;

    // ---- workspace arena with lifetime-based aliasing (peak ~141 MB) ----
    // R1: h1s (span L1 out, dead after span L2)      -> h2p (pair L2 out)
    // R2: XALL (dead after build_h1s) -> h2s (dead after span_l3/topk) -> h1p
    const size_t RSZ = (size_t)32768 * HID * 2;       // 64 MiB (largest tenant)
    size_t off = 0;
    auto alloc = [&](size_t bytes) -> void* {
        void* p = ws + off;
        off += (bytes + 255) & ~(size_t)255;
        return p;
    };
    char* R1 = (char*)alloc(RSZ);
    char* R2 = (char*)alloc(RSZ);
    float* h1s  = (float*)R1;                         // 16160*1024*4 = 63.1 MiB
    u16*   h2p  = (u16*)R1;                           // 32768*1024*2 = 64 MiB
    float* XALL = (float*)R2;                         // 2048*2048*4  = 16 MiB
    float* h2s  = (float*)R2;                         // 63.1 MiB
    u16*   h1p  = (u16*)R2;                           // 64 MiB
    float* TO     = (float*)alloc((size_t)1024 * HID * 4);
    float* wtabS  = (float*)alloc(8 * HID * 4);
    float* wtabPt = (float*)alloc(8 * HID * 4);
    float* wtabPo = (float*)alloc(8 * HID * 4);
    float* dtab   = (float*)alloc(14 * HID * 4);
    int*   t_idx  = (int*)alloc(BATCH * NZ * 4);
    int*   o_idx  = (int*)alloc(BATCH * NZ * 4);
    int*   toks   = (int*)alloc(2048 * 4);
    u16*   Wp2T   = (u16*)alloc((size_t)1024 * 1024 * 2);
    (void)ws_size; (void)in_sizes; (void)n_in; (void)out_size;

    // small bucket tables (fold bs1 into wtabS, bp1 into dtab)
    k_tables<<<dim3(4, 38), 256, 0, stream>>>(wemb, demb, Ws1, bs1, Wp1, bp1,
                                              wtabS, wtabPt, wtabPo, dtab);
    // layer-1 factorization: XALL = x2d @ [Ws1_top | Ws1_mid]  (fp32)
    k_sgemm128<<<dim3(8, 16), 256, 0, stream>>>(x, DIM, Ws1, HID, XALL, 2048, 2048, DIM, nullptr, 0);
    k_sgemm128<<<dim3(8, 16), 256, 0, stream>>>(x, DIM, Ws1 + (size_t)768 * HID, HID, XALL + 1024, 2048, 2048, DIM, nullptr, 0);
    k_build_h1s<<<16160, 256, 0, stream>>>(XALL, wtabS, h1s);
    // span layer2 (fp32 — must be, for exact top-k ordering); h2s overwrites XALL (dead)
    k_sgemm128<<<dim3(8, 127), 256, 0, stream>>>(h1s, HID, Ws2, HID, h2s, HID, 16160, HID, bs2, 1);
    k_span_l3<<<4040, 256, 0, stream>>>(h2s, Ws3, bs3, out);
    k_topk<<<16, 64, 0, stream>>>(out, t_idx, o_idx);
    k_toks<<<4, 256, 0, stream>>>(t_idx, o_idx, toks);
    // gathered pair layer-1: T = x[ta]@Wp1[0:768] + x[tb-1]@Wp1[768:1536]; O analog
    k_sgemm64<<<dim3(16, 16), 256, 0, stream>>>(x, DIM, Wp1, Wp1 + (size_t)1561 * HID, 512, HID,
                                                TO, HID, 1024, DIM, 0, toks);
    k_sgemm64<<<dim3(16, 16), 256, 0, stream>>>(x, DIM, Wp1 + (size_t)768 * HID, Wp1 + (size_t)2329 * HID, 512, HID,
                                                TO, HID, 1024, DIM, 1, toks + 1024);
    k_wp2t<<<4096, 256, 0, stream>>>(Wp2, Wp2T);
    // h1p overwrites h2s (dead after span_l3/topk)
    k_build_h1p<<<32768, 256, 0, stream>>>(TO, t_idx, o_idx, wtabPt, wtabPo, dtab, h1p);
    // pair layer2: bf16 MFMA (selection-free path); h2p overwrites h1s (dead)
    k_pair_l2<<<dim3(8, 256), 256, 0, stream>>>(h1p, Wp2T, bp2, h2p);
    k_pair_l3<<<8192, 256, 0, stream>>>(h2p, Wp3, bp3, out + 48480);
}

// Round 3
// 778.191 us; speedup vs baseline: 1.6797x; 1.6797x over previous
//
#include <hip/hip_runtime.h>
#include <cstdint>
#include <cstddef>

#define BATCH 8
#define SEQ   256
#define DIM   768
#define NSPAN 2020
#define HID   1024
#define NZ    64

typedef unsigned short u16;
typedef unsigned int   u32;

typedef __bf16 bf16x8 __attribute__((ext_vector_type(8)));
typedef float  f32x4  __attribute__((ext_vector_type(4)));

__device__ __forceinline__ u16 f2bf(float f) {
    union { float f; u32 u; } x; x.f = f;
    u32 r = x.u + 0x7fffu + ((x.u >> 16) & 1u);
    return (u16)(r >> 16);
}
__device__ __forceinline__ float bf2f(u16 b) {
    union { u32 u; float f; } x; x.u = ((u32)b) << 16;
    return x.f;
}
// split v = hi + lo (both bf16); residual v-hi is exact in fp32 (15 low mantissa bits)
__device__ __forceinline__ void splitbf(float v, u16& h, u16& l) {
    h = f2bf(v);
    l = f2bf(v - bf2f(h));
}

// span s -> (start, end, width); spans enumerated width-major: w=1..8, starts 0..L-w
__device__ __forceinline__ void span_decode(int s, int& start, int& end, int& w) {
    int off = 0;
#pragma unroll
    for (int wi = 1; wi <= 8; ++wi) {
        int cnt = SEQ - wi + 1;
        if (s < off + cnt) { w = wi; start = s - off; end = start + wi; return; }
        off += cnt;
    }
    w = 8; start = 0; end = 8;
}

// searchsorted(BUCKET_BINS, d, 'right') - 1
__device__ __forceinline__ int dbucket(int d) {
    int b = 0;
    b += (d >= 1);  b += (d >= 2);  b += (d >= 3);  b += (d >= 4);
    b += (d >= 5);  b += (d >= 7);  b += (d >= 8);  b += (d >= 15);
    b += (d >= 16); b += (d >= 31); b += (d >= 32); b += (d >= 63);
    b += (d >= 64);
    return b;
}

// ---------------------------------------------------------------------------
// Tiny per-bucket tables (width/dist embeddings only hit 14 rows).
// ---------------------------------------------------------------------------
__global__ __launch_bounds__(256) void k_tables(
    const float* __restrict__ wemb, const float* __restrict__ demb,
    const float* __restrict__ Ws1, const float* __restrict__ bs1,
    const float* __restrict__ Wp1, const float* __restrict__ bp1,
    float* __restrict__ wtabS, float* __restrict__ wtabPt,
    float* __restrict__ wtabPo, float* __restrict__ dtab)
{
    int h = blockIdx.x * 256 + threadIdx.x;   // 0..1023
    int row = blockIdx.y;                     // 0..37
    const int wb[8] = {1,2,3,4,5,5,6,7};      // width 1..8 -> bucket
    if (row < 8) {
        int bk = wb[row];
        float acc = bs1[h];
        for (int j = 0; j < 25; ++j) acc = fmaf(wemb[bk*25+j], Ws1[(size_t)(1536+j)*HID + h], acc);
        wtabS[row*HID + h] = acc;
    } else if (row < 16) {
        int bk = wb[row-8];
        float acc = 0.f;
        for (int j = 0; j < 25; ++j) acc = fmaf(wemb[bk*25+j], Wp1[(size_t)(1536+j)*HID + h], acc);
        wtabPt[(row-8)*HID + h] = acc;
    } else if (row < 24) {
        int bk = wb[row-16];
        float acc = 0.f;
        for (int j = 0; j < 25; ++j) acc = fmaf(wemb[bk*25+j], Wp1[(size_t)(3097+j)*HID + h], acc);
        wtabPo[(row-16)*HID + h] = acc;
    } else {
        int t = row - 24;                     // 0..13
        float acc = bp1[h];
        for (int j = 0; j < 25; ++j) acc = fmaf(demb[t*25+j], Wp1[(size_t)(3122+j)*HID + h], acc);
        dtab[t*HID + h] = acc;
    }
}

// ---------------------------------------------------------------------------
// split helpers (one-time prep)
// ---------------------------------------------------------------------------
__global__ void k_split_flat(const float* __restrict__ src, u16* __restrict__ hi,
                             u16* __restrict__ lo, int n)
{
    int i = blockIdx.x * 256 + threadIdx.x;
    if (i >= n) return;
    u16 h, l; splitbf(src[i], h, l);
    hi[i] = h; lo[i] = l;
}

// BT[n][k] for XALL GEMM: n<1024 -> Ws1[k][n] (top block), else Ws1[768+k][n-1024] (mid block)
__global__ void k_split_w1t(const float* __restrict__ Ws1, u16* __restrict__ th, u16* __restrict__ tl)
{
    int i = blockIdx.x * 256 + threadIdx.x;   // over 2048*768
    if (i >= 2048 * 768) return;
    int n = i / 768, k = i - n * 768;
    float v = (n < 1024) ? Ws1[(size_t)k * HID + n]
                         : Ws1[(size_t)(768 + k) * HID + (n - 1024)];
    u16 h, l; splitbf(v, h, l);
    th[i] = h; tl[i] = l;
}

// W2T[n][k] = Ws2[k][n], split
__global__ void k_split_w2t(const float* __restrict__ Ws2, u16* __restrict__ th, u16* __restrict__ tl)
{
    int i = blockIdx.x * 256 + threadIdx.x;   // over 1024*1024
    int n = i >> 10, k = i & 1023;
    u16 h, l; splitbf(Ws2[(size_t)k * HID + n], h, l);
    th[i] = h; tl[i] = l;
}

// ---------------------------------------------------------------------------
// Error-compensated split-bf16 MFMA GEMM: C = (Ah+Al)@(Bh+Bl)^T(stored as BT[n][k])
//   = Ah Bh + Al Bh + Ah Bl  (dropped AlBl ~ 2^-18 rel)
// 128x128 tile, BK=32, 3x16 MFMA per K-tile, fp32 C with optional bias/relu.
// ---------------------------------------------------------------------------
__global__ __launch_bounds__(256) void k_gemm3bf(
    const u16* __restrict__ Ah, const u16* __restrict__ Al, int lda,
    const u16* __restrict__ BTh, const u16* __restrict__ BTl, int ldb,
    float* __restrict__ C, int ldc,
    int M, int K,
    const float* __restrict__ bias, int relu)
{
    constexpr int LD = 40;   // bf16 per LDS row (80 B: 16B-aligned, 2-way bank alias = free)
    __shared__ __align__(16) u16 sm[4 * 128 * LD];
    u16* sAh = sm;
    u16* sAl = sm + 128 * LD;
    u16* sBh = sm + 2 * 128 * LD;
    u16* sBl = sm + 3 * 128 * LD;
    const int tid = threadIdx.x;
    const int bm = blockIdx.y * 128, bn = blockIdx.x * 128;
    const int wave = tid >> 6, lane = tid & 63;
    const int wr = wave >> 1, wc = wave & 1;
    const int q = lane >> 4, tl = lane & 15;

    f32x4 zero = {0.f, 0.f, 0.f, 0.f};
    f32x4 acc[4][4];
#pragma unroll
    for (int i = 0; i < 4; ++i)
#pragma unroll
        for (int j = 0; j < 4; ++j) acc[i][j] = zero;

    // staging: each tile = 128 rows x 32 bf16 = 512 16B-chunks; 2 chunks/thread/tile
    const int r0 = tid >> 2, o0 = (tid & 3) * 8;
    const int r1 = (tid + 256) >> 2, o1 = ((tid + 256) & 3) * 8;
    int am0 = bm + r0; if (am0 >= M) am0 = M - 1;
    int am1 = bm + r1; if (am1 >= M) am1 = M - 1;

    for (int k0 = 0; k0 < K; k0 += 32) {
        *(float4*)(&sAh[r0*LD + o0]) = *(const float4*)(Ah + (size_t)am0 * lda + k0 + o0);
        *(float4*)(&sAh[r1*LD + o1]) = *(const float4*)(Ah + (size_t)am1 * lda + k0 + o1);
        *(float4*)(&sAl[r0*LD + o0]) = *(const float4*)(Al + (size_t)am0 * lda + k0 + o0);
        *(float4*)(&sAl[r1*LD + o1]) = *(const float4*)(Al + (size_t)am1 * lda + k0 + o1);
        *(float4*)(&sBh[r0*LD + o0]) = *(const float4*)(BTh + (size_t)(bn + r0) * ldb + k0 + o0);
        *(float4*)(&sBh[r1*LD + o1]) = *(const float4*)(BTh + (size_t)(bn + r1) * ldb + k0 + o1);
        *(float4*)(&sBl[r0*LD + o0]) = *(const float4*)(BTl + (size_t)(bn + r0) * ldb + k0 + o0);
        *(float4*)(&sBl[r1*LD + o1]) = *(const float4*)(BTl + (size_t)(bn + r1) * ldb + k0 + o1);
        __syncthreads();
        bf16x8 ah[4], al[4], bh[4], bl[4];
#pragma unroll
        for (int t = 0; t < 4; ++t) {
            int arow = (wr*64 + t*16 + tl) * LD + q*8;
            int brow = (wc*64 + t*16 + tl) * LD + q*8;
            ah[t] = *(const bf16x8*)(&sAh[arow]);
            al[t] = *(const bf16x8*)(&sAl[arow]);
            bh[t] = *(const bf16x8*)(&sBh[brow]);
            bl[t] = *(const bf16x8*)(&sBl[brow]);
        }
#pragma unroll
        for (int ti = 0; ti < 4; ++ti)
#pragma unroll
            for (int tj = 0; tj < 4; ++tj) {
                acc[ti][tj] = __builtin_amdgcn_mfma_f32_16x16x32_bf16(ah[ti], bh[tj], acc[ti][tj], 0, 0, 0);
                acc[ti][tj] = __builtin_amdgcn_mfma_f32_16x16x32_bf16(al[ti], bh[tj], acc[ti][tj], 0, 0, 0);
                acc[ti][tj] = __builtin_amdgcn_mfma_f32_16x16x32_bf16(ah[ti], bl[tj], acc[ti][tj], 0, 0, 0);
            }
        __syncthreads();
    }
    // C/D layout: col = lane&15, row = (lane>>4)*4 + reg  [measured m89/m91]
#pragma unroll
    for (int ti = 0; ti < 4; ++ti) {
#pragma unroll
        for (int tj = 0; tj < 4; ++tj) {
            int gcol = bn + wc*64 + tj*16 + tl;
            float bsv = bias ? bias[gcol] : 0.f;
#pragma unroll
            for (int r = 0; r < 4; ++r) {
                int grow = bm + wr*64 + ti*16 + q*4 + r;
                if (grow >= M) continue;
                float v = acc[ti][tj][r] + bsv;
                if (relu) v = fmaxf(v, 0.f);
                C[(size_t)grow * ldc + gcol] = v;
            }
        }
    }
}

// ---------------------------------------------------------------------------
// fp32 SIMT GEMM, 64x64 tile, with A-row gather (rowmap) + dual B pointer.
// (tiny 1024x1024x768 gathered GEMMs for the pair T/O reps)
// ---------------------------------------------------------------------------
__global__ __launch_bounds__(256) void k_sgemm64(
    const float* __restrict__ A, int lda,
    const float* __restrict__ Bm, const float* __restrict__ BmO, int o_row_start, int ldb,
    float* __restrict__ C, int ldc,
    int M, int K, int accum,
    const int* __restrict__ rowmap)
{
    __shared__ float As[8][68];
    __shared__ float Bs[8][68];
    const int tid = threadIdx.x;
    const int tx = tid & 15, ty = tid >> 4;
    const int bm = blockIdx.y * 64, bn = blockIdx.x * 64;
    const float* Bp = (bm >= o_row_start) ? BmO : Bm;

    float acc[4][4];
#pragma unroll
    for (int i = 0; i < 4; ++i)
#pragma unroll
        for (int j = 0; j < 4; ++j) acc[i][j] = 0.f;

    const int ar = tid >> 2, ak = (tid & 3) * 2;
    const int br = tid >> 5, bc = (tid & 31) * 2;
    const int garow = bm + ar;
    const bool aok = garow < M;
    int aphys = 0;
    if (aok) aphys = rowmap ? rowmap[garow] : garow;
    const float* Aptr = A + (size_t)aphys * lda;

    for (int k0 = 0; k0 < K; k0 += 8) {
        float2 av = make_float2(0.f, 0.f);
        if (aok) av = *(const float2*)(Aptr + k0 + ak);
        As[ak][ar] = av.x; As[ak+1][ar] = av.y;
        float2 bv = *(const float2*)(Bp + (size_t)(k0 + br) * ldb + bn + bc);
        Bs[br][bc] = bv.x; Bs[br][bc+1] = bv.y;
        __syncthreads();
#pragma unroll
        for (int kk = 0; kk < 8; ++kk) {
            float a[4], b[4];
#pragma unroll
            for (int i = 0; i < 4; ++i) a[i] = As[kk][ty*4 + i];
#pragma unroll
            for (int j = 0; j < 4; ++j) b[j] = Bs[kk][tx*4 + j];
#pragma unroll
            for (int i = 0; i < 4; ++i)
#pragma unroll
                for (int j = 0; j < 4; ++j) acc[i][j] = fmaf(a[i], b[j], acc[i][j]);
        }
        __syncthreads();
    }
#pragma unroll
    for (int i = 0; i < 4; ++i) {
        int r = bm + ty*4 + i;
        if (r >= M) continue;
        float* crow = C + (size_t)r * ldc + bn + tx*4;
        float4 v = make_float4(acc[i][0], acc[i][1], acc[i][2], acc[i][3]);
        if (accum) {
            float4 o = *(const float4*)crow;
            v.x += o.x; v.y += o.y; v.z += o.z; v.w += o.w;
        }
        *(float4*)crow = v;
    }
}

// h1s = relu(XALL[b,start,0:1024] + XALL[b,end-1,1024:2048] + wtabS[w-1]) -> split bf16
__global__ __launch_bounds__(256) void k_build_h1s(
    const float* __restrict__ XALL, const float* __restrict__ wtabS,
    u16* __restrict__ h1h, u16* __restrict__ h1l)
{
    int r = blockIdx.x;                 // 0..16159
    int b = r / NSPAN, s = r - b * NSPAN;
    int st, en, w; span_decode(s, st, en, w);
    const float4* xs = (const float4*)(XALL + (size_t)(b*SEQ + st) * 2048);
    const float4* xe = (const float4*)(XALL + (size_t)(b*SEQ + en - 1) * 2048 + 1024);
    const float4* wt = (const float4*)(wtabS + (size_t)(w-1) * HID);
    int t = threadIdx.x;
    float4 a = xs[t], bz = xe[t], c = wt[t];
    float v0 = fmaxf(a.x + bz.x + c.x, 0.f);
    float v1 = fmaxf(a.y + bz.y + c.y, 0.f);
    float v2 = fmaxf(a.z + bz.z + c.z, 0.f);
    float v3 = fmaxf(a.w + bz.w + c.w, 0.f);
    u16 h0,l0,h1,l1,h2,l2,h3,l3;
    splitbf(v0,h0,l0); splitbf(v1,h1,l1); splitbf(v2,h2,l2); splitbf(v3,h3,l3);
    size_t base = (size_t)r * HID + t * 4;
    *(uint2*)(h1h + base) = make_uint2((u32)h0 | ((u32)h1 << 16), (u32)h2 | ((u32)h3 << 16));
    *(uint2*)(h1l + base) = make_uint2((u32)l0 | ((u32)l1 << 16), (u32)l2 | ((u32)l3 << 16));
}

// span layer3 + softmax -> out[r*3 + c]. One wave per row, 4 rows/block.
__global__ __launch_bounds__(256) void k_span_l3(
    const float* __restrict__ h2s, const float* __restrict__ Ws3,
    const float* __restrict__ bs3, float* __restrict__ out)
{
    int wave = threadIdx.x >> 6, lane = threadIdx.x & 63;
    int r = blockIdx.x * 4 + wave;      // 16160 = 4040*4 exact
    const float* hr = h2s + (size_t)r * HID;
    float s0 = 0.f, s1 = 0.f, s2 = 0.f;
    for (int h = lane; h < HID; h += 64) {
        float v = hr[h];
        const float* wrow = Ws3 + h * 3;
        s0 = fmaf(v, wrow[0], s0);
        s1 = fmaf(v, wrow[1], s1);
        s2 = fmaf(v, wrow[2], s2);
    }
#pragma unroll
    for (int off = 32; off > 0; off >>= 1) {
        s0 += __shfl_down(s0, off, 64);
        s1 += __shfl_down(s1, off, 64);
        s2 += __shfl_down(s2, off, 64);
    }
    if (lane == 0) {
        s0 += bs3[0]; s1 += bs3[1]; s2 += bs3[2];
        float m = fmaxf(s0, fmaxf(s1, s2));
        float e0 = expf(s0 - m), e1 = expf(s1 - m), e2 = expf(s2 - m);
        float inv = 1.f / (e0 + e1 + e2);
        float* o = out + (size_t)r * 3;
        o[0] = e0 * inv; o[1] = e1 * inv; o[2] = e2 * inv;
    }
}

// top-64 (descending, ties -> lower index). 256 threads: 4-wave scan + LDS combine.
__global__ __launch_bounds__(256) void k_topk(
    const float* __restrict__ sp, int* __restrict__ t_idx, int* __restrict__ o_idx)
{
    int b = blockIdx.x >> 1;
    int head = 1 + (blockIdx.x & 1);
    int* outp = (head == 1 ? t_idx : o_idx) + b * NZ;
    __shared__ float sc[NSPAN];
    __shared__ float swv[4];
    __shared__ int   swi[4];
    int tid = threadIdx.x, lane = tid & 63, wv = tid >> 6;
    for (int s = tid; s < NSPAN; s += 256)
        sc[s] = sp[((size_t)b * NSPAN + s) * 3 + head];
    __syncthreads();
    for (int it = 0; it < NZ; ++it) {
        float bv = -1e30f; int bi = 1 << 29;
        for (int s = tid; s < NSPAN; s += 256) {
            float v = sc[s];
            if (v > bv || (v == bv && s < bi)) { bv = v; bi = s; }
        }
#pragma unroll
        for (int off = 32; off > 0; off >>= 1) {
            float ov = __shfl_down(bv, off, 64);
            int   oi = __shfl_down(bi, off, 64);
            if (ov > bv || (ov == bv && oi < bi)) { bv = ov; bi = oi; }
        }
        if (lane == 0) { swv[wv] = bv; swi[wv] = bi; }
        __syncthreads();
        if (tid == 0) {
            float fv = swv[0]; int fi = swi[0];
#pragma unroll
            for (int wvi = 1; wvi < 4; ++wvi) {
                float ov = swv[wvi]; int oi = swi[wvi];
                if (ov > fv || (ov == fv && oi < fi)) { fv = ov; fi = oi; }
            }
            if (fi < 0 || fi >= NSPAN) fi = 0;
            outp[it] = fi; sc[fi] = -1e30f;
        }
        __syncthreads();
    }
}

// token rowmaps for the gathered T/O GEMMs.
__global__ void k_toks(const int* __restrict__ t_idx, const int* __restrict__ o_idx,
                       int* __restrict__ toks)
{
    int r = blockIdx.x * 256 + threadIdx.x;
    if (r >= 1024) return;
    int b, sidx;
    if (r < 512) { b = r >> 6; sidx = t_idx[r]; }
    else { int q = r - 512; b = q >> 6; sidx = o_idx[q]; }
    int st, en, w; span_decode(sidx, st, en, w);
    toks[r] = b * SEQ + st;
    toks[1024 + r] = b * SEQ + en - 1;
}

// h1_pair[row] = relu(T[b,i] + O[b,j] + wtabPt + wtabPo + dtab) -> bf16
__global__ __launch_bounds__(256) void k_build_h1p(
    const float* __restrict__ TO, const int* __restrict__ t_idx, const int* __restrict__ o_idx,
    const float* __restrict__ wtabPt, const float* __restrict__ wtabPo,
    const float* __restrict__ dtab, u16* __restrict__ h1p)
{
    int row = blockIdx.x;               // b*4096 + i*64 + j
    int b = row >> 12, i = (row >> 6) & 63, j = row & 63;
    int ts = t_idx[b*64 + i], os = o_idx[b*64 + j];
    int ta, tb, wt, oc, od, wo;
    span_decode(ts, ta, tb, wt);
    span_decode(os, oc, od, wo);
    int d1 = tb - oc; d1 = d1 < 0 ? -d1 : d1;
    int d2 = ta - od; d2 = d2 < 0 ? -d2 : d2;
    int dist = d1 < d2 ? d1 : d2;
    int db = dbucket(dist);
    const float4* T4 = (const float4*)(TO + (size_t)(b*64 + i) * HID);
    const float4* O4 = (const float4*)(TO + (size_t)(512 + b*64 + j) * HID);
    const float4* P4 = (const float4*)(wtabPt + (size_t)(wt-1) * HID);
    const float4* Q4 = (const float4*)(wtabPo + (size_t)(wo-1) * HID);
    const float4* D4 = (const float4*)(dtab + (size_t)db * HID);
    int t = threadIdx.x;
    float4 a = T4[t], c = O4[t], p = P4[t], q = Q4[t], d = D4[t];
    float vx = fmaxf(a.x + c.x + p.x + q.x + d.x, 0.f);
    float vy = fmaxf(a.y + c.y + p.y + q.y + d.y, 0.f);
    float vz = fmaxf(a.z + c.z + p.z + q.z + d.z, 0.f);
    float vw = fmaxf(a.w + c.w + p.w + q.w + d.w, 0.f);
    u32 p0 = (u32)f2bf(vx) | ((u32)f2bf(vy) << 16);
    u32 p1 = (u32)f2bf(vz) | ((u32)f2bf(vw) << 16);
    *(uint2*)(h1p + (size_t)row * HID + t * 4) = make_uint2(p0, p1);
}

// Wp2 [K][N] fp32 -> Wp2T [N][K] bf16
__global__ void k_wp2t(const float* __restrict__ Wp2, u16* __restrict__ Wp2T)
{
    int idx = blockIdx.x * 256 + threadIdx.x;   // over 1024*1024
    int k = idx >> 10, n = idx & 1023;
    Wp2T[(size_t)n * 1024 + k] = f2bf(Wp2[idx]);
}

// pair layer2: h2p = relu(h1p @ Wp2 + bp2), single-pass bf16 MFMA, 128x128 tile.
__global__ __launch_bounds__(256) void k_pair_l2(
    const u16* __restrict__ Abf, const u16* __restrict__ BT,
    const float* __restrict__ bias, u16* __restrict__ Cbf)
{
    constexpr int LD = 40;
    __shared__ __align__(16) u16 As[128 * LD];
    __shared__ __align__(16) u16 Bs[128 * LD];
    const int tid = threadIdx.x;
    const int bm = blockIdx.y * 128, bn = blockIdx.x * 128;
    const int wave = tid >> 6, lane = tid & 63;
    const int wr = wave >> 1, wc = wave & 1;
    const int q = lane >> 4, tl = lane & 15;

    f32x4 zero = {0.f, 0.f, 0.f, 0.f};
    f32x4 acc[4][4];
#pragma unroll
    for (int i = 0; i < 4; ++i)
#pragma unroll
        for (int j = 0; j < 4; ++j) acc[i][j] = zero;

    const int r0 = tid >> 2, o0 = (tid & 3) * 8;
    const int r1 = (tid + 256) >> 2, o1 = ((tid + 256) & 3) * 8;

    for (int k0 = 0; k0 < 1024; k0 += 32) {
        *(float4*)(&As[r0*LD + o0]) = *(const float4*)(Abf + (size_t)(bm + r0) * 1024 + k0 + o0);
        *(float4*)(&As[r1*LD + o1]) = *(const float4*)(Abf + (size_t)(bm + r1) * 1024 + k0 + o1);
        *(float4*)(&Bs[r0*LD + o0]) = *(const float4*)(BT + (size_t)(bn + r0) * 1024 + k0 + o0);
        *(float4*)(&Bs[r1*LD + o1]) = *(const float4*)(BT + (size_t)(bn + r1) * 1024 + k0 + o1);
        __syncthreads();
        bf16x8 af[4], bf[4];
#pragma unroll
        for (int t = 0; t < 4; ++t) {
            af[t] = *(const bf16x8*)(&As[(wr*64 + t*16 + tl) * LD + q*8]);
            bf[t] = *(const bf16x8*)(&Bs[(wc*64 + t*16 + tl) * LD + q*8]);
        }
#pragma unroll
        for (int ti = 0; ti < 4; ++ti)
#pragma unroll
            for (int tj = 0; tj < 4; ++tj)
                acc[ti][tj] = __builtin_amdgcn_mfma_f32_16x16x32_bf16(af[ti], bf[tj], acc[ti][tj], 0, 0, 0);
        __syncthreads();
    }
#pragma unroll
    for (int ti = 0; ti < 4; ++ti) {
#pragma unroll
        for (int tj = 0; tj < 4; ++tj) {
            int gcol = bn + wc*64 + tj*16 + tl;
            float bsv = bias[gcol];
#pragma unroll
            for (int r = 0; r < 4; ++r) {
                int grow = bm + wr*64 + ti*16 + q*4 + r;
                float v = acc[ti][tj][r] + bsv;
                v = fmaxf(v, 0.f);
                Cbf[(size_t)grow * 1024 + gcol] = f2bf(v);
            }
        }
    }
}

// pair layer3 + softmax -> out[48480 + r*4 + c]
__global__ __launch_bounds__(256) void k_pair_l3(
    const u16* __restrict__ h2p, const float* __restrict__ Wp3,
    const float* __restrict__ bp3, float* __restrict__ out)
{
    int wave = threadIdx.x >> 6, lane = threadIdx.x & 63;
    int r = blockIdx.x * 4 + wave;      // 32768 = 8192*4 exact
    const u16* hr = h2p + (size_t)r * HID;
    float s0 = 0.f, s1 = 0.f, s2 = 0.f, s3 = 0.f;
    for (int h = lane; h < HID; h += 64) {
        float v = bf2f(hr[h]);
        const float4 w = *(const float4*)(Wp3 + h * 4);
        s0 = fmaf(v, w.x, s0); s1 = fmaf(v, w.y, s1);
        s2 = fmaf(v, w.z, s2); s3 = fmaf(v, w.w, s3);
    }
#pragma unroll
    for (int off = 32; off > 0; off >>= 1) {
        s0 += __shfl_down(s0, off, 64);
        s1 += __shfl_down(s1, off, 64);
        s2 += __shfl_down(s2, off, 64);
        s3 += __shfl_down(s3, off, 64);
    }
    if (lane == 0) {
        s0 += bp3[0]; s1 += bp3[1]; s2 += bp3[2]; s3 += bp3[3];
        float m = fmaxf(fmaxf(s0, s1), fmaxf(s2, s3));
        float e0 = expf(s0 - m), e1 = expf(s1 - m), e2 = expf(s2 - m), e3 = expf(s3 - m);
        float inv = 1.f / (e0 + e1 + e2 + e3);
        float* o = out + (size_t)r * 4;
        o[0] = e0 * inv; o[1] = e1 * inv; o[2] = e2 * inv; o[3] = e3 * inv;
    }
}

extern "C" void kernel_launch(void* const* d_in, const int* in_sizes, int n_in,
                              void* d_out, int out_size, void* d_ws, size_t ws_size,
                              hipStream_t stream)
{
    const float* x    = (const float*)d_in[0];
    const float* wemb = (const float*)d_in[1];
    const float* demb = (const float*)d_in[2];
    const float* Ws1  = (const float*)d_in[3];
    const float* bs1  = (const float*)d_in[4];
    const float* Ws2  = (const float*)d_in[5];
    const float* bs2  = (const float*)d_in[6];
    const float* Ws3  = (const float*)d_in[7];
    const float* bs3  = (const float*)d_in[8];
    const float* Wp1  = (const float*)d_in[9];
    const float* bp1  = (const float*)d_in[10];
    const float* Wp2  = (const float*)d_in[11];
    const float* bp2  = (const float*)d_in[12];
    const float* Wp3  = (const float*)d_in[13];
    const float* bp3  = (const float*)d_in[14];
    float* out = (float*)d_out;
    char* ws = (char*)d_ws;

    // ---- workspace arena, lifetime-aliased (peak ~142 MB) ----
    // R1 (64 MiB): h1s_h+h1s_l (66.19e6 B, dead after span L2) -> h2p (64 MiB)
    // R2 (64 MiB): [XALL 16M | xh/xl/W1Th/W1Tl 12M] (dead after build_h1s)
    //              -> h2s (63.1M, dead after span_l3/topk) -> h1p (64 MiB)
    const size_t RSZ = (size_t)32768 * HID * 2;   // 64 MiB
    size_t off = 0;
    auto alloc = [&](size_t bytes) -> void* {
        void* p = ws + off;
        off += (bytes + 255) & ~(size_t)255;
        return p;
    };
    char* R1 = (char*)alloc(RSZ);
    char* R2 = (char*)alloc(RSZ);
    u16*   h1h  = (u16*)R1;                              // 33.1 MB
    u16*   h1l  = (u16*)(R1 + (size_t)16160 * HID * 2);  // 33.1 MB
    u16*   h2p  = (u16*)R1;                              // 64 MiB (after h1s dead)
    float* XALL = (float*)R2;                            // 16 MiB
    u16*   xh   = (u16*)(R2 + (16u << 20));              // 3 MB
    u16*   xl   = (u16*)(R2 + (19u << 20));
    u16*   W1Th = (u16*)(R2 + (22u << 20));
    u16*   W1Tl = (u16*)(R2 + (25u << 20));
    float* h2s  = (float*)R2;                            // 63.1 MB (after XALL/splits dead)
    u16*   h1p  = (u16*)R2;                              // 64 MiB (after h2s dead)
    float* TO     = (float*)alloc((size_t)1024 * HID * 4);
    u16*   W2Th   = (u16*)alloc((size_t)1024 * 1024 * 2);
    u16*   W2Tl   = (u16*)alloc((size_t)1024 * 1024 * 2);
    u16*   Wp2T   = (u16*)alloc((size_t)1024 * 1024 * 2);
    float* wtabS  = (float*)alloc(8 * HID * 4);
    float* wtabPt = (float*)alloc(8 * HID * 4);
    float* wtabPo = (float*)alloc(8 * HID * 4);
    float* dtab   = (float*)alloc(14 * HID * 4);
    int*   t_idx  = (int*)alloc(BATCH * NZ * 4);
    int*   o_idx  = (int*)alloc(BATCH * NZ * 4);
    int*   toks   = (int*)alloc(2048 * 4);
    (void)ws_size; (void)in_sizes; (void)n_in; (void)out_size;

    // prep: tables + bf16 hi/lo splits
    k_tables<<<dim3(4, 38), 256, 0, stream>>>(wemb, demb, Ws1, bs1, Wp1, bp1,
                                              wtabS, wtabPt, wtabPo, dtab);
    k_split_flat<<<6144, 256, 0, stream>>>(x, xh, xl, 2048 * 768);
    k_split_w1t<<<6144, 256, 0, stream>>>(Ws1, W1Th, W1Tl);
    k_split_w2t<<<4096, 256, 0, stream>>>(Ws2, W2Th, W2Tl);
    k_wp2t<<<4096, 256, 0, stream>>>(Wp2, Wp2T);

    // layer-1 factorization: XALL = x2d @ [Ws1_top | Ws1_mid]  (3-pass split-bf16 MFMA)
    k_gemm3bf<<<dim3(16, 16), 256, 0, stream>>>(xh, xl, 768, W1Th, W1Tl, 768,
                                                XALL, 2048, 2048, 768, nullptr, 0);
    k_build_h1s<<<16160, 256, 0, stream>>>(XALL, wtabS, h1h, h1l);
    // span layer2: 3-pass split-bf16 MFMA (error ~1e-6, preserves top-k ordering)
    k_gemm3bf<<<dim3(8, 127), 256, 0, stream>>>(h1h, h1l, HID, W2Th, W2Tl, HID,
                                                h2s, HID, 16160, HID, bs2, 1);
    k_span_l3<<<4040, 256, 0, stream>>>(h2s, Ws3, bs3, out);
    k_topk<<<16, 256, 0, stream>>>(out, t_idx, o_idx);
    k_toks<<<4, 256, 0, stream>>>(t_idx, o_idx, toks);
    // gathered pair layer-1 (fp32): T = x[ta]@Wp1[0:768] + x[tb-1]@Wp1[768:1536]; O analog
    k_sgemm64<<<dim3(16, 16), 256, 0, stream>>>(x, DIM, Wp1, Wp1 + (size_t)1561 * HID, 512, HID,
                                                TO, HID, 1024, DIM, 0, toks);
    k_sgemm64<<<dim3(16, 16), 256, 0, stream>>>(x, DIM, Wp1 + (size_t)768 * HID, Wp1 + (size_t)2329 * HID, 512, HID,
                                                TO, HID, 1024, DIM, 1, toks + 1024);
    k_build_h1p<<<32768, 256, 0, stream>>>(TO, t_idx, o_idx, wtabPt, wtabPo, dtab, h1p);
    // pair layer2: single-pass bf16 MFMA (selection-free path)
    k_pair_l2<<<dim3(8, 256), 256, 0, stream>>>(h1p, Wp2T, bp2, h2p);
    k_pair_l3<<<8192, 256, 0, stream>>>(h2p, Wp3, bp3, out + 48480);
}

// Round 4
// 735.910 us; speedup vs baseline: 1.7762x; 1.0575x over previous
//
#include <hip/hip_runtime.h>
#include <cstdint>
#include <cstddef>

#define BATCH 8
#define SEQ   256
#define DIM   768
#define NSPAN 2020
#define HID   1024
#define NZ    64

typedef unsigned short u16;
typedef unsigned int   u32;

typedef __bf16 bf16x8 __attribute__((ext_vector_type(8)));
typedef float  f32x4  __attribute__((ext_vector_type(4)));

__device__ __forceinline__ u16 f2bf(float f) {
    union { float f; u32 u; } x; x.f = f;
    u32 r = x.u + 0x7fffu + ((x.u >> 16) & 1u);
    return (u16)(r >> 16);
}
__device__ __forceinline__ float bf2f(u16 b) {
    union { u32 u; float f; } x; x.u = ((u32)b) << 16;
    return x.f;
}
// split v = hi + lo (both bf16); residual v-hi is exact in fp32
__device__ __forceinline__ void splitbf(float v, u16& h, u16& l) {
    h = f2bf(v);
    l = f2bf(v - bf2f(h));
}

// span s -> (start, end, width); spans enumerated width-major: w=1..8, starts 0..L-w
__device__ __forceinline__ void span_decode(int s, int& start, int& end, int& w) {
    int off = 0;
#pragma unroll
    for (int wi = 1; wi <= 8; ++wi) {
        int cnt = SEQ - wi + 1;
        if (s < off + cnt) { w = wi; start = s - off; end = start + wi; return; }
        off += cnt;
    }
    w = 8; start = 0; end = 8;
}

// searchsorted(BUCKET_BINS, d, 'right') - 1
__device__ __forceinline__ int dbucket(int d) {
    int b = 0;
    b += (d >= 1);  b += (d >= 2);  b += (d >= 3);  b += (d >= 4);
    b += (d >= 5);  b += (d >= 7);  b += (d >= 8);  b += (d >= 15);
    b += (d >= 16); b += (d >= 31); b += (d >= 32); b += (d >= 63);
    b += (d >= 64);
    return b;
}

// XCD-aware deswizzle: 1D launch; guarantees (linear id) % 8 == by % 8 so all
// column-blocks sharing one A-row-tile land on the SAME XCD (id%8 round-robin).
// sft = log2(nbx). Grid must be ceil(nby/8)*8*nbx blocks.
__device__ __forceinline__ void xcd_map(int L, int sft, int& bx, int& by) {
    int grp = L >> (3 + sft);
    int rem = L & ((1 << (3 + sft)) - 1);
    bx = rem >> 3;
    by = (grp << 3) | (rem & 7);
}

// ---------------------------------------------------------------------------
// Tiny per-bucket tables (width/dist embeddings only hit 14 rows).
// ---------------------------------------------------------------------------
__global__ __launch_bounds__(256) void k_tables(
    const float* __restrict__ wemb, const float* __restrict__ demb,
    const float* __restrict__ Ws1, const float* __restrict__ bs1,
    const float* __restrict__ Wp1, const float* __restrict__ bp1,
    float* __restrict__ wtabS, float* __restrict__ wtabPt,
    float* __restrict__ wtabPo, float* __restrict__ dtab)
{
    int h = blockIdx.x * 256 + threadIdx.x;   // 0..1023
    int row = blockIdx.y;                     // 0..37
    const int wb[8] = {1,2,3,4,5,5,6,7};      // width 1..8 -> bucket
    if (row < 8) {
        int bk = wb[row];
        float acc = bs1[h];
        for (int j = 0; j < 25; ++j) acc = fmaf(wemb[bk*25+j], Ws1[(size_t)(1536+j)*HID + h], acc);
        wtabS[row*HID + h] = acc;
    } else if (row < 16) {
        int bk = wb[row-8];
        float acc = 0.f;
        for (int j = 0; j < 25; ++j) acc = fmaf(wemb[bk*25+j], Wp1[(size_t)(1536+j)*HID + h], acc);
        wtabPt[(row-8)*HID + h] = acc;
    } else if (row < 24) {
        int bk = wb[row-16];
        float acc = 0.f;
        for (int j = 0; j < 25; ++j) acc = fmaf(wemb[bk*25+j], Wp1[(size_t)(3097+j)*HID + h], acc);
        wtabPo[(row-16)*HID + h] = acc;
    } else {
        int t = row - 24;                     // 0..13
        float acc = bp1[h];
        for (int j = 0; j < 25; ++j) acc = fmaf(demb[t*25+j], Wp1[(size_t)(3122+j)*HID + h], acc);
        dtab[t*HID + h] = acc;
    }
}

// ---------------------------------------------------------------------------
// Fused one-time prep: x split | W1T split | W2T split | Wp2T cast.
// Segmented flat index space; segment boundaries are multiples of 256 so each
// block stays in one segment (wave-uniform branch).
//   seg0: [0, 1572864)          x -> xh/xl
//   seg1: [1572864, 3145728)    Ws1 -> W1Th/W1Tl (transposed+rearranged)
//   seg2: [3145728, 4194304)    Ws2 -> W2Th/W2Tl (transposed)
//   seg3: [4194304, 5242880)    Wp2 -> Wp2T bf16 (transposed)
// ---------------------------------------------------------------------------
__global__ __launch_bounds__(256) void k_prep(
    const float* __restrict__ x,  u16* __restrict__ xh,   u16* __restrict__ xl,
    const float* __restrict__ Ws1, u16* __restrict__ W1Th, u16* __restrict__ W1Tl,
    const float* __restrict__ Ws2, u16* __restrict__ W2Th, u16* __restrict__ W2Tl,
    const float* __restrict__ Wp2, u16* __restrict__ Wp2T)
{
    int gi = blockIdx.x * 256 + threadIdx.x;
    if (gi < 1572864) {
        int i = gi;
        u16 h, l; splitbf(x[i], h, l);
        xh[i] = h; xl[i] = l;
    } else if (gi < 3145728) {
        int i = gi - 1572864;                 // over 2048*768
        int n = i / 768, k = i - n * 768;
        float v = (n < 1024) ? Ws1[(size_t)k * HID + n]
                             : Ws1[(size_t)(768 + k) * HID + (n - 1024)];
        u16 h, l; splitbf(v, h, l);
        W1Th[i] = h; W1Tl[i] = l;
    } else if (gi < 4194304) {
        int i = gi - 3145728;                 // over 1024*1024
        int n = i >> 10, k = i & 1023;
        u16 h, l; splitbf(Ws2[(size_t)k * HID + n], h, l);
        W2Th[i] = h; W2Tl[i] = l;
    } else {
        int i = gi - 4194304;                 // over 1024*1024
        int n = i >> 10, k = i & 1023;
        Wp2T[i] = f2bf(Wp2[(size_t)k * HID + n]);
    }
}

// ---------------------------------------------------------------------------
// Error-compensated split-bf16 MFMA GEMM: C = (Ah+Al)@(Bh+Bl)^T(stored BT[n][k])
//   = Ah Bh + Al Bh + Ah Bl  (dropped AlBl ~ 2^-18 rel)
// 128x128 tile, BK=32. 1D grid with XCD-aware (bx,by) mapping.
// ---------------------------------------------------------------------------
__global__ __launch_bounds__(256) void k_gemm3bf(
    const u16* __restrict__ Ah, const u16* __restrict__ Al, int lda,
    const u16* __restrict__ BTh, const u16* __restrict__ BTl, int ldb,
    float* __restrict__ C, int ldc,
    int M, int K, int nby, int sft,
    const float* __restrict__ bias, int relu)
{
    int bx, by;
    xcd_map(blockIdx.x, sft, bx, by);
    if (by >= nby) return;
    constexpr int LD = 40;   // bf16 per LDS row (80 B; 2-way bank alias = free)
    __shared__ __align__(16) u16 sm[4 * 128 * LD];
    u16* sAh = sm;
    u16* sAl = sm + 128 * LD;
    u16* sBh = sm + 2 * 128 * LD;
    u16* sBl = sm + 3 * 128 * LD;
    const int tid = threadIdx.x;
    const int bm = by * 128, bn = bx * 128;
    const int wave = tid >> 6, lane = tid & 63;
    const int wr = wave >> 1, wc = wave & 1;
    const int q = lane >> 4, tl = lane & 15;

    f32x4 zero = {0.f, 0.f, 0.f, 0.f};
    f32x4 acc[4][4];
#pragma unroll
    for (int i = 0; i < 4; ++i)
#pragma unroll
        for (int j = 0; j < 4; ++j) acc[i][j] = zero;

    const int r0 = tid >> 2, o0 = (tid & 3) * 8;
    const int r1 = (tid + 256) >> 2, o1 = ((tid + 256) & 3) * 8;
    int am0 = bm + r0; if (am0 >= M) am0 = M - 1;
    int am1 = bm + r1; if (am1 >= M) am1 = M - 1;

    for (int k0 = 0; k0 < K; k0 += 32) {
        *(float4*)(&sAh[r0*LD + o0]) = *(const float4*)(Ah + (size_t)am0 * lda + k0 + o0);
        *(float4*)(&sAh[r1*LD + o1]) = *(const float4*)(Ah + (size_t)am1 * lda + k0 + o1);
        *(float4*)(&sAl[r0*LD + o0]) = *(const float4*)(Al + (size_t)am0 * lda + k0 + o0);
        *(float4*)(&sAl[r1*LD + o1]) = *(const float4*)(Al + (size_t)am1 * lda + k0 + o1);
        *(float4*)(&sBh[r0*LD + o0]) = *(const float4*)(BTh + (size_t)(bn + r0) * ldb + k0 + o0);
        *(float4*)(&sBh[r1*LD + o1]) = *(const float4*)(BTh + (size_t)(bn + r1) * ldb + k0 + o1);
        *(float4*)(&sBl[r0*LD + o0]) = *(const float4*)(BTl + (size_t)(bn + r0) * ldb + k0 + o0);
        *(float4*)(&sBl[r1*LD + o1]) = *(const float4*)(BTl + (size_t)(bn + r1) * ldb + k0 + o1);
        __syncthreads();
        bf16x8 ah[4], al[4], bh[4], bl[4];
#pragma unroll
        for (int t = 0; t < 4; ++t) {
            int arow = (wr*64 + t*16 + tl) * LD + q*8;
            int brow = (wc*64 + t*16 + tl) * LD + q*8;
            ah[t] = *(const bf16x8*)(&sAh[arow]);
            al[t] = *(const bf16x8*)(&sAl[arow]);
            bh[t] = *(const bf16x8*)(&sBh[brow]);
            bl[t] = *(const bf16x8*)(&sBl[brow]);
        }
#pragma unroll
        for (int ti = 0; ti < 4; ++ti)
#pragma unroll
            for (int tj = 0; tj < 4; ++tj) {
                acc[ti][tj] = __builtin_amdgcn_mfma_f32_16x16x32_bf16(ah[ti], bh[tj], acc[ti][tj], 0, 0, 0);
                acc[ti][tj] = __builtin_amdgcn_mfma_f32_16x16x32_bf16(al[ti], bh[tj], acc[ti][tj], 0, 0, 0);
                acc[ti][tj] = __builtin_amdgcn_mfma_f32_16x16x32_bf16(ah[ti], bl[tj], acc[ti][tj], 0, 0, 0);
            }
        __syncthreads();
    }
    // C/D layout: col = lane&15, row = (lane>>4)*4 + reg  [measured m89/m91]
#pragma unroll
    for (int ti = 0; ti < 4; ++ti) {
#pragma unroll
        for (int tj = 0; tj < 4; ++tj) {
            int gcol = bn + wc*64 + tj*16 + tl;
            float bsv = bias ? bias[gcol] : 0.f;
#pragma unroll
            for (int r = 0; r < 4; ++r) {
                int grow = bm + wr*64 + ti*16 + q*4 + r;
                if (grow >= M) continue;
                float v = acc[ti][tj][r] + bsv;
                if (relu) v = fmaxf(v, 0.f);
                C[(size_t)grow * ldc + gcol] = v;
            }
        }
    }
}

// ---------------------------------------------------------------------------
// fp32 SIMT GEMM, 64x64 tile, with A-row gather (rowmap) + dual B pointer.
// ---------------------------------------------------------------------------
__global__ __launch_bounds__(256) void k_sgemm64(
    const float* __restrict__ A, int lda,
    const float* __restrict__ Bm, const float* __restrict__ BmO, int o_row_start, int ldb,
    float* __restrict__ C, int ldc,
    int M, int K, int accum,
    const int* __restrict__ rowmap)
{
    __shared__ float As[8][68];
    __shared__ float Bs[8][68];
    const int tid = threadIdx.x;
    const int tx = tid & 15, ty = tid >> 4;
    const int bm = blockIdx.y * 64, bn = blockIdx.x * 64;
    const float* Bp = (bm >= o_row_start) ? BmO : Bm;

    float acc[4][4];
#pragma unroll
    for (int i = 0; i < 4; ++i)
#pragma unroll
        for (int j = 0; j < 4; ++j) acc[i][j] = 0.f;

    const int ar = tid >> 2, ak = (tid & 3) * 2;
    const int br = tid >> 5, bc = (tid & 31) * 2;
    const int garow = bm + ar;
    const bool aok = garow < M;
    int aphys = 0;
    if (aok) aphys = rowmap ? rowmap[garow] : garow;
    const float* Aptr = A + (size_t)aphys * lda;

    for (int k0 = 0; k0 < K; k0 += 8) {
        float2 av = make_float2(0.f, 0.f);
        if (aok) av = *(const float2*)(Aptr + k0 + ak);
        As[ak][ar] = av.x; As[ak+1][ar] = av.y;
        float2 bv = *(const float2*)(Bp + (size_t)(k0 + br) * ldb + bn + bc);
        Bs[br][bc] = bv.x; Bs[br][bc+1] = bv.y;
        __syncthreads();
#pragma unroll
        for (int kk = 0; kk < 8; ++kk) {
            float a[4], b[4];
#pragma unroll
            for (int i = 0; i < 4; ++i) a[i] = As[kk][ty*4 + i];
#pragma unroll
            for (int j = 0; j < 4; ++j) b[j] = Bs[kk][tx*4 + j];
#pragma unroll
            for (int i = 0; i < 4; ++i)
#pragma unroll
                for (int j = 0; j < 4; ++j) acc[i][j] = fmaf(a[i], b[j], acc[i][j]);
        }
        __syncthreads();
    }
#pragma unroll
    for (int i = 0; i < 4; ++i) {
        int r = bm + ty*4 + i;
        if (r >= M) continue;
        float* crow = C + (size_t)r * ldc + bn + tx*4;
        float4 v = make_float4(acc[i][0], acc[i][1], acc[i][2], acc[i][3]);
        if (accum) {
            float4 o = *(const float4*)crow;
            v.x += o.x; v.y += o.y; v.z += o.z; v.w += o.w;
        }
        *(float4*)crow = v;
    }
}

// h1s = relu(XALL[b,start,0:1024] + XALL[b,end-1,1024:2048] + wtabS[w-1]) -> split bf16
__global__ __launch_bounds__(256) void k_build_h1s(
    const float* __restrict__ XALL, const float* __restrict__ wtabS,
    u16* __restrict__ h1h, u16* __restrict__ h1l)
{
    int r = blockIdx.x;                 // 0..16159
    int b = r / NSPAN, s = r - b * NSPAN;
    int st, en, w; span_decode(s, st, en, w);
    const float4* xs = (const float4*)(XALL + (size_t)(b*SEQ + st) * 2048);
    const float4* xe = (const float4*)(XALL + (size_t)(b*SEQ + en - 1) * 2048 + 1024);
    const float4* wt = (const float4*)(wtabS + (size_t)(w-1) * HID);
    int t = threadIdx.x;
    float4 a = xs[t], bz = xe[t], c = wt[t];
    float v0 = fmaxf(a.x + bz.x + c.x, 0.f);
    float v1 = fmaxf(a.y + bz.y + c.y, 0.f);
    float v2 = fmaxf(a.z + bz.z + c.z, 0.f);
    float v3 = fmaxf(a.w + bz.w + c.w, 0.f);
    u16 h0,l0,h1,l1,h2,l2,h3,l3;
    splitbf(v0,h0,l0); splitbf(v1,h1,l1); splitbf(v2,h2,l2); splitbf(v3,h3,l3);
    size_t base = (size_t)r * HID + t * 4;
    *(uint2*)(h1h + base) = make_uint2((u32)h0 | ((u32)h1 << 16), (u32)h2 | ((u32)h3 << 16));
    *(uint2*)(h1l + base) = make_uint2((u32)l0 | ((u32)l1 << 16), (u32)l2 | ((u32)l3 << 16));
}

// span layer3 + softmax -> out[r*3 + c]. One wave per row, 4 rows/block.
__global__ __launch_bounds__(256) void k_span_l3(
    const float* __restrict__ h2s, const float* __restrict__ Ws3,
    const float* __restrict__ bs3, float* __restrict__ out)
{
    int wave = threadIdx.x >> 6, lane = threadIdx.x & 63;
    int r = blockIdx.x * 4 + wave;      // 16160 = 4040*4 exact
    const float* hr = h2s + (size_t)r * HID;
    float s0 = 0.f, s1 = 0.f, s2 = 0.f;
    for (int h = lane; h < HID; h += 64) {
        float v = hr[h];
        const float* wrow = Ws3 + h * 3;
        s0 = fmaf(v, wrow[0], s0);
        s1 = fmaf(v, wrow[1], s1);
        s2 = fmaf(v, wrow[2], s2);
    }
#pragma unroll
    for (int off = 32; off > 0; off >>= 1) {
        s0 += __shfl_down(s0, off, 64);
        s1 += __shfl_down(s1, off, 64);
        s2 += __shfl_down(s2, off, 64);
    }
    if (lane == 0) {
        s0 += bs3[0]; s1 += bs3[1]; s2 += bs3[2];
        float m = fmaxf(s0, fmaxf(s1, s2));
        float e0 = expf(s0 - m), e1 = expf(s1 - m), e2 = expf(s2 - m);
        float inv = 1.f / (e0 + e1 + e2);
        float* o = out + (size_t)r * 3;
        o[0] = e0 * inv; o[1] = e1 * inv; o[2] = e2 * inv;
    }
}

// top-64 (descending, ties -> lower index). 256 threads: 4-wave scan + LDS combine.
__global__ __launch_bounds__(256) void k_topk(
    const float* __restrict__ sp, int* __restrict__ t_idx, int* __restrict__ o_idx)
{
    int b = blockIdx.x >> 1;
    int head = 1 + (blockIdx.x & 1);
    int* outp = (head == 1 ? t_idx : o_idx) + b * NZ;
    __shared__ float sc[NSPAN];
    __shared__ float swv[4];
    __shared__ int   swi[4];
    int tid = threadIdx.x, lane = tid & 63, wv = tid >> 6;
    for (int s = tid; s < NSPAN; s += 256)
        sc[s] = sp[((size_t)b * NSPAN + s) * 3 + head];
    __syncthreads();
    for (int it = 0; it < NZ; ++it) {
        float bv = -1e30f; int bi = 1 << 29;
        for (int s = tid; s < NSPAN; s += 256) {
            float v = sc[s];
            if (v > bv || (v == bv && s < bi)) { bv = v; bi = s; }
        }
#pragma unroll
        for (int off = 32; off > 0; off >>= 1) {
            float ov = __shfl_down(bv, off, 64);
            int   oi = __shfl_down(bi, off, 64);
            if (ov > bv || (ov == bv && oi < bi)) { bv = ov; bi = oi; }
        }
        if (lane == 0) { swv[wv] = bv; swi[wv] = bi; }
        __syncthreads();
        if (tid == 0) {
            float fv = swv[0]; int fi = swi[0];
#pragma unroll
            for (int wvi = 1; wvi < 4; ++wvi) {
                float ov = swv[wvi]; int oi = swi[wvi];
                if (ov > fv || (ov == fv && oi < fi)) { fv = ov; fi = oi; }
            }
            if (fi < 0 || fi >= NSPAN) fi = 0;
            outp[it] = fi; sc[fi] = -1e30f;
        }
        __syncthreads();
    }
}

// token rowmaps for the gathered T/O GEMMs.
__global__ void k_toks(const int* __restrict__ t_idx, const int* __restrict__ o_idx,
                       int* __restrict__ toks)
{
    int r = blockIdx.x * 256 + threadIdx.x;
    if (r >= 1024) return;
    int b, sidx;
    if (r < 512) { b = r >> 6; sidx = t_idx[r]; }
    else { int q = r - 512; b = q >> 6; sidx = o_idx[q]; }
    int st, en, w; span_decode(sidx, st, en, w);
    toks[r] = b * SEQ + st;
    toks[1024 + r] = b * SEQ + en - 1;
}

// h1_pair[row] = relu(T[b,i] + O[b,j] + wtabPt + wtabPo + dtab) -> bf16
__global__ __launch_bounds__(256) void k_build_h1p(
    const float* __restrict__ TO, const int* __restrict__ t_idx, const int* __restrict__ o_idx,
    const float* __restrict__ wtabPt, const float* __restrict__ wtabPo,
    const float* __restrict__ dtab, u16* __restrict__ h1p)
{
    int row = blockIdx.x;               // b*4096 + i*64 + j
    int b = row >> 12, i = (row >> 6) & 63, j = row & 63;
    int ts = t_idx[b*64 + i], os = o_idx[b*64 + j];
    int ta, tb, wt, oc, od, wo;
    span_decode(ts, ta, tb, wt);
    span_decode(os, oc, od, wo);
    int d1 = tb - oc; d1 = d1 < 0 ? -d1 : d1;
    int d2 = ta - od; d2 = d2 < 0 ? -d2 : d2;
    int dist = d1 < d2 ? d1 : d2;
    int db = dbucket(dist);
    const float4* T4 = (const float4*)(TO + (size_t)(b*64 + i) * HID);
    const float4* O4 = (const float4*)(TO + (size_t)(512 + b*64 + j) * HID);
    const float4* P4 = (const float4*)(wtabPt + (size_t)(wt-1) * HID);
    const float4* Q4 = (const float4*)(wtabPo + (size_t)(wo-1) * HID);
    const float4* D4 = (const float4*)(dtab + (size_t)db * HID);
    int t = threadIdx.x;
    float4 a = T4[t], c = O4[t], p = P4[t], q = Q4[t], d = D4[t];
    float vx = fmaxf(a.x + c.x + p.x + q.x + d.x, 0.f);
    float vy = fmaxf(a.y + c.y + p.y + q.y + d.y, 0.f);
    float vz = fmaxf(a.z + c.z + p.z + q.z + d.z, 0.f);
    float vw = fmaxf(a.w + c.w + p.w + q.w + d.w, 0.f);
    u32 p0 = (u32)f2bf(vx) | ((u32)f2bf(vy) << 16);
    u32 p1 = (u32)f2bf(vz) | ((u32)f2bf(vw) << 16);
    *(uint2*)(h1p + (size_t)row * HID + t * 4) = make_uint2(p0, p1);
}

// pair layer2: h2p = relu(h1p @ Wp2 + bp2), single-pass bf16 MFMA, 128x128 tile.
// 1D grid with XCD-aware mapping (sft=3, nby=256).
__global__ __launch_bounds__(256) void k_pair_l2(
    const u16* __restrict__ Abf, const u16* __restrict__ BT,
    const float* __restrict__ bias, u16* __restrict__ Cbf)
{
    int bx, by;
    xcd_map(blockIdx.x, 3, bx, by);
    constexpr int LD = 40;
    __shared__ __align__(16) u16 As[128 * LD];
    __shared__ __align__(16) u16 Bs[128 * LD];
    const int tid = threadIdx.x;
    const int bm = by * 128, bn = bx * 128;
    const int wave = tid >> 6, lane = tid & 63;
    const int wr = wave >> 1, wc = wave & 1;
    const int q = lane >> 4, tl = lane & 15;

    f32x4 zero = {0.f, 0.f, 0.f, 0.f};
    f32x4 acc[4][4];
#pragma unroll
    for (int i = 0; i < 4; ++i)
#pragma unroll
        for (int j = 0; j < 4; ++j) acc[i][j] = zero;

    const int r0 = tid >> 2, o0 = (tid & 3) * 8;
    const int r1 = (tid + 256) >> 2, o1 = ((tid + 256) & 3) * 8;

    for (int k0 = 0; k0 < 1024; k0 += 32) {
        *(float4*)(&As[r0*LD + o0]) = *(const float4*)(Abf + (size_t)(bm + r0) * 1024 + k0 + o0);
        *(float4*)(&As[r1*LD + o1]) = *(const float4*)(Abf + (size_t)(bm + r1) * 1024 + k0 + o1);
        *(float4*)(&Bs[r0*LD + o0]) = *(const float4*)(BT + (size_t)(bn + r0) * 1024 + k0 + o0);
        *(float4*)(&Bs[r1*LD + o1]) = *(const float4*)(BT + (size_t)(bn + r1) * 1024 + k0 + o1);
        __syncthreads();
        bf16x8 af[4], bf[4];
#pragma unroll
        for (int t = 0; t < 4; ++t) {
            af[t] = *(const bf16x8*)(&As[(wr*64 + t*16 + tl) * LD + q*8]);
            bf[t] = *(const bf16x8*)(&Bs[(wc*64 + t*16 + tl) * LD + q*8]);
        }
#pragma unroll
        for (int ti = 0; ti < 4; ++ti)
#pragma unroll
            for (int tj = 0; tj < 4; ++tj)
                acc[ti][tj] = __builtin_amdgcn_mfma_f32_16x16x32_bf16(af[ti], bf[tj], acc[ti][tj], 0, 0, 0);
        __syncthreads();
    }
#pragma unroll
    for (int ti = 0; ti < 4; ++ti) {
#pragma unroll
        for (int tj = 0; tj < 4; ++tj) {
            int gcol = bn + wc*64 + tj*16 + tl;
            float bsv = bias[gcol];
#pragma unroll
            for (int r = 0; r < 4; ++r) {
                int grow = bm + wr*64 + ti*16 + q*4 + r;
                float v = acc[ti][tj][r] + bsv;
                v = fmaxf(v, 0.f);
                Cbf[(size_t)grow * 1024 + gcol] = f2bf(v);
            }
        }
    }
}

// pair layer3 + softmax -> out[48480 + r*4 + c]
__global__ __launch_bounds__(256) void k_pair_l3(
    const u16* __restrict__ h2p, const float* __restrict__ Wp3,
    const float* __restrict__ bp3, float* __restrict__ out)
{
    int wave = threadIdx.x >> 6, lane = threadIdx.x & 63;
    int r = blockIdx.x * 4 + wave;      // 32768 = 8192*4 exact
    const u16* hr = h2p + (size_t)r * HID;
    float s0 = 0.f, s1 = 0.f, s2 = 0.f, s3 = 0.f;
    for (int h = lane; h < HID; h += 64) {
        float v = bf2f(hr[h]);
        const float4 w = *(const float4*)(Wp3 + h * 4);
        s0 = fmaf(v, w.x, s0); s1 = fmaf(v, w.y, s1);
        s2 = fmaf(v, w.z, s2); s3 = fmaf(v, w.w, s3);
    }
#pragma unroll
    for (int off = 32; off > 0; off >>= 1) {
        s0 += __shfl_down(s0, off, 64);
        s1 += __shfl_down(s1, off, 64);
        s2 += __shfl_down(s2, off, 64);
        s3 += __shfl_down(s3, off, 64);
    }
    if (lane == 0) {
        s0 += bp3[0]; s1 += bp3[1]; s2 += bp3[2]; s3 += bp3[3];
        float m = fmaxf(fmaxf(s0, s1), fmaxf(s2, s3));
        float e0 = expf(s0 - m), e1 = expf(s1 - m), e2 = expf(s2 - m), e3 = expf(s3 - m);
        float inv = 1.f / (e0 + e1 + e2 + e3);
        float* o = out + (size_t)r * 4;
        o[0] = e0 * inv; o[1] = e1 * inv; o[2] = e2 * inv; o[3] = e3 * inv;
    }
}

extern "C" void kernel_launch(void* const* d_in, const int* in_sizes, int n_in,
                              void* d_out, int out_size, void* d_ws, size_t ws_size,
                              hipStream_t stream)
{
    const float* x    = (const float*)d_in[0];
    const float* wemb = (const float*)d_in[1];
    const float* demb = (const float*)d_in[2];
    const float* Ws1  = (const float*)d_in[3];
    const float* bs1  = (const float*)d_in[4];
    const float* Ws2  = (const float*)d_in[5];
    const float* bs2  = (const float*)d_in[6];
    const float* Ws3  = (const float*)d_in[7];
    const float* bs3  = (const float*)d_in[8];
    const float* Wp1  = (const float*)d_in[9];
    const float* bp1  = (const float*)d_in[10];
    const float* Wp2  = (const float*)d_in[11];
    const float* bp2  = (const float*)d_in[12];
    const float* Wp3  = (const float*)d_in[13];
    const float* bp3  = (const float*)d_in[14];
    float* out = (float*)d_out;
    char* ws = (char*)d_ws;

    // ---- workspace arena, lifetime-aliased (peak ~142 MB) ----
    const size_t RSZ = (size_t)32768 * HID * 2;   // 64 MiB
    size_t off = 0;
    auto alloc = [&](size_t bytes) -> void* {
        void* p = ws + off;
        off += (bytes + 255) & ~(size_t)255;
        return p;
    };
    char* R1 = (char*)alloc(RSZ);
    char* R2 = (char*)alloc(RSZ);
    u16*   h1h  = (u16*)R1;                              // 33.1 MB
    u16*   h1l  = (u16*)(R1 + (size_t)16160 * HID * 2);  // 33.1 MB
    u16*   h2p  = (u16*)R1;                              // 64 MiB (after h1s dead)
    float* XALL = (float*)R2;                            // 16 MiB
    u16*   xh   = (u16*)(R2 + (16u << 20));              // 3 MB
    u16*   xl   = (u16*)(R2 + (19u << 20));
    u16*   W1Th = (u16*)(R2 + (22u << 20));
    u16*   W1Tl = (u16*)(R2 + (25u << 20));
    float* h2s  = (float*)R2;                            // 63.1 MB (after XALL/splits dead)
    u16*   h1p  = (u16*)R2;                              // 64 MiB (after h2s dead)
    float* TO     = (float*)alloc((size_t)1024 * HID * 4);
    u16*   W2Th   = (u16*)alloc((size_t)1024 * 1024 * 2);
    u16*   W2Tl   = (u16*)alloc((size_t)1024 * 1024 * 2);
    u16*   Wp2T   = (u16*)alloc((size_t)1024 * 1024 * 2);
    float* wtabS  = (float*)alloc(8 * HID * 4);
    float* wtabPt = (float*)alloc(8 * HID * 4);
    float* wtabPo = (float*)alloc(8 * HID * 4);
    float* dtab   = (float*)alloc(14 * HID * 4);
    int*   t_idx  = (int*)alloc(BATCH * NZ * 4);
    int*   o_idx  = (int*)alloc(BATCH * NZ * 4);
    int*   toks   = (int*)alloc(2048 * 4);
    (void)ws_size; (void)in_sizes; (void)n_in; (void)out_size;

    // prep: tables + all bf16 splits/transposes (fused)
    k_tables<<<dim3(4, 38), 256, 0, stream>>>(wemb, demb, Ws1, bs1, Wp1, bp1,
                                              wtabS, wtabPt, wtabPo, dtab);
    k_prep<<<20480, 256, 0, stream>>>(x, xh, xl, Ws1, W1Th, W1Tl,
                                      Ws2, W2Th, W2Tl, Wp2, Wp2T);

    // layer-1 factorization: XALL = x2d @ [Ws1_top | Ws1_mid]  (3-pass split-bf16 MFMA)
    // nbx=16 (sft=4), nby=16 -> grid ceil(16/8)*8*16 = 256
    k_gemm3bf<<<256, 256, 0, stream>>>(xh, xl, 768, W1Th, W1Tl, 768,
                                       XALL, 2048, 2048, 768, 16, 4, nullptr, 0);
    k_build_h1s<<<16160, 256, 0, stream>>>(XALL, wtabS, h1h, h1l);
    // span layer2: 3-pass split-bf16 MFMA. nbx=8 (sft=3), nby=127 -> grid 16*64=1024
    k_gemm3bf<<<1024, 256, 0, stream>>>(h1h, h1l, HID, W2Th, W2Tl, HID,
                                        h2s, HID, 16160, HID, 127, 3, bs2, 1);
    k_span_l3<<<4040, 256, 0, stream>>>(h2s, Ws3, bs3, out);
    k_topk<<<16, 256, 0, stream>>>(out, t_idx, o_idx);
    k_toks<<<4, 256, 0, stream>>>(t_idx, o_idx, toks);
    // gathered pair layer-1 (fp32)
    k_sgemm64<<<dim3(16, 16), 256, 0, stream>>>(x, DIM, Wp1, Wp1 + (size_t)1561 * HID, 512, HID,
                                                TO, HID, 1024, DIM, 0, toks);
    k_sgemm64<<<dim3(16, 16), 256, 0, stream>>>(x, DIM, Wp1 + (size_t)768 * HID, Wp1 + (size_t)2329 * HID, 512, HID,
                                                TO, HID, 1024, DIM, 1, toks + 1024);
    k_build_h1p<<<32768, 256, 0, stream>>>(TO, t_idx, o_idx, wtabPt, wtabPo, dtab, h1p);
    // pair layer2: single-pass bf16 MFMA, XCD-swizzled (nby=256 -> grid 2048)
    k_pair_l2<<<2048, 256, 0, stream>>>(h1p, Wp2T, bp2, h2p);
    k_pair_l3<<<8192, 256, 0, stream>>>(h2p, Wp3, bp3, out + 48480);
}

// Round 5
// 692.334 us; speedup vs baseline: 1.8880x; 1.0629x over previous
//
#include <hip/hip_runtime.h>
#include <cstdint>
#include <cstddef>

#define BATCH 8
#define SEQ   256
#define DIM   768
#define NSPAN 2020
#define HID   1024
#define NZ    64

typedef unsigned short u16;
typedef unsigned int   u32;

typedef __bf16 bf16x8 __attribute__((ext_vector_type(8)));
typedef float  f32x4  __attribute__((ext_vector_type(4)));

__device__ __forceinline__ u16 f2bf(float f) {
    union { float f; u32 u; } x; x.f = f;
    u32 r = x.u + 0x7fffu + ((x.u >> 16) & 1u);
    return (u16)(r >> 16);
}
__device__ __forceinline__ float bf2f(u16 b) {
    union { u32 u; float f; } x; x.u = ((u32)b) << 16;
    return x.f;
}
// split v = hi + lo (both bf16); residual v-hi is exact in fp32
__device__ __forceinline__ void splitbf(float v, u16& h, u16& l) {
    h = f2bf(v);
    l = f2bf(v - bf2f(h));
}

// async global->LDS, 16B per lane; lane i lands at ldsbase + i*16 [m97/m104]
__device__ __forceinline__ void gld_lds16(const void* g, void* l) {
    __builtin_amdgcn_global_load_lds(
        (const __attribute__((address_space(1))) unsigned int*)g,
        (__attribute__((address_space(3))) unsigned int*)l, 16, 0, 0);
}

// span s -> (start, end, width); spans enumerated width-major: w=1..8, starts 0..L-w
__device__ __forceinline__ void span_decode(int s, int& start, int& end, int& w) {
    int off = 0;
#pragma unroll
    for (int wi = 1; wi <= 8; ++wi) {
        int cnt = SEQ - wi + 1;
        if (s < off + cnt) { w = wi; start = s - off; end = start + wi; return; }
        off += cnt;
    }
    w = 8; start = 0; end = 8;
}

// searchsorted(BUCKET_BINS, d, 'right') - 1
__device__ __forceinline__ int dbucket(int d) {
    int b = 0;
    b += (d >= 1);  b += (d >= 2);  b += (d >= 3);  b += (d >= 4);
    b += (d >= 5);  b += (d >= 7);  b += (d >= 8);  b += (d >= 15);
    b += (d >= 16); b += (d >= 31); b += (d >= 32); b += (d >= 63);
    b += (d >= 64);
    return b;
}

// XCD-aware deswizzle: (linear id) % 8 == by % 8 -> all column-blocks of one
// A-row-tile land on the SAME XCD (id%8 round-robin). sft = log2(nbx).
__device__ __forceinline__ void xcd_map(int L, int sft, int& bx, int& by) {
    int grp = L >> (3 + sft);
    int rem = L & ((1 << (3 + sft)) - 1);
    bx = rem >> 3;
    by = (grp << 3) | (rem & 7);
}

// ---------------------------------------------------------------------------
// Tiny per-bucket tables (width/dist embeddings only hit 14 rows).
// ---------------------------------------------------------------------------
__global__ __launch_bounds__(256) void k_tables(
    const float* __restrict__ wemb, const float* __restrict__ demb,
    const float* __restrict__ Ws1, const float* __restrict__ bs1,
    const float* __restrict__ Wp1, const float* __restrict__ bp1,
    float* __restrict__ wtabS, float* __restrict__ wtabPt,
    float* __restrict__ wtabPo, float* __restrict__ dtab)
{
    int h = blockIdx.x * 256 + threadIdx.x;   // 0..1023
    int row = blockIdx.y;                     // 0..37
    const int wb[8] = {1,2,3,4,5,5,6,7};      // width 1..8 -> bucket
    if (row < 8) {
        int bk = wb[row];
        float acc = bs1[h];
        for (int j = 0; j < 25; ++j) acc = fmaf(wemb[bk*25+j], Ws1[(size_t)(1536+j)*HID + h], acc);
        wtabS[row*HID + h] = acc;
    } else if (row < 16) {
        int bk = wb[row-8];
        float acc = 0.f;
        for (int j = 0; j < 25; ++j) acc = fmaf(wemb[bk*25+j], Wp1[(size_t)(1536+j)*HID + h], acc);
        wtabPt[(row-8)*HID + h] = acc;
    } else if (row < 24) {
        int bk = wb[row-16];
        float acc = 0.f;
        for (int j = 0; j < 25; ++j) acc = fmaf(wemb[bk*25+j], Wp1[(size_t)(3097+j)*HID + h], acc);
        wtabPo[(row-16)*HID + h] = acc;
    } else {
        int t = row - 24;                     // 0..13
        float acc = bp1[h];
        for (int j = 0; j < 25; ++j) acc = fmaf(demb[t*25+j], Wp1[(size_t)(3122+j)*HID + h], acc);
        dtab[t*HID + h] = acc;
    }
}

// ---------------------------------------------------------------------------
// Fused one-time prep (segmented flat index; boundaries multiple of 256).
// ---------------------------------------------------------------------------
__global__ __launch_bounds__(256) void k_prep(
    const float* __restrict__ x,  u16* __restrict__ xh,   u16* __restrict__ xl,
    const float* __restrict__ Ws1, u16* __restrict__ W1Th, u16* __restrict__ W1Tl,
    const float* __restrict__ Ws2, u16* __restrict__ W2Th, u16* __restrict__ W2Tl,
    const float* __restrict__ Wp2, u16* __restrict__ Wp2T)
{
    int gi = blockIdx.x * 256 + threadIdx.x;
    if (gi < 1572864) {
        int i = gi;
        u16 h, l; splitbf(x[i], h, l);
        xh[i] = h; xl[i] = l;
    } else if (gi < 3145728) {
        int i = gi - 1572864;                 // over 2048*768
        int n = i / 768, k = i - n * 768;
        float v = (n < 1024) ? Ws1[(size_t)k * HID + n]
                             : Ws1[(size_t)(768 + k) * HID + (n - 1024)];
        u16 h, l; splitbf(v, h, l);
        W1Th[i] = h; W1Tl[i] = l;
    } else if (gi < 4194304) {
        int i = gi - 3145728;                 // over 1024*1024
        int n = i >> 10, k = i & 1023;
        u16 h, l; splitbf(Ws2[(size_t)k * HID + n], h, l);
        W2Th[i] = h; W2Tl[i] = l;
    } else {
        int i = gi - 4194304;                 // over 1024*1024
        int n = i >> 10, k = i & 1023;
        Wp2T[i] = f2bf(Wp2[(size_t)k * HID + n]);
    }
}

// ---------------------------------------------------------------------------
// Error-compensated split-bf16 MFMA GEMM: C = AhBh + AlBh + AhBl
// 128x128 tile, BK=32, global_load_lds width-16 staging, XCD-aware grid.
// LDS layout unpadded [row][32 u16] (64B rows) -- required by global_load_lds
// lane->base+lane*16 mapping [m104]; 8-way bank aliasing hits the 8-cycle
// floor anyway for b128 x 64 lanes (m97 ran this exact pattern at 874 TF).
// ---------------------------------------------------------------------------
__global__ __launch_bounds__(256) void k_gemm3bf(
    const u16* __restrict__ Ah, const u16* __restrict__ Al, int lda,
    const u16* __restrict__ BTh, const u16* __restrict__ BTl, int ldb,
    float* __restrict__ C, int ldc,
    int M, int K, int nby, int sft,
    const float* __restrict__ bias, int relu)
{
    int bx, by;
    xcd_map(blockIdx.x, sft, bx, by);
    if (by >= nby) return;
    __shared__ __align__(16) u16 sm[4 * 128 * 32];     // 32 KiB
    u16* sAh = sm;
    u16* sAl = sm + 4096;
    u16* sBh = sm + 8192;
    u16* sBl = sm + 12288;
    const int tid = threadIdx.x;
    const int bm = by * 128, bn = bx * 128;
    const int wave = tid >> 6, lane = tid & 63;
    const int wr = wave >> 1, wc = wave & 1;
    const int q = lane >> 4, tl = lane & 15;

    f32x4 zero = {0.f, 0.f, 0.f, 0.f};
    f32x4 acc[4][4];
#pragma unroll
    for (int i = 0; i < 4; ++i)
#pragma unroll
        for (int j = 0; j < 4; ++j) acc[i][j] = zero;

    // staging: per wave, 2 chunks of 16 rows per array (lane -> row srow, col scol)
    const int srow = lane >> 2;
    const int scol = (lane & 3) * 8;
    int ra0 = bm + wave * 32 + srow;      if (ra0 >= M) ra0 = M - 1;
    int ra1 = bm + wave * 32 + 16 + srow; if (ra1 >= M) ra1 = M - 1;
    const int rb0 = bn + wave * 32 + srow;
    const int rb1 = bn + wave * 32 + 16 + srow;
    u16* dA0 = sAh + wave * 1024;  u16* dA1 = dA0 + 512;
    u16* dL0 = sAl + wave * 1024;  u16* dL1 = dL0 + 512;
    u16* dB0 = sBh + wave * 1024;  u16* dB1 = dB0 + 512;
    u16* dC0 = sBl + wave * 1024;  u16* dC1 = dC0 + 512;
    const u16* gA0 = Ah  + (size_t)ra0 * lda + scol;
    const u16* gA1 = Ah  + (size_t)ra1 * lda + scol;
    const u16* gL0 = Al  + (size_t)ra0 * lda + scol;
    const u16* gL1 = Al  + (size_t)ra1 * lda + scol;
    const u16* gB0 = BTh + (size_t)rb0 * ldb + scol;
    const u16* gB1 = BTh + (size_t)rb1 * ldb + scol;
    const u16* gC0 = BTl + (size_t)rb0 * ldb + scol;
    const u16* gC1 = BTl + (size_t)rb1 * ldb + scol;

    for (int k0 = 0; k0 < K; k0 += 32) {
        gld_lds16(gA0 + k0, dA0);
        gld_lds16(gA1 + k0, dA1);
        gld_lds16(gL0 + k0, dL0);
        gld_lds16(gL1 + k0, dL1);
        gld_lds16(gB0 + k0, dB0);
        gld_lds16(gB1 + k0, dB1);
        gld_lds16(gC0 + k0, dC0);
        gld_lds16(gC1 + k0, dC1);
        __syncthreads();     // drains vmcnt before ds_read (compiler-enforced)
        bf16x8 ah[4], al[4], bh[4], bl[4];
#pragma unroll
        for (int t = 0; t < 4; ++t) {
            int arow = (wr*64 + t*16 + tl) * 32 + q*8;
            int brow = (wc*64 + t*16 + tl) * 32 + q*8;
            ah[t] = *(const bf16x8*)(&sAh[arow]);
            al[t] = *(const bf16x8*)(&sAl[arow]);
            bh[t] = *(const bf16x8*)(&sBh[brow]);
            bl[t] = *(const bf16x8*)(&sBl[brow]);
        }
#pragma unroll
        for (int ti = 0; ti < 4; ++ti)
#pragma unroll
            for (int tj = 0; tj < 4; ++tj) {
                acc[ti][tj] = __builtin_amdgcn_mfma_f32_16x16x32_bf16(ah[ti], bh[tj], acc[ti][tj], 0, 0, 0);
                acc[ti][tj] = __builtin_amdgcn_mfma_f32_16x16x32_bf16(al[ti], bh[tj], acc[ti][tj], 0, 0, 0);
                acc[ti][tj] = __builtin_amdgcn_mfma_f32_16x16x32_bf16(ah[ti], bl[tj], acc[ti][tj], 0, 0, 0);
            }
        __syncthreads();
    }
    // C/D layout: col = lane&15, row = (lane>>4)*4 + reg  [measured m89/m91]
#pragma unroll
    for (int ti = 0; ti < 4; ++ti) {
#pragma unroll
        for (int tj = 0; tj < 4; ++tj) {
            int gcol = bn + wc*64 + tj*16 + tl;
            float bsv = bias ? bias[gcol] : 0.f;
#pragma unroll
            for (int r = 0; r < 4; ++r) {
                int grow = bm + wr*64 + ti*16 + q*4 + r;
                if (grow >= M) continue;
                float v = acc[ti][tj][r] + bsv;
                if (relu) v = fmaxf(v, 0.f);
                C[(size_t)grow * ldc + gcol] = v;
            }
        }
    }
}

// ---------------------------------------------------------------------------
// Gathered pair layer-1 (fp32, 64x64 tile): TO[r] = x[toks[r]]@B1 + x[toks[1024+r]]@B2
// B1/B2 selected by T/O half (row tiles are 64-aligned; 512 boundary safe).
// ---------------------------------------------------------------------------
__global__ __launch_bounds__(256) void k_pairL1(
    const float* __restrict__ x, const float* __restrict__ Wp1,
    float* __restrict__ TO, const int* __restrict__ toks)
{
    __shared__ float As[8][68];
    __shared__ float Bs[8][68];
    const int tid = threadIdx.x;
    const int tx = tid & 15, ty = tid >> 4;
    const int bm = blockIdx.y * 64, bn = blockIdx.x * 64;

    float acc[4][4];
#pragma unroll
    for (int i = 0; i < 4; ++i)
#pragma unroll
        for (int j = 0; j < 4; ++j) acc[i][j] = 0.f;

    const int ar = tid >> 2, ak = (tid & 3) * 2;
    const int br = tid >> 5, bc = (tid & 31) * 2;
    const int garow = bm + ar;
    const bool isO = bm >= 512;

#pragma unroll
    for (int p = 0; p < 2; ++p) {
        int aphys = toks[garow + p * 1024];
        const float* Aptr = x + (size_t)aphys * DIM;
        const float* Bp = Wp1 + (size_t)(isO ? (p ? 2329 : 1561) : (p ? 768 : 0)) * HID;
        for (int k0 = 0; k0 < DIM; k0 += 8) {
            float2 av = *(const float2*)(Aptr + k0 + ak);
            As[ak][ar] = av.x; As[ak+1][ar] = av.y;
            float2 bv = *(const float2*)(Bp + (size_t)(k0 + br) * HID + bn + bc);
            Bs[br][bc] = bv.x; Bs[br][bc+1] = bv.y;
            __syncthreads();
#pragma unroll
            for (int kk = 0; kk < 8; ++kk) {
                float a[4], b[4];
#pragma unroll
                for (int i = 0; i < 4; ++i) a[i] = As[kk][ty*4 + i];
#pragma unroll
                for (int j = 0; j < 4; ++j) b[j] = Bs[kk][tx*4 + j];
#pragma unroll
                for (int i = 0; i < 4; ++i)
#pragma unroll
                    for (int j = 0; j < 4; ++j) acc[i][j] = fmaf(a[i], b[j], acc[i][j]);
            }
            __syncthreads();
        }
    }
#pragma unroll
    for (int i = 0; i < 4; ++i) {
        int r = bm + ty*4 + i;
        float* crow = TO + (size_t)r * HID + bn + tx*4;
        *(float4*)crow = make_float4(acc[i][0], acc[i][1], acc[i][2], acc[i][3]);
    }
}

// h1s = relu(XALL[b,start,0:1024] + XALL[b,end-1,1024:2048] + wtabS[w-1]) -> split bf16
__global__ __launch_bounds__(256) void k_build_h1s(
    const float* __restrict__ XALL, const float* __restrict__ wtabS,
    u16* __restrict__ h1h, u16* __restrict__ h1l)
{
    int r = blockIdx.x;                 // 0..16159
    int b = r / NSPAN, s = r - b * NSPAN;
    int st, en, w; span_decode(s, st, en, w);
    const float4* xs = (const float4*)(XALL + (size_t)(b*SEQ + st) * 2048);
    const float4* xe = (const float4*)(XALL + (size_t)(b*SEQ + en - 1) * 2048 + 1024);
    const float4* wt = (const float4*)(wtabS + (size_t)(w-1) * HID);
    int t = threadIdx.x;
    float4 a = xs[t], bz = xe[t], c = wt[t];
    float v0 = fmaxf(a.x + bz.x + c.x, 0.f);
    float v1 = fmaxf(a.y + bz.y + c.y, 0.f);
    float v2 = fmaxf(a.z + bz.z + c.z, 0.f);
    float v3 = fmaxf(a.w + bz.w + c.w, 0.f);
    u16 h0,l0,h1,l1,h2,l2,h3,l3;
    splitbf(v0,h0,l0); splitbf(v1,h1,l1); splitbf(v2,h2,l2); splitbf(v3,h3,l3);
    size_t base = (size_t)r * HID + t * 4;
    *(uint2*)(h1h + base) = make_uint2((u32)h0 | ((u32)h1 << 16), (u32)h2 | ((u32)h3 << 16));
    *(uint2*)(h1l + base) = make_uint2((u32)l0 | ((u32)l1 << 16), (u32)l2 | ((u32)l3 << 16));
}

// span layer3 + softmax -> out[r*3 + c]. One wave per row, 4 rows/block.
__global__ __launch_bounds__(256) void k_span_l3(
    const float* __restrict__ h2s, const float* __restrict__ Ws3,
    const float* __restrict__ bs3, float* __restrict__ out)
{
    int wave = threadIdx.x >> 6, lane = threadIdx.x & 63;
    int r = blockIdx.x * 4 + wave;      // 16160 = 4040*4 exact
    const float* hr = h2s + (size_t)r * HID;
    float s0 = 0.f, s1 = 0.f, s2 = 0.f;
    for (int h = lane; h < HID; h += 64) {
        float v = hr[h];
        const float* wrow = Ws3 + h * 3;
        s0 = fmaf(v, wrow[0], s0);
        s1 = fmaf(v, wrow[1], s1);
        s2 = fmaf(v, wrow[2], s2);
    }
#pragma unroll
    for (int off = 32; off > 0; off >>= 1) {
        s0 += __shfl_down(s0, off, 64);
        s1 += __shfl_down(s1, off, 64);
        s2 += __shfl_down(s2, off, 64);
    }
    if (lane == 0) {
        s0 += bs3[0]; s1 += bs3[1]; s2 += bs3[2];
        float m = fmaxf(s0, fmaxf(s1, s2));
        float e0 = expf(s0 - m), e1 = expf(s1 - m), e2 = expf(s2 - m);
        float inv = 1.f / (e0 + e1 + e2);
        float* o = out + (size_t)r * 3;
        o[0] = e0 * inv; o[1] = e1 * inv; o[2] = e2 * inv;
    }
}

// top-64 (descending, ties -> lower index) + fused token-rowmap build.
__global__ __launch_bounds__(256) void k_topk(
    const float* __restrict__ sp, int* __restrict__ t_idx, int* __restrict__ o_idx,
    int* __restrict__ toks)
{
    int b = blockIdx.x >> 1;
    int head = 1 + (blockIdx.x & 1);
    int* outp = (head == 1 ? t_idx : o_idx) + b * NZ;
    __shared__ float sc[NSPAN];
    __shared__ float swv[4];
    __shared__ int   swi[4];
    __shared__ int   sel[NZ];
    int tid = threadIdx.x, lane = tid & 63, wv = tid >> 6;
    for (int s = tid; s < NSPAN; s += 256)
        sc[s] = sp[((size_t)b * NSPAN + s) * 3 + head];
    __syncthreads();
    for (int it = 0; it < NZ; ++it) {
        float bv = -1e30f; int bi = 1 << 29;
        for (int s = tid; s < NSPAN; s += 256) {
            float v = sc[s];
            if (v > bv || (v == bv && s < bi)) { bv = v; bi = s; }
        }
#pragma unroll
        for (int off = 32; off > 0; off >>= 1) {
            float ov = __shfl_down(bv, off, 64);
            int   oi = __shfl_down(bi, off, 64);
            if (ov > bv || (ov == bv && oi < bi)) { bv = ov; bi = oi; }
        }
        if (lane == 0) { swv[wv] = bv; swi[wv] = bi; }
        __syncthreads();
        if (tid == 0) {
            float fv = swv[0]; int fi = swi[0];
#pragma unroll
            for (int wvi = 1; wvi < 4; ++wvi) {
                float ov = swv[wvi]; int oi = swi[wvi];
                if (ov > fv || (ov == fv && oi < fi)) { fv = ov; fi = oi; }
            }
            if (fi < 0 || fi >= NSPAN) fi = 0;
            outp[it] = fi; sel[it] = fi; sc[fi] = -1e30f;
        }
        __syncthreads();
    }
    if (tid < NZ) {
        int st, en, w; span_decode(sel[tid], st, en, w);
        int base = (head == 1 ? 0 : 512) + b * NZ + tid;
        toks[base] = b * SEQ + st;
        toks[1024 + base] = b * SEQ + en - 1;
    }
}

// h1_pair[row] = relu(T[b,i] + O[b,j] + wtabPt + wtabPo + dtab) -> bf16
__global__ __launch_bounds__(256) void k_build_h1p(
    const float* __restrict__ TO, const int* __restrict__ t_idx, const int* __restrict__ o_idx,
    const float* __restrict__ wtabPt, const float* __restrict__ wtabPo,
    const float* __restrict__ dtab, u16* __restrict__ h1p)
{
    int row = blockIdx.x;               // b*4096 + i*64 + j
    int b = row >> 12, i = (row >> 6) & 63, j = row & 63;
    int ts = t_idx[b*64 + i], os = o_idx[b*64 + j];
    int ta, tb, wt, oc, od, wo;
    span_decode(ts, ta, tb, wt);
    span_decode(os, oc, od, wo);
    int d1 = tb - oc; d1 = d1 < 0 ? -d1 : d1;
    int d2 = ta - od; d2 = d2 < 0 ? -d2 : d2;
    int dist = d1 < d2 ? d1 : d2;
    int db = dbucket(dist);
    const float4* T4 = (const float4*)(TO + (size_t)(b*64 + i) * HID);
    const float4* O4 = (const float4*)(TO + (size_t)(512 + b*64 + j) * HID);
    const float4* P4 = (const float4*)(wtabPt + (size_t)(wt-1) * HID);
    const float4* Q4 = (const float4*)(wtabPo + (size_t)(wo-1) * HID);
    const float4* D4 = (const float4*)(dtab + (size_t)db * HID);
    int t = threadIdx.x;
    float4 a = T4[t], c = O4[t], p = P4[t], q = Q4[t], d = D4[t];
    float vx = fmaxf(a.x + c.x + p.x + q.x + d.x, 0.f);
    float vy = fmaxf(a.y + c.y + p.y + q.y + d.y, 0.f);
    float vz = fmaxf(a.z + c.z + p.z + q.z + d.z, 0.f);
    float vw = fmaxf(a.w + c.w + p.w + q.w + d.w, 0.f);
    u32 p0 = (u32)f2bf(vx) | ((u32)f2bf(vy) << 16);
    u32 p1 = (u32)f2bf(vz) | ((u32)f2bf(vw) << 16);
    *(uint2*)(h1p + (size_t)row * HID + t * 4) = make_uint2(p0, p1);
}

// pair layer2: h2p = relu(h1p @ Wp2 + bp2), single-pass bf16 MFMA, 128x128 tile,
// global_load_lds staging, XCD-aware grid (nbx=8, nby=256).
__global__ __launch_bounds__(256) void k_pair_l2(
    const u16* __restrict__ Abf, const u16* __restrict__ BT,
    const float* __restrict__ bias, u16* __restrict__ Cbf)
{
    int bx, by;
    xcd_map(blockIdx.x, 3, bx, by);
    __shared__ __align__(16) u16 sm[2 * 128 * 32];     // 16 KiB
    u16* As = sm;
    u16* Bs = sm + 4096;
    const int tid = threadIdx.x;
    const int bm = by * 128, bn = bx * 128;
    const int wave = tid >> 6, lane = tid & 63;
    const int wr = wave >> 1, wc = wave & 1;
    const int q = lane >> 4, tl = lane & 15;

    f32x4 zero = {0.f, 0.f, 0.f, 0.f};
    f32x4 acc[4][4];
#pragma unroll
    for (int i = 0; i < 4; ++i)
#pragma unroll
        for (int j = 0; j < 4; ++j) acc[i][j] = zero;

    const int srow = lane >> 2;
    const int scol = (lane & 3) * 8;
    const u16* gA0 = Abf + (size_t)(bm + wave*32 + srow) * 1024 + scol;
    const u16* gA1 = Abf + (size_t)(bm + wave*32 + 16 + srow) * 1024 + scol;
    const u16* gB0 = BT  + (size_t)(bn + wave*32 + srow) * 1024 + scol;
    const u16* gB1 = BT  + (size_t)(bn + wave*32 + 16 + srow) * 1024 + scol;
    u16* dA0 = As + wave * 1024;  u16* dA1 = dA0 + 512;
    u16* dB0 = Bs + wave * 1024;  u16* dB1 = dB0 + 512;

    for (int k0 = 0; k0 < 1024; k0 += 32) {
        gld_lds16(gA0 + k0, dA0);
        gld_lds16(gA1 + k0, dA1);
        gld_lds16(gB0 + k0, dB0);
        gld_lds16(gB1 + k0, dB1);
        __syncthreads();
        bf16x8 af[4], bf[4];
#pragma unroll
        for (int t = 0; t < 4; ++t) {
            af[t] = *(const bf16x8*)(&As[(wr*64 + t*16 + tl) * 32 + q*8]);
            bf[t] = *(const bf16x8*)(&Bs[(wc*64 + t*16 + tl) * 32 + q*8]);
        }
#pragma unroll
        for (int ti = 0; ti < 4; ++ti)
#pragma unroll
            for (int tj = 0; tj < 4; ++tj)
                acc[ti][tj] = __builtin_amdgcn_mfma_f32_16x16x32_bf16(af[ti], bf[tj], acc[ti][tj], 0, 0, 0);
        __syncthreads();
    }
#pragma unroll
    for (int ti = 0; ti < 4; ++ti) {
#pragma unroll
        for (int tj = 0; tj < 4; ++tj) {
            int gcol = bn + wc*64 + tj*16 + tl;
            float bsv = bias[gcol];
#pragma unroll
            for (int r = 0; r < 4; ++r) {
                int grow = bm + wr*64 + ti*16 + q*4 + r;
                float v = acc[ti][tj][r] + bsv;
                v = fmaxf(v, 0.f);
                Cbf[(size_t)grow * 1024 + gcol] = f2bf(v);
            }
        }
    }
}

// pair layer3 + softmax -> out[48480 + r*4 + c]
__global__ __launch_bounds__(256) void k_pair_l3(
    const u16* __restrict__ h2p, const float* __restrict__ Wp3,
    const float* __restrict__ bp3, float* __restrict__ out)
{
    int wave = threadIdx.x >> 6, lane = threadIdx.x & 63;
    int r = blockIdx.x * 4 + wave;      // 32768 = 8192*4 exact
    const u16* hr = h2p + (size_t)r * HID;
    float s0 = 0.f, s1 = 0.f, s2 = 0.f, s3 = 0.f;
    for (int h = lane; h < HID; h += 64) {
        float v = bf2f(hr[h]);
        const float4 w = *(const float4*)(Wp3 + h * 4);
        s0 = fmaf(v, w.x, s0); s1 = fmaf(v, w.y, s1);
        s2 = fmaf(v, w.z, s2); s3 = fmaf(v, w.w, s3);
    }
#pragma unroll
    for (int off = 32; off > 0; off >>= 1) {
        s0 += __shfl_down(s0, off, 64);
        s1 += __shfl_down(s1, off, 64);
        s2 += __shfl_down(s2, off, 64);
        s3 += __shfl_down(s3, off, 64);
    }
    if (lane == 0) {
        s0 += bp3[0]; s1 += bp3[1]; s2 += bp3[2]; s3 += bp3[3];
        float m = fmaxf(fmaxf(s0, s1), fmaxf(s2, s3));
        float e0 = expf(s0 - m), e1 = expf(s1 - m), e2 = expf(s2 - m), e3 = expf(s3 - m);
        float inv = 1.f / (e0 + e1 + e2 + e3);
        float* o = out + (size_t)r * 4;
        o[0] = e0 * inv; o[1] = e1 * inv; o[2] = e2 * inv; o[3] = e3 * inv;
    }
}

extern "C" void kernel_launch(void* const* d_in, const int* in_sizes, int n_in,
                              void* d_out, int out_size, void* d_ws, size_t ws_size,
                              hipStream_t stream)
{
    const float* x    = (const float*)d_in[0];
    const float* wemb = (const float*)d_in[1];
    const float* demb = (const float*)d_in[2];
    const float* Ws1  = (const float*)d_in[3];
    const float* bs1  = (const float*)d_in[4];
    const float* Ws2  = (const float*)d_in[5];
    const float* bs2  = (const float*)d_in[6];
    const float* Ws3  = (const float*)d_in[7];
    const float* bs3  = (const float*)d_in[8];
    const float* Wp1  = (const float*)d_in[9];
    const float* bp1  = (const float*)d_in[10];
    const float* Wp2  = (const float*)d_in[11];
    const float* bp2  = (const float*)d_in[12];
    const float* Wp3  = (const float*)d_in[13];
    const float* bp3  = (const float*)d_in[14];
    float* out = (float*)d_out;
    char* ws = (char*)d_ws;

    // ---- workspace arena, lifetime-aliased (peak ~142 MB) ----
    const size_t RSZ = (size_t)32768 * HID * 2;   // 64 MiB
    size_t off = 0;
    auto alloc = [&](size_t bytes) -> void* {
        void* p = ws + off;
        off += (bytes + 255) & ~(size_t)255;
        return p;
    };
    char* R1 = (char*)alloc(RSZ);
    char* R2 = (char*)alloc(RSZ);
    u16*   h1h  = (u16*)R1;                              // 33.1 MB
    u16*   h1l  = (u16*)(R1 + (size_t)16160 * HID * 2);  // 33.1 MB
    u16*   h2p  = (u16*)R1;                              // 64 MiB (after h1s dead)
    float* XALL = (float*)R2;                            // 16 MiB
    u16*   xh   = (u16*)(R2 + (16u << 20));              // 3 MB
    u16*   xl   = (u16*)(R2 + (19u << 20));
    u16*   W1Th = (u16*)(R2 + (22u << 20));
    u16*   W1Tl = (u16*)(R2 + (25u << 20));
    float* h2s  = (float*)R2;                            // 63.1 MB (after XALL/splits dead)
    u16*   h1p  = (u16*)R2;                              // 64 MiB (after h2s dead)
    float* TO     = (float*)alloc((size_t)1024 * HID * 4);
    u16*   W2Th   = (u16*)alloc((size_t)1024 * 1024 * 2);
    u16*   W2Tl   = (u16*)alloc((size_t)1024 * 1024 * 2);
    u16*   Wp2T   = (u16*)alloc((size_t)1024 * 1024 * 2);
    float* wtabS  = (float*)alloc(8 * HID * 4);
    float* wtabPt = (float*)alloc(8 * HID * 4);
    float* wtabPo = (float*)alloc(8 * HID * 4);
    float* dtab   = (float*)alloc(14 * HID * 4);
    int*   t_idx  = (int*)alloc(BATCH * NZ * 4);
    int*   o_idx  = (int*)alloc(BATCH * NZ * 4);
    int*   toks   = (int*)alloc(2048 * 4);
    (void)ws_size; (void)in_sizes; (void)n_in; (void)out_size;

    // prep: tables + all bf16 splits/transposes (fused)
    k_tables<<<dim3(4, 38), 256, 0, stream>>>(wemb, demb, Ws1, bs1, Wp1, bp1,
                                              wtabS, wtabPt, wtabPo, dtab);
    k_prep<<<20480, 256, 0, stream>>>(x, xh, xl, Ws1, W1Th, W1Tl,
                                      Ws2, W2Th, W2Tl, Wp2, Wp2T);

    // layer-1 factorization: XALL = x2d @ [Ws1_top | Ws1_mid] (3-pass split-bf16)
    k_gemm3bf<<<256, 256, 0, stream>>>(xh, xl, 768, W1Th, W1Tl, 768,
                                       XALL, 2048, 2048, 768, 16, 4, nullptr, 0);
    k_build_h1s<<<16160, 256, 0, stream>>>(XALL, wtabS, h1h, h1l);
    // span layer2: 3-pass split-bf16 MFMA (error ~1e-6, preserves top-k order)
    k_gemm3bf<<<1024, 256, 0, stream>>>(h1h, h1l, HID, W2Th, W2Tl, HID,
                                        h2s, HID, 16160, HID, 127, 3, bs2, 1);
    k_span_l3<<<4040, 256, 0, stream>>>(h2s, Ws3, bs3, out);
    k_topk<<<16, 256, 0, stream>>>(out, t_idx, o_idx, toks);
    // gathered pair layer-1 (fp32, fused T/O + both K-halves)
    k_pairL1<<<dim3(16, 16), 256, 0, stream>>>(x, Wp1, TO, toks);
    k_build_h1p<<<32768, 256, 0, stream>>>(TO, t_idx, o_idx, wtabPt, wtabPo, dtab, h1p);
    // pair layer2: single-pass bf16 MFMA (selection-free path)
    k_pair_l2<<<2048, 256, 0, stream>>>(h1p, Wp2T, bp2, h2p);
    k_pair_l3<<<8192, 256, 0, stream>>>(h2p, Wp3, bp3, out + 48480);
}

// Round 7
// 598.734 us; speedup vs baseline: 2.1832x; 1.1563x over previous
//
#include <hip/hip_runtime.h>
#include <cstdint>
#include <cstddef>

#define BATCH 8
#define SEQ   256
#define DIM   768
#define NSPAN 2020
#define HID   1024
#define NZ    64

typedef unsigned short u16;
typedef unsigned int   u32;

typedef __bf16 bf16x8 __attribute__((ext_vector_type(8)));
typedef float  f32x4  __attribute__((ext_vector_type(4)));

__device__ __forceinline__ u16 f2bf(float f) {
    union { float f; u32 u; } x; x.f = f;
    u32 r = x.u + 0x7fffu + ((x.u >> 16) & 1u);
    return (u16)(r >> 16);
}
__device__ __forceinline__ float bf2f(u16 b) {
    union { u32 u; float f; } x; x.u = ((u32)b) << 16;
    return x.f;
}
// split v = hi + lo (both bf16); residual v-hi is exact in fp32
__device__ __forceinline__ void splitbf(float v, u16& h, u16& l) {
    h = f2bf(v);
    l = f2bf(v - bf2f(h));
}

// async global->LDS, 16B per lane; LDS dest = wave-uniform base + lane*16;
// global src may be per-lane (row gather OK) [m97/m104]
__device__ __forceinline__ void gld_lds16(const void* g, void* l) {
    __builtin_amdgcn_global_load_lds(
        (const __attribute__((address_space(1))) unsigned int*)g,
        (__attribute__((address_space(3))) unsigned int*)l, 16, 0, 0);
}

// span s -> (start, end, width); spans enumerated width-major: w=1..8, starts 0..L-w
__device__ __forceinline__ void span_decode(int s, int& start, int& end, int& w) {
    int off = 0;
#pragma unroll
    for (int wi = 1; wi <= 8; ++wi) {
        int cnt = SEQ - wi + 1;
        if (s < off + cnt) { w = wi; start = s - off; end = start + wi; return; }
        off += cnt;
    }
    w = 8; start = 0; end = 8;
}

// searchsorted(BUCKET_BINS, d, 'right') - 1
__device__ __forceinline__ int dbucket(int d) {
    int b = 0;
    b += (d >= 1);  b += (d >= 2);  b += (d >= 3);  b += (d >= 4);
    b += (d >= 5);  b += (d >= 7);  b += (d >= 8);  b += (d >= 15);
    b += (d >= 16); b += (d >= 31); b += (d >= 32); b += (d >= 63);
    b += (d >= 64);
    return b;
}

// XCD-aware deswizzle: (linear id) % 8 == by % 8 -> all column-blocks of one
// A-row-tile land on the SAME XCD (id%8 round-robin). sft = log2(nbx).
__device__ __forceinline__ void xcd_map(int L, int sft, int& bx, int& by) {
    int grp = L >> (3 + sft);
    int rem = L & ((1 << (3 + sft)) - 1);
    bx = rem >> 3;
    by = (grp << 3) | (rem & 7);
}

// ---------------------------------------------------------------------------
// Tiny per-bucket tables (width/dist embeddings only hit 14 rows).
// ---------------------------------------------------------------------------
__global__ __launch_bounds__(256) void k_tables(
    const float* __restrict__ wemb, const float* __restrict__ demb,
    const float* __restrict__ Ws1, const float* __restrict__ bs1,
    const float* __restrict__ Wp1, const float* __restrict__ bp1,
    float* __restrict__ wtabS, float* __restrict__ wtabPt,
    float* __restrict__ wtabPo, float* __restrict__ dtab)
{
    int h = blockIdx.x * 256 + threadIdx.x;   // 0..1023
    int row = blockIdx.y;                     // 0..37
    const int wb[8] = {1,2,3,4,5,5,6,7};      // width 1..8 -> bucket
    if (row < 8) {
        int bk = wb[row];
        float acc = bs1[h];
        for (int j = 0; j < 25; ++j) acc = fmaf(wemb[bk*25+j], Ws1[(size_t)(1536+j)*HID + h], acc);
        wtabS[row*HID + h] = acc;
    } else if (row < 16) {
        int bk = wb[row-8];
        float acc = 0.f;
        for (int j = 0; j < 25; ++j) acc = fmaf(wemb[bk*25+j], Wp1[(size_t)(1536+j)*HID + h], acc);
        wtabPt[(row-8)*HID + h] = acc;
    } else if (row < 24) {
        int bk = wb[row-16];
        float acc = 0.f;
        for (int j = 0; j < 25; ++j) acc = fmaf(wemb[bk*25+j], Wp1[(size_t)(3097+j)*HID + h], acc);
        wtabPo[(row-16)*HID + h] = acc;
    } else {
        int t = row - 24;                     // 0..13
        float acc = bp1[h];
        for (int j = 0; j < 25; ++j) acc = fmaf(demb[t*25+j], Wp1[(size_t)(3122+j)*HID + h], acc);
        dtab[t*HID + h] = acc;
    }
}

// ---------------------------------------------------------------------------
// Fused one-time prep (segmented flat index; boundaries multiple of 256).
//   seg0: [0, 1572864)            x -> xh/xl   (xh PERSISTENT: read by k_pairL1 late)
//   seg1: [1572864, 3145728)      Ws1 -> W1Th/W1Tl (transposed+rearranged)
//   seg2: [3145728, 4194304)      Ws2 -> W2Th/W2Tl (transposed)
//   seg3: [4194304, 5242880)      Wp2 -> Wp2T bf16 (transposed)
//   seg4: [5242880, 8388608)      Wp1 4 blocks -> Wp1T4 bf16 [blk][n=1024][k=768]
// ---------------------------------------------------------------------------
__global__ __launch_bounds__(256) void k_prep(
    const float* __restrict__ x,  u16* __restrict__ xh,   u16* __restrict__ xl,
    const float* __restrict__ Ws1, u16* __restrict__ W1Th, u16* __restrict__ W1Tl,
    const float* __restrict__ Ws2, u16* __restrict__ W2Th, u16* __restrict__ W2Tl,
    const float* __restrict__ Wp2, u16* __restrict__ Wp2T,
    const float* __restrict__ Wp1, u16* __restrict__ Wp1T4)
{
    int gi = blockIdx.x * 256 + threadIdx.x;
    if (gi < 1572864) {
        int i = gi;
        u16 h, l; splitbf(x[i], h, l);
        xh[i] = h; xl[i] = l;
    } else if (gi < 3145728) {
        int i = gi - 1572864;                 // over 2048*768
        int n = i / 768, k = i - n * 768;
        float v = (n < 1024) ? Ws1[(size_t)k * HID + n]
                             : Ws1[(size_t)(768 + k) * HID + (n - 1024)];
        u16 h, l; splitbf(v, h, l);
        W1Th[i] = h; W1Tl[i] = l;
    } else if (gi < 4194304) {
        int i = gi - 3145728;                 // over 1024*1024
        int n = i >> 10, k = i & 1023;
        u16 h, l; splitbf(Ws2[(size_t)k * HID + n], h, l);
        W2Th[i] = h; W2Tl[i] = l;
    } else if (gi < 5242880) {
        int i = gi - 4194304;                 // over 1024*1024
        int n = i >> 10, k = i & 1023;
        Wp2T[i] = f2bf(Wp2[(size_t)k * HID + n]);
    } else {
        int i = gi - 5242880;                 // over 4*1024*768
        int blk = i / 786432;
        int rem = i - blk * 786432;
        int n = rem / 768, k = rem - n * 768;
        const int roff[4] = {0, 768, 1561, 2329};   // (T,p0),(T,p1),(O,p0),(O,p1)
        Wp1T4[i] = f2bf(Wp1[(size_t)(roff[blk] + k) * HID + n]);
    }
}

// ---------------------------------------------------------------------------
// Error-compensated split-bf16 MFMA GEMM: C = AhBh + AlBh + AhBl
// 128x128 tile, BK=32, global_load_lds width-16 staging, XCD-aware grid.
// ---------------------------------------------------------------------------
__global__ __launch_bounds__(256) void k_gemm3bf(
    const u16* __restrict__ Ah, const u16* __restrict__ Al, int lda,
    const u16* __restrict__ BTh, const u16* __restrict__ BTl, int ldb,
    float* __restrict__ C, int ldc,
    int M, int K, int nby, int sft,
    const float* __restrict__ bias, int relu)
{
    int bx, by;
    xcd_map(blockIdx.x, sft, bx, by);
    if (by >= nby) return;
    __shared__ __align__(16) u16 sm[4 * 128 * 32];     // 32 KiB
    u16* sAh = sm;
    u16* sAl = sm + 4096;
    u16* sBh = sm + 8192;
    u16* sBl = sm + 12288;
    const int tid = threadIdx.x;
    const int bm = by * 128, bn = bx * 128;
    const int wave = tid >> 6, lane = tid & 63;
    const int wr = wave >> 1, wc = wave & 1;
    const int q = lane >> 4, tl = lane & 15;

    f32x4 zero = {0.f, 0.f, 0.f, 0.f};
    f32x4 acc[4][4];
#pragma unroll
    for (int i = 0; i < 4; ++i)
#pragma unroll
        for (int j = 0; j < 4; ++j) acc[i][j] = zero;

    const int srow = lane >> 2;
    const int scol = (lane & 3) * 8;
    int ra0 = bm + wave * 32 + srow;      if (ra0 >= M) ra0 = M - 1;
    int ra1 = bm + wave * 32 + 16 + srow; if (ra1 >= M) ra1 = M - 1;
    const int rb0 = bn + wave * 32 + srow;
    const int rb1 = bn + wave * 32 + 16 + srow;
    u16* dA0 = sAh + wave * 1024;  u16* dA1 = dA0 + 512;
    u16* dL0 = sAl + wave * 1024;  u16* dL1 = dL0 + 512;
    u16* dB0 = sBh + wave * 1024;  u16* dB1 = dB0 + 512;
    u16* dC0 = sBl + wave * 1024;  u16* dC1 = dC0 + 512;
    const u16* gA0 = Ah  + (size_t)ra0 * lda + scol;
    const u16* gA1 = Ah  + (size_t)ra1 * lda + scol;
    const u16* gL0 = Al  + (size_t)ra0 * lda + scol;
    const u16* gL1 = Al  + (size_t)ra1 * lda + scol;
    const u16* gB0 = BTh + (size_t)rb0 * ldb + scol;
    const u16* gB1 = BTh + (size_t)rb1 * ldb + scol;
    const u16* gC0 = BTl + (size_t)rb0 * ldb + scol;
    const u16* gC1 = BTl + (size_t)rb1 * ldb + scol;

    for (int k0 = 0; k0 < K; k0 += 32) {
        gld_lds16(gA0 + k0, dA0);
        gld_lds16(gA1 + k0, dA1);
        gld_lds16(gL0 + k0, dL0);
        gld_lds16(gL1 + k0, dL1);
        gld_lds16(gB0 + k0, dB0);
        gld_lds16(gB1 + k0, dB1);
        gld_lds16(gC0 + k0, dC0);
        gld_lds16(gC1 + k0, dC1);
        __syncthreads();
        bf16x8 ah[4], al[4], bh[4], bl[4];
#pragma unroll
        for (int t = 0; t < 4; ++t) {
            int arow = (wr*64 + t*16 + tl) * 32 + q*8;
            int brow = (wc*64 + t*16 + tl) * 32 + q*8;
            ah[t] = *(const bf16x8*)(&sAh[arow]);
            al[t] = *(const bf16x8*)(&sAl[arow]);
            bh[t] = *(const bf16x8*)(&sBh[brow]);
            bl[t] = *(const bf16x8*)(&sBl[brow]);
        }
#pragma unroll
        for (int ti = 0; ti < 4; ++ti)
#pragma unroll
            for (int tj = 0; tj < 4; ++tj) {
                acc[ti][tj] = __builtin_amdgcn_mfma_f32_16x16x32_bf16(ah[ti], bh[tj], acc[ti][tj], 0, 0, 0);
                acc[ti][tj] = __builtin_amdgcn_mfma_f32_16x16x32_bf16(al[ti], bh[tj], acc[ti][tj], 0, 0, 0);
                acc[ti][tj] = __builtin_amdgcn_mfma_f32_16x16x32_bf16(ah[ti], bl[tj], acc[ti][tj], 0, 0, 0);
            }
        __syncthreads();
    }
    // C/D layout: col = lane&15, row = (lane>>4)*4 + reg  [measured m89/m91]
#pragma unroll
    for (int ti = 0; ti < 4; ++ti) {
#pragma unroll
        for (int tj = 0; tj < 4; ++tj) {
            int gcol = bn + wc*64 + tj*16 + tl;
            float bsv = bias ? bias[gcol] : 0.f;
#pragma unroll
            for (int r = 0; r < 4; ++r) {
                int grow = bm + wr*64 + ti*16 + q*4 + r;
                if (grow >= M) continue;
                float v = acc[ti][tj][r] + bsv;
                if (relu) v = fmaxf(v, 0.f);
                C[(size_t)grow * ldc + gcol] = v;
            }
        }
    }
}

// ---------------------------------------------------------------------------
// Gathered pair layer-1, bf16 MFMA: TO[r] = xh[toks[r]]@B(p0) + xh[toks[1024+r]]@B(p1)
// 64x64 tiles, 2x2 wave-tiles of 32x32, BK=32, global_load_lds with row gather.
// B = Wp1T4 blocks: (isO*2 + p), each [1024 n][768 k] bf16.
// ---------------------------------------------------------------------------
__global__ __launch_bounds__(256) void k_pairL1(
    const u16* __restrict__ xh, const u16* __restrict__ Wp1T4,
    float* __restrict__ TO, const int* __restrict__ toks)
{
    __shared__ __align__(16) u16 sm[2 * 64 * 32];   // A 4KB | B 4KB
    u16* sA = sm;
    u16* sB = sm + 2048;
    const int tid = threadIdx.x;
    const int bx = blockIdx.x & 15, by = blockIdx.x >> 4;
    const int bm = by * 64, bn = bx * 64;
    const int wave = tid >> 6, lane = tid & 63;
    const int wr = wave >> 1, wc = wave & 1;
    const int q = lane >> 4, tl = lane & 15;
    const bool isO = bm >= 512;

    f32x4 zero = {0.f, 0.f, 0.f, 0.f};
    f32x4 acc[2][2];
#pragma unroll
    for (int i = 0; i < 2; ++i)
#pragma unroll
        for (int j = 0; j < 2; ++j) acc[i][j] = zero;

    const int srow = tid >> 2;          // 0..63 (wave w covers rows w*16..w*16+15)
    const int scol = (tid & 3) * 8;
    u16* dA = sA + wave * 512;          // lane lands at dA + lane*8 elems = srow*32+scol
    u16* dB = sB + wave * 512;

#pragma unroll
    for (int p = 0; p < 2; ++p) {
        int arow = toks[bm + srow + p * 1024];    // per-lane row gather
        const u16* gA = xh + (size_t)arow * DIM + scol;
        const u16* gB = Wp1T4 + ((size_t)((isO ? 2 : 0) + p) * 1024 + bn + srow) * DIM + scol;
        for (int k0 = 0; k0 < DIM; k0 += 32) {
            gld_lds16(gA + k0, dA);
            gld_lds16(gB + k0, dB);
            __syncthreads();
            bf16x8 af[2], bf[2];
#pragma unroll
            for (int t = 0; t < 2; ++t) {
                af[t] = *(const bf16x8*)(&sA[(wr*32 + t*16 + tl) * 32 + q*8]);
                bf[t] = *(const bf16x8*)(&sB[(wc*32 + t*16 + tl) * 32 + q*8]);
            }
#pragma unroll
            for (int ti = 0; ti < 2; ++ti)
#pragma unroll
                for (int tj = 0; tj < 2; ++tj)
                    acc[ti][tj] = __builtin_amdgcn_mfma_f32_16x16x32_bf16(af[ti], bf[tj], acc[ti][tj], 0, 0, 0);
            __syncthreads();
        }
    }
#pragma unroll
    for (int ti = 0; ti < 2; ++ti) {
#pragma unroll
        for (int tj = 0; tj < 2; ++tj) {
            int gcol = bn + wc*32 + tj*16 + tl;
#pragma unroll
            for (int r = 0; r < 4; ++r) {
                int grow = bm + wr*32 + ti*16 + q*4 + r;
                TO[(size_t)grow * HID + gcol] = acc[ti][tj][r];
            }
        }
    }
}

// h1s = relu(XALL[b,start,0:1024] + XALL[b,end-1,1024:2048] + wtabS[w-1]) -> split bf16
__global__ __launch_bounds__(256) void k_build_h1s(
    const float* __restrict__ XALL, const float* __restrict__ wtabS,
    u16* __restrict__ h1h, u16* __restrict__ h1l)
{
    int r = blockIdx.x;                 // 0..16159
    int b = r / NSPAN, s = r - b * NSPAN;
    int st, en, w; span_decode(s, st, en, w);
    const float4* xs = (const float4*)(XALL + (size_t)(b*SEQ + st) * 2048);
    const float4* xe = (const float4*)(XALL + (size_t)(b*SEQ + en - 1) * 2048 + 1024);
    const float4* wt = (const float4*)(wtabS + (size_t)(w-1) * HID);
    int t = threadIdx.x;
    float4 a = xs[t], bz = xe[t], c = wt[t];
    float v0 = fmaxf(a.x + bz.x + c.x, 0.f);
    float v1 = fmaxf(a.y + bz.y + c.y, 0.f);
    float v2 = fmaxf(a.z + bz.z + c.z, 0.f);
    float v3 = fmaxf(a.w + bz.w + c.w, 0.f);
    u16 h0,l0,h1,l1,h2,l2,h3,l3;
    splitbf(v0,h0,l0); splitbf(v1,h1,l1); splitbf(v2,h2,l2); splitbf(v3,h3,l3);
    size_t base = (size_t)r * HID + t * 4;
    *(uint2*)(h1h + base) = make_uint2((u32)h0 | ((u32)h1 << 16), (u32)h2 | ((u32)h3 << 16));
    *(uint2*)(h1l + base) = make_uint2((u32)l0 | ((u32)l1 << 16), (u32)l2 | ((u32)l3 << 16));
}

// span layer3 + softmax -> out[r*3 + c]. One wave per row, 4 rows/block.
__global__ __launch_bounds__(256) void k_span_l3(
    const float* __restrict__ h2s, const float* __restrict__ Ws3,
    const float* __restrict__ bs3, float* __restrict__ out)
{
    int wave = threadIdx.x >> 6, lane = threadIdx.x & 63;
    int r = blockIdx.x * 4 + wave;      // 16160 = 4040*4 exact
    const float* hr = h2s + (size_t)r * HID;
    float s0 = 0.f, s1 = 0.f, s2 = 0.f;
    for (int h = lane; h < HID; h += 64) {
        float v = hr[h];
        const float* wrow = Ws3 + h * 3;
        s0 = fmaf(v, wrow[0], s0);
        s1 = fmaf(v, wrow[1], s1);
        s2 = fmaf(v, wrow[2], s2);
    }
#pragma unroll
    for (int off = 32; off > 0; off >>= 1) {
        s0 += __shfl_down(s0, off, 64);
        s1 += __shfl_down(s1, off, 64);
        s2 += __shfl_down(s2, off, 64);
    }
    if (lane == 0) {
        s0 += bs3[0]; s1 += bs3[1]; s2 += bs3[2];
        float m = fmaxf(s0, fmaxf(s1, s2));
        float e0 = expf(s0 - m), e1 = expf(s1 - m), e2 = expf(s2 - m);
        float inv = 1.f / (e0 + e1 + e2);
        float* o = out + (size_t)r * 3;
        o[0] = e0 * inv; o[1] = e1 * inv; o[2] = e2 * inv;
    }
}

// top-64 (descending, ties -> lower index) + fused token-rowmap build.
__global__ __launch_bounds__(256) void k_topk(
    const float* __restrict__ sp, int* __restrict__ t_idx, int* __restrict__ o_idx,
    int* __restrict__ toks)
{
    int b = blockIdx.x >> 1;
    int head = 1 + (blockIdx.x & 1);
    int* outp = (head == 1 ? t_idx : o_idx) + b * NZ;
    __shared__ float sc[NSPAN];
    __shared__ float swv[4];
    __shared__ int   swi[4];
    __shared__ int   sel[NZ];
    int tid = threadIdx.x, lane = tid & 63, wv = tid >> 6;
    for (int s = tid; s < NSPAN; s += 256)
        sc[s] = sp[((size_t)b * NSPAN + s) * 3 + head];
    __syncthreads();
    for (int it = 0; it < NZ; ++it) {
        float bv = -1e30f; int bi = 1 << 29;
        for (int s = tid; s < NSPAN; s += 256) {
            float v = sc[s];
            if (v > bv || (v == bv && s < bi)) { bv = v; bi = s; }
        }
#pragma unroll
        for (int off = 32; off > 0; off >>= 1) {
            float ov = __shfl_down(bv, off, 64);
            int   oi = __shfl_down(bi, off, 64);
            if (ov > bv || (ov == bv && oi < bi)) { bv = ov; bi = oi; }
        }
        if (lane == 0) { swv[wv] = bv; swi[wv] = bi; }
        __syncthreads();
        if (tid == 0) {
            float fv = swv[0]; int fi = swi[0];
#pragma unroll
            for (int wvi = 1; wvi < 4; ++wvi) {
                float ov = swv[wvi]; int oi = swi[wvi];
                if (ov > fv || (ov == fv && oi < fi)) { fv = ov; fi = oi; }
            }
            if (fi < 0 || fi >= NSPAN) fi = 0;
            outp[it] = fi; sel[it] = fi; sc[fi] = -1e30f;
        }
        __syncthreads();
    }
    if (tid < NZ) {
        int st, en, w; span_decode(sel[tid], st, en, w);
        int base = (head == 1 ? 0 : 512) + b * NZ + tid;
        toks[base] = b * SEQ + st;
        toks[1024 + base] = b * SEQ + en - 1;
    }
}

// h1_pair[row] = relu(T[b,i] + O[b,j] + wtabPt + wtabPo + dtab) -> bf16
__global__ __launch_bounds__(256) void k_build_h1p(
    const float* __restrict__ TO, const int* __restrict__ t_idx, const int* __restrict__ o_idx,
    const float* __restrict__ wtabPt, const float* __restrict__ wtabPo,
    const float* __restrict__ dtab, u16* __restrict__ h1p)
{
    int row = blockIdx.x;               // b*4096 + i*64 + j
    int b = row >> 12, i = (row >> 6) & 63, j = row & 63;
    int ts = t_idx[b*64 + i], os = o_idx[b*64 + j];
    int ta, tb, wt, oc, od, wo;
    span_decode(ts, ta, tb, wt);
    span_decode(os, oc, od, wo);
    int d1 = tb - oc; d1 = d1 < 0 ? -d1 : d1;
    int d2 = ta - od; d2 = d2 < 0 ? -d2 : d2;
    int dist = d1 < d2 ? d1 : d2;
    int db = dbucket(dist);
    const float4* T4 = (const float4*)(TO + (size_t)(b*64 + i) * HID);
    const float4* O4 = (const float4*)(TO + (size_t)(512 + b*64 + j) * HID);
    const float4* P4 = (const float4*)(wtabPt + (size_t)(wt-1) * HID);
    const float4* Q4 = (const float4*)(wtabPo + (size_t)(wo-1) * HID);
    const float4* D4 = (const float4*)(dtab + (size_t)db * HID);
    int t = threadIdx.x;
    float4 a = T4[t], c = O4[t], p = P4[t], q = Q4[t], d = D4[t];
    float vx = fmaxf(a.x + c.x + p.x + q.x + d.x, 0.f);
    float vy = fmaxf(a.y + c.y + p.y + q.y + d.y, 0.f);
    float vz = fmaxf(a.z + c.z + p.z + q.z + d.z, 0.f);
    float vw = fmaxf(a.w + c.w + p.w + q.w + d.w, 0.f);
    u32 p0 = (u32)f2bf(vx) | ((u32)f2bf(vy) << 16);
    u32 p1 = (u32)f2bf(vz) | ((u32)f2bf(vw) << 16);
    *(uint2*)(h1p + (size_t)row * HID + t * 4) = make_uint2(p0, p1);
}

// pair layer2: h2p = relu(h1p @ Wp2 + bp2), single-pass bf16 MFMA, 128x128 tile,
// global_load_lds staging, XCD-aware grid (nbx=8, nby=256).
__global__ __launch_bounds__(256) void k_pair_l2(
    const u16* __restrict__ Abf, const u16* __restrict__ BT,
    const float* __restrict__ bias, u16* __restrict__ Cbf)
{
    int bx, by;
    xcd_map(blockIdx.x, 3, bx, by);
    __shared__ __align__(16) u16 sm[2 * 128 * 32];     // 16 KiB
    u16* As = sm;
    u16* Bs = sm + 4096;
    const int tid = threadIdx.x;
    const int bm = by * 128, bn = bx * 128;
    const int wave = tid >> 6, lane = tid & 63;
    const int wr = wave >> 1, wc = wave & 1;
    const int q = lane >> 4, tl = lane & 15;

    f32x4 zero = {0.f, 0.f, 0.f, 0.f};
    f32x4 acc[4][4];
#pragma unroll
    for (int i = 0; i < 4; ++i)
#pragma unroll
        for (int j = 0; j < 4; ++j) acc[i][j] = zero;

    const int srow = lane >> 2;
    const int scol = (lane & 3) * 8;
    const u16* gA0 = Abf + (size_t)(bm + wave*32 + srow) * 1024 + scol;
    const u16* gA1 = Abf + (size_t)(bm + wave*32 + 16 + srow) * 1024 + scol;
    const u16* gB0 = BT  + (size_t)(bn + wave*32 + srow) * 1024 + scol;
    const u16* gB1 = BT  + (size_t)(bn + wave*32 + 16 + srow) * 1024 + scol;
    u16* dA0 = As + wave * 1024;  u16* dA1 = dA0 + 512;
    u16* dB0 = Bs + wave * 1024;  u16* dB1 = dB0 + 512;

    for (int k0 = 0; k0 < 1024; k0 += 32) {
        gld_lds16(gA0 + k0, dA0);
        gld_lds16(gA1 + k0, dA1);
        gld_lds16(gB0 + k0, dB0);
        gld_lds16(gB1 + k0, dB1);
        __syncthreads();
        bf16x8 af[4], bf[4];
#pragma unroll
        for (int t = 0; t < 4; ++t) {
            af[t] = *(const bf16x8*)(&As[(wr*64 + t*16 + tl) * 32 + q*8]);
            bf[t] = *(const bf16x8*)(&Bs[(wc*64 + t*16 + tl) * 32 + q*8]);
        }
#pragma unroll
        for (int ti = 0; ti < 4; ++ti)
#pragma unroll
            for (int tj = 0; tj < 4; ++tj)
                acc[ti][tj] = __builtin_amdgcn_mfma_f32_16x16x32_bf16(af[ti], bf[tj], acc[ti][tj], 0, 0, 0);
        __syncthreads();
    }
#pragma unroll
    for (int ti = 0; ti < 4; ++ti) {
#pragma unroll
        for (int tj = 0; tj < 4; ++tj) {
            int gcol = bn + wc*64 + tj*16 + tl;
            float bsv = bias[gcol];
#pragma unroll
            for (int r = 0; r < 4; ++r) {
                int grow = bm + wr*64 + ti*16 + q*4 + r;
                float v = acc[ti][tj][r] + bsv;
                v = fmaxf(v, 0.f);
                Cbf[(size_t)grow * 1024 + gcol] = f2bf(v);
            }
        }
    }
}

// pair layer3 + softmax -> out[48480 + r*4 + c]
__global__ __launch_bounds__(256) void k_pair_l3(
    const u16* __restrict__ h2p, const float* __restrict__ Wp3,
    const float* __restrict__ bp3, float* __restrict__ out)
{
    int wave = threadIdx.x >> 6, lane = threadIdx.x & 63;
    int r = blockIdx.x * 4 + wave;      // 32768 = 8192*4 exact
    const u16* hr = h2p + (size_t)r * HID;
    float s0 = 0.f, s1 = 0.f, s2 = 0.f, s3 = 0.f;
    for (int h = lane; h < HID; h += 64) {
        float v = bf2f(hr[h]);
        const float4 w = *(const float4*)(Wp3 + h * 4);
        s0 = fmaf(v, w.x, s0); s1 = fmaf(v, w.y, s1);
        s2 = fmaf(v, w.z, s2); s3 = fmaf(v, w.w, s3);
    }
#pragma unroll
    for (int off = 32; off > 0; off >>= 1) {
        s0 += __shfl_down(s0, off, 64);
        s1 += __shfl_down(s1, off, 64);
        s2 += __shfl_down(s2, off, 64);
        s3 += __shfl_down(s3, off, 64);
    }
    if (lane == 0) {
        s0 += bp3[0]; s1 += bp3[1]; s2 += bp3[2]; s3 += bp3[3];
        float m = fmaxf(fmaxf(s0, s1), fmaxf(s2, s3));
        float e0 = expf(s0 - m), e1 = expf(s1 - m), e2 = expf(s2 - m), e3 = expf(s3 - m);
        float inv = 1.f / (e0 + e1 + e2 + e3);
        float* o = out + (size_t)r * 4;
        o[0] = e0 * inv; o[1] = e1 * inv; o[2] = e2 * inv; o[3] = e3 * inv;
    }
}

extern "C" void kernel_launch(void* const* d_in, const int* in_sizes, int n_in,
                              void* d_out, int out_size, void* d_ws, size_t ws_size,
                              hipStream_t stream)
{
    const float* x    = (const float*)d_in[0];
    const float* wemb = (const float*)d_in[1];
    const float* demb = (const float*)d_in[2];
    const float* Ws1  = (const float*)d_in[3];
    const float* bs1  = (const float*)d_in[4];
    const float* Ws2  = (const float*)d_in[5];
    const float* bs2  = (const float*)d_in[6];
    const float* Ws3  = (const float*)d_in[7];
    const float* bs3  = (const float*)d_in[8];
    const float* Wp1  = (const float*)d_in[9];
    const float* bp1  = (const float*)d_in[10];
    const float* Wp2  = (const float*)d_in[11];
    const float* bp2  = (const float*)d_in[12];
    const float* Wp3  = (const float*)d_in[13];
    const float* bp3  = (const float*)d_in[14];
    float* out = (float*)d_out;
    char* ws = (char*)d_ws;

    // ---- workspace arena, lifetime-aliased (peak ~154 MB) ----
    // R1 (64 MiB): h1h+h1l (dead after span L2)  -> h2p
    // R2 (64 MiB): [XALL | xl | W1Th | W1Tl] (dead after build_h1s / XALL gemm)
    //              -> h2s (dead after span_l3)   -> h1p
    // xh is PERSISTENT (read by k_pairL1 after h2s clobbers R2) -- round-6 bug fix.
    const size_t RSZ = (size_t)32768 * HID * 2;   // 64 MiB
    size_t off = 0;
    auto alloc = [&](size_t bytes) -> void* {
        void* p = ws + off;
        off += (bytes + 255) & ~(size_t)255;
        return p;
    };
    char* R1 = (char*)alloc(RSZ);
    char* R2 = (char*)alloc(RSZ);
    u16*   h1h  = (u16*)R1;                              // 33.1 MB
    u16*   h1l  = (u16*)(R1 + (size_t)16160 * HID * 2);  // 33.1 MB
    u16*   h2p  = (u16*)R1;                              // 64 MiB (after h1s dead)
    float* XALL = (float*)R2;                            // 16 MiB
    u16*   xl   = (u16*)(R2 + (16u << 20));              // 3 MB (dead after XALL gemm)
    u16*   W1Th = (u16*)(R2 + (19u << 20));              // 3 MB (dead after XALL gemm)
    u16*   W1Tl = (u16*)(R2 + (22u << 20));              // 3 MB (dead after XALL gemm)
    float* h2s  = (float*)R2;                            // 63.1 MB (after the above dead)
    u16*   h1p  = (u16*)R2;                              // 64 MiB (after h2s dead)
    u16*   xh     = (u16*)alloc((size_t)2048 * DIM * 2);   // 3 MB PERSISTENT
    float* TO     = (float*)alloc((size_t)1024 * HID * 4);
    u16*   W2Th   = (u16*)alloc((size_t)1024 * 1024 * 2);
    u16*   W2Tl   = (u16*)alloc((size_t)1024 * 1024 * 2);
    u16*   Wp2T   = (u16*)alloc((size_t)1024 * 1024 * 2);
    u16*   Wp1T4  = (u16*)alloc((size_t)4 * 1024 * 768 * 2);
    float* wtabS  = (float*)alloc(8 * HID * 4);
    float* wtabPt = (float*)alloc(8 * HID * 4);
    float* wtabPo = (float*)alloc(8 * HID * 4);
    float* dtab   = (float*)alloc(14 * HID * 4);
    int*   t_idx  = (int*)alloc(BATCH * NZ * 4);
    int*   o_idx  = (int*)alloc(BATCH * NZ * 4);
    int*   toks   = (int*)alloc(2048 * 4);
    (void)ws_size; (void)in_sizes; (void)n_in; (void)out_size;

    // prep: tables + all bf16 splits/transposes (fused; 8388608 indices)
    k_tables<<<dim3(4, 38), 256, 0, stream>>>(wemb, demb, Ws1, bs1, Wp1, bp1,
                                              wtabS, wtabPt, wtabPo, dtab);
    k_prep<<<32768, 256, 0, stream>>>(x, xh, xl, Ws1, W1Th, W1Tl,
                                      Ws2, W2Th, W2Tl, Wp2, Wp2T, Wp1, Wp1T4);

    // layer-1 factorization: XALL = x2d @ [Ws1_top | Ws1_mid] (3-pass split-bf16)
    k_gemm3bf<<<256, 256, 0, stream>>>(xh, xl, 768, W1Th, W1Tl, 768,
                                       XALL, 2048, 2048, 768, 16, 4, nullptr, 0);
    k_build_h1s<<<16160, 256, 0, stream>>>(XALL, wtabS, h1h, h1l);
    // span layer2: 3-pass split-bf16 MFMA (error ~1e-6, preserves top-k order)
    k_gemm3bf<<<1024, 256, 0, stream>>>(h1h, h1l, HID, W2Th, W2Tl, HID,
                                        h2s, HID, 16160, HID, 127, 3, bs2, 1);
    k_span_l3<<<4040, 256, 0, stream>>>(h2s, Ws3, bs3, out);
    k_topk<<<16, 256, 0, stream>>>(out, t_idx, o_idx, toks);
    // gathered pair layer-1: bf16 MFMA with per-lane row gather (reads persistent xh)
    k_pairL1<<<256, 256, 0, stream>>>(xh, Wp1T4, TO, toks);
    k_build_h1p<<<32768, 256, 0, stream>>>(TO, t_idx, o_idx, wtabPt, wtabPo, dtab, h1p);
    // pair layer2: single-pass bf16 MFMA (selection-free path)
    k_pair_l2<<<2048, 256, 0, stream>>>(h1p, Wp2T, bp2, h2p);
    k_pair_l3<<<8192, 256, 0, stream>>>(h2p, Wp3, bp3, out + 48480);
}

// Round 8
// 556.423 us; speedup vs baseline: 2.3492x; 1.0760x over previous
//
#include <hip/hip_runtime.h>
#include <cstdint>
#include <cstddef>

#define BATCH 8
#define SEQ   256
#define DIM   768
#define NSPAN 2020
#define HID   1024
#define NZ    64

typedef unsigned short u16;
typedef unsigned int   u32;

typedef __bf16 bf16x8 __attribute__((ext_vector_type(8)));
typedef float  f32x4  __attribute__((ext_vector_type(4)));

__device__ __forceinline__ u16 f2bf(float f) {
    union { float f; u32 u; } x; x.f = f;
    u32 r = x.u + 0x7fffu + ((x.u >> 16) & 1u);
    return (u16)(r >> 16);
}
__device__ __forceinline__ float bf2f(u16 b) {
    union { u32 u; float f; } x; x.u = ((u32)b) << 16;
    return x.f;
}
// split v = hi + lo (both bf16); residual v-hi is exact in fp32
__device__ __forceinline__ void splitbf(float v, u16& h, u16& l) {
    h = f2bf(v);
    l = f2bf(v - bf2f(h));
}

// async global->LDS, 16B per lane; LDS dest = wave-uniform base + lane*16;
// global src may be per-lane (row gather OK) [m97/m104]
__device__ __forceinline__ void gld_lds16(const void* g, void* l) {
    __builtin_amdgcn_global_load_lds(
        (const __attribute__((address_space(1))) unsigned int*)g,
        (__attribute__((address_space(3))) unsigned int*)l, 16, 0, 0);
}

// span s -> (start, end, width); spans enumerated width-major: w=1..8, starts 0..L-w
__device__ __forceinline__ void span_decode(int s, int& start, int& end, int& w) {
    int off = 0;
#pragma unroll
    for (int wi = 1; wi <= 8; ++wi) {
        int cnt = SEQ - wi + 1;
        if (s < off + cnt) { w = wi; start = s - off; end = start + wi; return; }
        off += cnt;
    }
    w = 8; start = 0; end = 8;
}

// searchsorted(BUCKET_BINS, d, 'right') - 1
__device__ __forceinline__ int dbucket(int d) {
    int b = 0;
    b += (d >= 1);  b += (d >= 2);  b += (d >= 3);  b += (d >= 4);
    b += (d >= 5);  b += (d >= 7);  b += (d >= 8);  b += (d >= 15);
    b += (d >= 16); b += (d >= 31); b += (d >= 32); b += (d >= 63);
    b += (d >= 64);
    return b;
}

// XCD-aware deswizzle: (linear id) % 8 == by % 8 -> all column-blocks of one
// A-row-tile land on the SAME XCD (id%8 round-robin). sft = log2(nbx).
__device__ __forceinline__ void xcd_map(int L, int sft, int& bx, int& by) {
    int grp = L >> (3 + sft);
    int rem = L & ((1 << (3 + sft)) - 1);
    bx = rem >> 3;
    by = (grp << 3) | (rem & 7);
}

// ---------------------------------------------------------------------------
// Tiny per-bucket tables (width/dist embeddings only hit 14 rows).
// ---------------------------------------------------------------------------
__global__ __launch_bounds__(256) void k_tables(
    const float* __restrict__ wemb, const float* __restrict__ demb,
    const float* __restrict__ Ws1, const float* __restrict__ bs1,
    const float* __restrict__ Wp1, const float* __restrict__ bp1,
    float* __restrict__ wtabS, float* __restrict__ wtabPt,
    float* __restrict__ wtabPo, float* __restrict__ dtab)
{
    int h = blockIdx.x * 256 + threadIdx.x;   // 0..1023
    int row = blockIdx.y;                     // 0..37
    const int wb[8] = {1,2,3,4,5,5,6,7};      // width 1..8 -> bucket
    if (row < 8) {
        int bk = wb[row];
        float acc = bs1[h];
        for (int j = 0; j < 25; ++j) acc = fmaf(wemb[bk*25+j], Ws1[(size_t)(1536+j)*HID + h], acc);
        wtabS[row*HID + h] = acc;
    } else if (row < 16) {
        int bk = wb[row-8];
        float acc = 0.f;
        for (int j = 0; j < 25; ++j) acc = fmaf(wemb[bk*25+j], Wp1[(size_t)(1536+j)*HID + h], acc);
        wtabPt[(row-8)*HID + h] = acc;
    } else if (row < 24) {
        int bk = wb[row-16];
        float acc = 0.f;
        for (int j = 0; j < 25; ++j) acc = fmaf(wemb[bk*25+j], Wp1[(size_t)(3097+j)*HID + h], acc);
        wtabPo[(row-16)*HID + h] = acc;
    } else {
        int t = row - 24;                     // 0..13
        float acc = bp1[h];
        for (int j = 0; j < 25; ++j) acc = fmaf(demb[t*25+j], Wp1[(size_t)(3122+j)*HID + h], acc);
        dtab[t*HID + h] = acc;
    }
}

// ---------------------------------------------------------------------------
// Fused one-time prep (segmented flat index; boundaries multiple of 256).
// ---------------------------------------------------------------------------
__global__ __launch_bounds__(256) void k_prep(
    const float* __restrict__ x,  u16* __restrict__ xh,   u16* __restrict__ xl,
    const float* __restrict__ Ws1, u16* __restrict__ W1Th, u16* __restrict__ W1Tl,
    const float* __restrict__ Ws2, u16* __restrict__ W2Th, u16* __restrict__ W2Tl,
    const float* __restrict__ Wp2, u16* __restrict__ Wp2T,
    const float* __restrict__ Wp1, u16* __restrict__ Wp1T4)
{
    int gi = blockIdx.x * 256 + threadIdx.x;
    if (gi < 1572864) {
        int i = gi;
        u16 h, l; splitbf(x[i], h, l);
        xh[i] = h; xl[i] = l;
    } else if (gi < 3145728) {
        int i = gi - 1572864;                 // over 2048*768
        int n = i / 768, k = i - n * 768;
        float v = (n < 1024) ? Ws1[(size_t)k * HID + n]
                             : Ws1[(size_t)(768 + k) * HID + (n - 1024)];
        u16 h, l; splitbf(v, h, l);
        W1Th[i] = h; W1Tl[i] = l;
    } else if (gi < 4194304) {
        int i = gi - 3145728;                 // over 1024*1024
        int n = i >> 10, k = i & 1023;
        u16 h, l; splitbf(Ws2[(size_t)k * HID + n], h, l);
        W2Th[i] = h; W2Tl[i] = l;
    } else if (gi < 5242880) {
        int i = gi - 4194304;                 // over 1024*1024
        int n = i >> 10, k = i & 1023;
        Wp2T[i] = f2bf(Wp2[(size_t)k * HID + n]);
    } else {
        int i = gi - 5242880;                 // over 4*1024*768
        int blk = i / 786432;
        int rem = i - blk * 786432;
        int n = rem / 768, k = rem - n * 768;
        const int roff[4] = {0, 768, 1561, 2329};   // (T,p0),(T,p1),(O,p0),(O,p1)
        Wp1T4[i] = f2bf(Wp1[(size_t)(roff[blk] + k) * HID + n]);
    }
}

// ---------------------------------------------------------------------------
// Error-compensated split-bf16 MFMA GEMM: C = AhBh + AlBh + AhBl  (XALL path)
// 128x128 tile, BK=32, global_load_lds staging, XCD-aware grid.
// ---------------------------------------------------------------------------
__global__ __launch_bounds__(256) void k_gemm3bf(
    const u16* __restrict__ Ah, const u16* __restrict__ Al, int lda,
    const u16* __restrict__ BTh, const u16* __restrict__ BTl, int ldb,
    float* __restrict__ C, int ldc,
    int M, int K, int nby, int sft)
{
    int bx, by;
    xcd_map(blockIdx.x, sft, bx, by);
    if (by >= nby) return;
    __shared__ __align__(16) u16 sm[4 * 128 * 32];     // 32 KiB
    u16* sAh = sm;
    u16* sAl = sm + 4096;
    u16* sBh = sm + 8192;
    u16* sBl = sm + 12288;
    const int tid = threadIdx.x;
    const int bm = by * 128, bn = bx * 128;
    const int wave = tid >> 6, lane = tid & 63;
    const int wr = wave >> 1, wc = wave & 1;
    const int q = lane >> 4, tl = lane & 15;

    f32x4 zero = {0.f, 0.f, 0.f, 0.f};
    f32x4 acc[4][4];
#pragma unroll
    for (int i = 0; i < 4; ++i)
#pragma unroll
        for (int j = 0; j < 4; ++j) acc[i][j] = zero;

    const int srow = lane >> 2;
    const int scol = (lane & 3) * 8;
    int ra0 = bm + wave * 32 + srow;      if (ra0 >= M) ra0 = M - 1;
    int ra1 = bm + wave * 32 + 16 + srow; if (ra1 >= M) ra1 = M - 1;
    const int rb0 = bn + wave * 32 + srow;
    const int rb1 = bn + wave * 32 + 16 + srow;
    u16* dA0 = sAh + wave * 1024;  u16* dA1 = dA0 + 512;
    u16* dL0 = sAl + wave * 1024;  u16* dL1 = dL0 + 512;
    u16* dB0 = sBh + wave * 1024;  u16* dB1 = dB0 + 512;
    u16* dC0 = sBl + wave * 1024;  u16* dC1 = dC0 + 512;
    const u16* gA0 = Ah  + (size_t)ra0 * lda + scol;
    const u16* gA1 = Ah  + (size_t)ra1 * lda + scol;
    const u16* gL0 = Al  + (size_t)ra0 * lda + scol;
    const u16* gL1 = Al  + (size_t)ra1 * lda + scol;
    const u16* gB0 = BTh + (size_t)rb0 * ldb + scol;
    const u16* gB1 = BTh + (size_t)rb1 * ldb + scol;
    const u16* gC0 = BTl + (size_t)rb0 * ldb + scol;
    const u16* gC1 = BTl + (size_t)rb1 * ldb + scol;

    for (int k0 = 0; k0 < K; k0 += 32) {
        gld_lds16(gA0 + k0, dA0);
        gld_lds16(gA1 + k0, dA1);
        gld_lds16(gL0 + k0, dL0);
        gld_lds16(gL1 + k0, dL1);
        gld_lds16(gB0 + k0, dB0);
        gld_lds16(gB1 + k0, dB1);
        gld_lds16(gC0 + k0, dC0);
        gld_lds16(gC1 + k0, dC1);
        __syncthreads();
        bf16x8 ah[4], al[4], bh[4], bl[4];
#pragma unroll
        for (int t = 0; t < 4; ++t) {
            int arow = (wr*64 + t*16 + tl) * 32 + q*8;
            int brow = (wc*64 + t*16 + tl) * 32 + q*8;
            ah[t] = *(const bf16x8*)(&sAh[arow]);
            al[t] = *(const bf16x8*)(&sAl[arow]);
            bh[t] = *(const bf16x8*)(&sBh[brow]);
            bl[t] = *(const bf16x8*)(&sBl[brow]);
        }
#pragma unroll
        for (int ti = 0; ti < 4; ++ti)
#pragma unroll
            for (int tj = 0; tj < 4; ++tj) {
                acc[ti][tj] = __builtin_amdgcn_mfma_f32_16x16x32_bf16(ah[ti], bh[tj], acc[ti][tj], 0, 0, 0);
                acc[ti][tj] = __builtin_amdgcn_mfma_f32_16x16x32_bf16(al[ti], bh[tj], acc[ti][tj], 0, 0, 0);
                acc[ti][tj] = __builtin_amdgcn_mfma_f32_16x16x32_bf16(ah[ti], bl[tj], acc[ti][tj], 0, 0, 0);
            }
        __syncthreads();
    }
    // C/D layout: col = lane&15, row = (lane>>4)*4 + reg  [measured m89/m91]
#pragma unroll
    for (int ti = 0; ti < 4; ++ti) {
#pragma unroll
        for (int tj = 0; tj < 4; ++tj) {
            int gcol = bn + wc*64 + tj*16 + tl;
#pragma unroll
            for (int r = 0; r < 4; ++r) {
                int grow = bm + wr*64 + ti*16 + q*4 + r;
                if (grow >= M) continue;
                C[(size_t)grow * ldc + gcol] = acc[ti][tj][r];
            }
        }
    }
}

// ---------------------------------------------------------------------------
// Span layer-2 GEMM with FUSED layer-3 projection epilogue.
// h2 = relu(h1 @ Ws2 + bs2) never materialized: epilogue computes the block's
// partial logits l_c = sum_{cols in window} h2[row][col] * Ws3[col][c] and
// writes part[row][slot][3], slot = bx*2 + wc (16 slots cover N=1024).
// Deterministic (fixed order per slot; fixed-order reduce kernel follows).
// ---------------------------------------------------------------------------
__global__ __launch_bounds__(256) void k_span_l2(
    const u16* __restrict__ Ah, const u16* __restrict__ Al,
    const u16* __restrict__ BTh, const u16* __restrict__ BTl,
    const float* __restrict__ bs2, const float* __restrict__ Ws3,
    float* __restrict__ part, int M)
{
    int bx, by;
    xcd_map(blockIdx.x, 3, bx, by);
    if (by >= 127) return;
    __shared__ __align__(16) u16 sm[4 * 128 * 32];
    u16* sAh = sm;
    u16* sAl = sm + 4096;
    u16* sBh = sm + 8192;
    u16* sBl = sm + 12288;
    const int tid = threadIdx.x;
    const int bm = by * 128, bn = bx * 128;
    const int wave = tid >> 6, lane = tid & 63;
    const int wr = wave >> 1, wc = wave & 1;
    const int q = lane >> 4, tl = lane & 15;

    f32x4 zero = {0.f, 0.f, 0.f, 0.f};
    f32x4 acc[4][4];
#pragma unroll
    for (int i = 0; i < 4; ++i)
#pragma unroll
        for (int j = 0; j < 4; ++j) acc[i][j] = zero;

    const int srow = lane >> 2;
    const int scol = (lane & 3) * 8;
    int ra0 = bm + wave * 32 + srow;      if (ra0 >= M) ra0 = M - 1;
    int ra1 = bm + wave * 32 + 16 + srow; if (ra1 >= M) ra1 = M - 1;
    const int rb0 = bn + wave * 32 + srow;
    const int rb1 = bn + wave * 32 + 16 + srow;
    u16* dA0 = sAh + wave * 1024;  u16* dA1 = dA0 + 512;
    u16* dL0 = sAl + wave * 1024;  u16* dL1 = dL0 + 512;
    u16* dB0 = sBh + wave * 1024;  u16* dB1 = dB0 + 512;
    u16* dC0 = sBl + wave * 1024;  u16* dC1 = dC0 + 512;
    const u16* gA0 = Ah  + (size_t)ra0 * HID + scol;
    const u16* gA1 = Ah  + (size_t)ra1 * HID + scol;
    const u16* gL0 = Al  + (size_t)ra0 * HID + scol;
    const u16* gL1 = Al  + (size_t)ra1 * HID + scol;
    const u16* gB0 = BTh + (size_t)rb0 * HID + scol;
    const u16* gB1 = BTh + (size_t)rb1 * HID + scol;
    const u16* gC0 = BTl + (size_t)rb0 * HID + scol;
    const u16* gC1 = BTl + (size_t)rb1 * HID + scol;

    for (int k0 = 0; k0 < HID; k0 += 32) {
        gld_lds16(gA0 + k0, dA0);
        gld_lds16(gA1 + k0, dA1);
        gld_lds16(gL0 + k0, dL0);
        gld_lds16(gL1 + k0, dL1);
        gld_lds16(gB0 + k0, dB0);
        gld_lds16(gB1 + k0, dB1);
        gld_lds16(gC0 + k0, dC0);
        gld_lds16(gC1 + k0, dC1);
        __syncthreads();
        bf16x8 ah[4], al[4], bh[4], bl[4];
#pragma unroll
        for (int t = 0; t < 4; ++t) {
            int arow = (wr*64 + t*16 + tl) * 32 + q*8;
            int brow = (wc*64 + t*16 + tl) * 32 + q*8;
            ah[t] = *(const bf16x8*)(&sAh[arow]);
            al[t] = *(const bf16x8*)(&sAl[arow]);
            bh[t] = *(const bf16x8*)(&sBh[brow]);
            bl[t] = *(const bf16x8*)(&sBl[brow]);
        }
#pragma unroll
        for (int ti = 0; ti < 4; ++ti)
#pragma unroll
            for (int tj = 0; tj < 4; ++tj) {
                acc[ti][tj] = __builtin_amdgcn_mfma_f32_16x16x32_bf16(ah[ti], bh[tj], acc[ti][tj], 0, 0, 0);
                acc[ti][tj] = __builtin_amdgcn_mfma_f32_16x16x32_bf16(al[ti], bh[tj], acc[ti][tj], 0, 0, 0);
                acc[ti][tj] = __builtin_amdgcn_mfma_f32_16x16x32_bf16(ah[ti], bl[tj], acc[ti][tj], 0, 0, 0);
            }
        __syncthreads();
    }
    // fused L3: per row, partial dot over this wave's 64-col window
    const int slot = bx * 2 + wc;   // 0..15
#pragma unroll
    for (int ti = 0; ti < 4; ++ti) {
#pragma unroll
        for (int r = 0; r < 4; ++r) {
            int grow = bm + wr*64 + ti*16 + q*4 + r;
            float l0 = 0.f, l1 = 0.f, l2 = 0.f;
#pragma unroll
            for (int tj = 0; tj < 4; ++tj) {
                int gcol = bn + wc*64 + tj*16 + tl;
                float v = fmaxf(acc[ti][tj][r] + bs2[gcol], 0.f);
                const float* w3 = Ws3 + gcol * 3;
                l0 = fmaf(v, w3[0], l0);
                l1 = fmaf(v, w3[1], l1);
                l2 = fmaf(v, w3[2], l2);
            }
#pragma unroll
            for (int off = 8; off > 0; off >>= 1) {
                l0 += __shfl_down(l0, off, 16);
                l1 += __shfl_down(l1, off, 16);
                l2 += __shfl_down(l2, off, 16);
            }
            if (tl == 0 && grow < M) {
                float* dst = part + ((size_t)grow * 16 + slot) * 3;
                dst[0] = l0; dst[1] = l1; dst[2] = l2;
            }
        }
    }
}

// reduce 16 slots (fixed order) + softmax -> out[r*3+c]
__global__ __launch_bounds__(256) void k_span_red(
    const float* __restrict__ part, const float* __restrict__ bs3,
    float* __restrict__ out)
{
    int r = blockIdx.x * 256 + threadIdx.x;
    if (r >= 16160) return;
    const float* p = part + (size_t)r * 48;
    float s0 = bs3[0], s1 = bs3[1], s2 = bs3[2];
#pragma unroll
    for (int t = 0; t < 16; ++t) {
        s0 += p[t*3]; s1 += p[t*3+1]; s2 += p[t*3+2];
    }
    float m = fmaxf(s0, fmaxf(s1, s2));
    float e0 = expf(s0 - m), e1 = expf(s1 - m), e2 = expf(s2 - m);
    float inv = 1.f / (e0 + e1 + e2);
    float* o = out + (size_t)r * 3;
    o[0] = e0 * inv; o[1] = e1 * inv; o[2] = e2 * inv;
}

// ---------------------------------------------------------------------------
// Gathered pair layer-1, bf16 MFMA: TO[r] = xh[toks[r]]@B(p0) + xh[toks[1024+r]]@B(p1)
// ---------------------------------------------------------------------------
__global__ __launch_bounds__(256) void k_pairL1(
    const u16* __restrict__ xh, const u16* __restrict__ Wp1T4,
    float* __restrict__ TO, const int* __restrict__ toks)
{
    __shared__ __align__(16) u16 sm[2 * 64 * 32];   // A 4KB | B 4KB
    u16* sA = sm;
    u16* sB = sm + 2048;
    const int tid = threadIdx.x;
    const int bx = blockIdx.x & 15, by = blockIdx.x >> 4;
    const int bm = by * 64, bn = bx * 64;
    const int wave = tid >> 6, lane = tid & 63;
    const int wr = wave >> 1, wc = wave & 1;
    const int q = lane >> 4, tl = lane & 15;
    const bool isO = bm >= 512;

    f32x4 zero = {0.f, 0.f, 0.f, 0.f};
    f32x4 acc[2][2];
#pragma unroll
    for (int i = 0; i < 2; ++i)
#pragma unroll
        for (int j = 0; j < 2; ++j) acc[i][j] = zero;

    const int srow = tid >> 2;
    const int scol = (tid & 3) * 8;
    u16* dA = sA + wave * 512;
    u16* dB = sB + wave * 512;

#pragma unroll
    for (int p = 0; p < 2; ++p) {
        int arow = toks[bm + srow + p * 1024];    // per-lane row gather
        const u16* gA = xh + (size_t)arow * DIM + scol;
        const u16* gB = Wp1T4 + ((size_t)((isO ? 2 : 0) + p) * 1024 + bn + srow) * DIM + scol;
        for (int k0 = 0; k0 < DIM; k0 += 32) {
            gld_lds16(gA + k0, dA);
            gld_lds16(gB + k0, dB);
            __syncthreads();
            bf16x8 af[2], bf[2];
#pragma unroll
            for (int t = 0; t < 2; ++t) {
                af[t] = *(const bf16x8*)(&sA[(wr*32 + t*16 + tl) * 32 + q*8]);
                bf[t] = *(const bf16x8*)(&sB[(wc*32 + t*16 + tl) * 32 + q*8]);
            }
#pragma unroll
            for (int ti = 0; ti < 2; ++ti)
#pragma unroll
                for (int tj = 0; tj < 2; ++tj)
                    acc[ti][tj] = __builtin_amdgcn_mfma_f32_16x16x32_bf16(af[ti], bf[tj], acc[ti][tj], 0, 0, 0);
            __syncthreads();
        }
    }
#pragma unroll
    for (int ti = 0; ti < 2; ++ti) {
#pragma unroll
        for (int tj = 0; tj < 2; ++tj) {
            int gcol = bn + wc*32 + tj*16 + tl;
#pragma unroll
            for (int r = 0; r < 4; ++r) {
                int grow = bm + wr*32 + ti*16 + q*4 + r;
                TO[(size_t)grow * HID + gcol] = acc[ti][tj][r];
            }
        }
    }
}

// h1s = relu(XALL[b,start,0:1024] + XALL[b,end-1,1024:2048] + wtabS[w-1]) -> split bf16
__global__ __launch_bounds__(256) void k_build_h1s(
    const float* __restrict__ XALL, const float* __restrict__ wtabS,
    u16* __restrict__ h1h, u16* __restrict__ h1l)
{
    int r = blockIdx.x;                 // 0..16159
    int b = r / NSPAN, s = r - b * NSPAN;
    int st, en, w; span_decode(s, st, en, w);
    const float4* xs = (const float4*)(XALL + (size_t)(b*SEQ + st) * 2048);
    const float4* xe = (const float4*)(XALL + (size_t)(b*SEQ + en - 1) * 2048 + 1024);
    const float4* wt = (const float4*)(wtabS + (size_t)(w-1) * HID);
    int t = threadIdx.x;
    float4 a = xs[t], bz = xe[t], c = wt[t];
    float v0 = fmaxf(a.x + bz.x + c.x, 0.f);
    float v1 = fmaxf(a.y + bz.y + c.y, 0.f);
    float v2 = fmaxf(a.z + bz.z + c.z, 0.f);
    float v3 = fmaxf(a.w + bz.w + c.w, 0.f);
    u16 h0,l0,h1,l1,h2,l2,h3,l3;
    splitbf(v0,h0,l0); splitbf(v1,h1,l1); splitbf(v2,h2,l2); splitbf(v3,h3,l3);
    size_t base = (size_t)r * HID + t * 4;
    *(uint2*)(h1h + base) = make_uint2((u32)h0 | ((u32)h1 << 16), (u32)h2 | ((u32)h3 << 16));
    *(uint2*)(h1l + base) = make_uint2((u32)l0 | ((u32)l1 << 16), (u32)l2 | ((u32)l3 << 16));
}

// top-64 (descending, ties -> lower index) + fused token-rowmap build.
__global__ __launch_bounds__(256) void k_topk(
    const float* __restrict__ sp, int* __restrict__ t_idx, int* __restrict__ o_idx,
    int* __restrict__ toks)
{
    int b = blockIdx.x >> 1;
    int head = 1 + (blockIdx.x & 1);
    int* outp = (head == 1 ? t_idx : o_idx) + b * NZ;
    __shared__ float sc[NSPAN];
    __shared__ float swv[4];
    __shared__ int   swi[4];
    __shared__ int   sel[NZ];
    int tid = threadIdx.x, lane = tid & 63, wv = tid >> 6;
    for (int s = tid; s < NSPAN; s += 256)
        sc[s] = sp[((size_t)b * NSPAN + s) * 3 + head];
    __syncthreads();
    for (int it = 0; it < NZ; ++it) {
        float bv = -1e30f; int bi = 1 << 29;
        for (int s = tid; s < NSPAN; s += 256) {
            float v = sc[s];
            if (v > bv || (v == bv && s < bi)) { bv = v; bi = s; }
        }
#pragma unroll
        for (int off = 32; off > 0; off >>= 1) {
            float ov = __shfl_down(bv, off, 64);
            int   oi = __shfl_down(bi, off, 64);
            if (ov > bv || (ov == bv && oi < bi)) { bv = ov; bi = oi; }
        }
        if (lane == 0) { swv[wv] = bv; swi[wv] = bi; }
        __syncthreads();
        if (tid == 0) {
            float fv = swv[0]; int fi = swi[0];
#pragma unroll
            for (int wvi = 1; wvi < 4; ++wvi) {
                float ov = swv[wvi]; int oi = swi[wvi];
                if (ov > fv || (ov == fv && oi < fi)) { fv = ov; fi = oi; }
            }
            if (fi < 0 || fi >= NSPAN) fi = 0;
            outp[it] = fi; sel[it] = fi; sc[fi] = -1e30f;
        }
        __syncthreads();
    }
    if (tid < NZ) {
        int st, en, w; span_decode(sel[tid], st, en, w);
        int base = (head == 1 ? 0 : 512) + b * NZ + tid;
        toks[base] = b * SEQ + st;
        toks[1024 + base] = b * SEQ + en - 1;
    }
}

// h1_pair[row] = relu(T[b,i] + O[b,j] + wtabPt + wtabPo + dtab) -> bf16
__global__ __launch_bounds__(256) void k_build_h1p(
    const float* __restrict__ TO, const int* __restrict__ t_idx, const int* __restrict__ o_idx,
    const float* __restrict__ wtabPt, const float* __restrict__ wtabPo,
    const float* __restrict__ dtab, u16* __restrict__ h1p)
{
    int row = blockIdx.x;               // b*4096 + i*64 + j
    int b = row >> 12, i = (row >> 6) & 63, j = row & 63;
    int ts = t_idx[b*64 + i], os = o_idx[b*64 + j];
    int ta, tb, wt, oc, od, wo;
    span_decode(ts, ta, tb, wt);
    span_decode(os, oc, od, wo);
    int d1 = tb - oc; d1 = d1 < 0 ? -d1 : d1;
    int d2 = ta - od; d2 = d2 < 0 ? -d2 : d2;
    int dist = d1 < d2 ? d1 : d2;
    int db = dbucket(dist);
    const float4* T4 = (const float4*)(TO + (size_t)(b*64 + i) * HID);
    const float4* O4 = (const float4*)(TO + (size_t)(512 + b*64 + j) * HID);
    const float4* P4 = (const float4*)(wtabPt + (size_t)(wt-1) * HID);
    const float4* Q4 = (const float4*)(wtabPo + (size_t)(wo-1) * HID);
    const float4* D4 = (const float4*)(dtab + (size_t)db * HID);
    int t = threadIdx.x;
    float4 a = T4[t], c = O4[t], p = P4[t], q = Q4[t], d = D4[t];
    float vx = fmaxf(a.x + c.x + p.x + q.x + d.x, 0.f);
    float vy = fmaxf(a.y + c.y + p.y + q.y + d.y, 0.f);
    float vz = fmaxf(a.z + c.z + p.z + q.z + d.z, 0.f);
    float vw = fmaxf(a.w + c.w + p.w + q.w + d.w, 0.f);
    u32 p0 = (u32)f2bf(vx) | ((u32)f2bf(vy) << 16);
    u32 p1 = (u32)f2bf(vz) | ((u32)f2bf(vw) << 16);
    *(uint2*)(h1p + (size_t)row * HID + t * 4) = make_uint2(p0, p1);
}

// pair layer2 with FUSED layer-3 projection epilogue (h2p never materialized):
// part[row][slot][4], slot = bx*2 + wc. Deterministic.
__global__ __launch_bounds__(256) void k_pair_l2(
    const u16* __restrict__ Abf, const u16* __restrict__ BT,
    const float* __restrict__ bp2, const float* __restrict__ Wp3,
    float* __restrict__ part)
{
    int bx, by;
    xcd_map(blockIdx.x, 3, bx, by);
    __shared__ __align__(16) u16 sm[2 * 128 * 32];     // 16 KiB
    u16* As = sm;
    u16* Bs = sm + 4096;
    const int tid = threadIdx.x;
    const int bm = by * 128, bn = bx * 128;
    const int wave = tid >> 6, lane = tid & 63;
    const int wr = wave >> 1, wc = wave & 1;
    const int q = lane >> 4, tl = lane & 15;

    f32x4 zero = {0.f, 0.f, 0.f, 0.f};
    f32x4 acc[4][4];
#pragma unroll
    for (int i = 0; i < 4; ++i)
#pragma unroll
        for (int j = 0; j < 4; ++j) acc[i][j] = zero;

    const int srow = lane >> 2;
    const int scol = (lane & 3) * 8;
    const u16* gA0 = Abf + (size_t)(bm + wave*32 + srow) * 1024 + scol;
    const u16* gA1 = Abf + (size_t)(bm + wave*32 + 16 + srow) * 1024 + scol;
    const u16* gB0 = BT  + (size_t)(bn + wave*32 + srow) * 1024 + scol;
    const u16* gB1 = BT  + (size_t)(bn + wave*32 + 16 + srow) * 1024 + scol;
    u16* dA0 = As + wave * 1024;  u16* dA1 = dA0 + 512;
    u16* dB0 = Bs + wave * 1024;  u16* dB1 = dB0 + 512;

    for (int k0 = 0; k0 < 1024; k0 += 32) {
        gld_lds16(gA0 + k0, dA0);
        gld_lds16(gA1 + k0, dA1);
        gld_lds16(gB0 + k0, dB0);
        gld_lds16(gB1 + k0, dB1);
        __syncthreads();
        bf16x8 af[4], bf[4];
#pragma unroll
        for (int t = 0; t < 4; ++t) {
            af[t] = *(const bf16x8*)(&As[(wr*64 + t*16 + tl) * 32 + q*8]);
            bf[t] = *(const bf16x8*)(&Bs[(wc*64 + t*16 + tl) * 32 + q*8]);
        }
#pragma unroll
        for (int ti = 0; ti < 4; ++ti)
#pragma unroll
            for (int tj = 0; tj < 4; ++tj)
                acc[ti][tj] = __builtin_amdgcn_mfma_f32_16x16x32_bf16(af[ti], bf[tj], acc[ti][tj], 0, 0, 0);
        __syncthreads();
    }
    // fused L3 projection
    const int slot = bx * 2 + wc;   // 0..15
#pragma unroll
    for (int ti = 0; ti < 4; ++ti) {
#pragma unroll
        for (int r = 0; r < 4; ++r) {
            int grow = bm + wr*64 + ti*16 + q*4 + r;
            float l0 = 0.f, l1 = 0.f, l2 = 0.f, l3 = 0.f;
#pragma unroll
            for (int tj = 0; tj < 4; ++tj) {
                int gcol = bn + wc*64 + tj*16 + tl;
                float v = fmaxf(acc[ti][tj][r] + bp2[gcol], 0.f);
                const float4 w = *(const float4*)(Wp3 + gcol * 4);
                l0 = fmaf(v, w.x, l0); l1 = fmaf(v, w.y, l1);
                l2 = fmaf(v, w.z, l2); l3 = fmaf(v, w.w, l3);
            }
#pragma unroll
            for (int off = 8; off > 0; off >>= 1) {
                l0 += __shfl_down(l0, off, 16);
                l1 += __shfl_down(l1, off, 16);
                l2 += __shfl_down(l2, off, 16);
                l3 += __shfl_down(l3, off, 16);
            }
            if (tl == 0) {
                float* dst = part + ((size_t)grow * 16 + slot) * 4;
                dst[0] = l0; dst[1] = l1; dst[2] = l2; dst[3] = l3;
            }
        }
    }
}

// reduce 16 slots (fixed order) + softmax -> out[48480 + r*4 + c]
__global__ __launch_bounds__(256) void k_pair_red(
    const float* __restrict__ part, const float* __restrict__ bp3,
    float* __restrict__ out)
{
    int r = blockIdx.x * 256 + threadIdx.x;   // 32768 = 128*256 exact
    const float4* p = (const float4*)(part + (size_t)r * 64);
    float s0 = bp3[0], s1 = bp3[1], s2 = bp3[2], s3 = bp3[3];
#pragma unroll
    for (int t = 0; t < 16; ++t) {
        float4 v = p[t];
        s0 += v.x; s1 += v.y; s2 += v.z; s3 += v.w;
    }
    float m = fmaxf(fmaxf(s0, s1), fmaxf(s2, s3));
    float e0 = expf(s0 - m), e1 = expf(s1 - m), e2 = expf(s2 - m), e3 = expf(s3 - m);
    float inv = 1.f / (e0 + e1 + e2 + e3);
    float* o = out + (size_t)r * 4;
    o[0] = e0 * inv; o[1] = e1 * inv; o[2] = e2 * inv; o[3] = e3 * inv;
}

extern "C" void kernel_launch(void* const* d_in, const int* in_sizes, int n_in,
                              void* d_out, int out_size, void* d_ws, size_t ws_size,
                              hipStream_t stream)
{
    const float* x    = (const float*)d_in[0];
    const float* wemb = (const float*)d_in[1];
    const float* demb = (const float*)d_in[2];
    const float* Ws1  = (const float*)d_in[3];
    const float* bs1  = (const float*)d_in[4];
    const float* Ws2  = (const float*)d_in[5];
    const float* bs2  = (const float*)d_in[6];
    const float* Ws3  = (const float*)d_in[7];
    const float* bs3  = (const float*)d_in[8];
    const float* Wp1  = (const float*)d_in[9];
    const float* bp1  = (const float*)d_in[10];
    const float* Wp2  = (const float*)d_in[11];
    const float* bp2  = (const float*)d_in[12];
    const float* Wp3  = (const float*)d_in[13];
    const float* bp3  = (const float*)d_in[14];
    float* out = (float*)d_out;
    char* ws = (char*)d_ws;

    // ---- workspace arena, lifetime-aliased ----
    // R1 (64 MiB): h1h+h1l (dead after k_span_l2)
    // R2 (64 MiB): [XALL | xl | W1Th | W1Tl] (dead after build_h1s) -> h1p
    // xh PERSISTENT (read by k_pairL1 late).
    const size_t RSZ = (size_t)32768 * HID * 2;   // 64 MiB
    size_t off = 0;
    auto alloc = [&](size_t bytes) -> void* {
        void* p = ws + off;
        off += (bytes + 255) & ~(size_t)255;
        return p;
    };
    char* R1 = (char*)alloc(RSZ);
    char* R2 = (char*)alloc(RSZ);
    u16*   h1h  = (u16*)R1;                              // 33.1 MB
    u16*   h1l  = (u16*)(R1 + (size_t)16160 * HID * 2);  // 33.1 MB
    float* XALL = (float*)R2;                            // 16 MiB
    u16*   xl   = (u16*)(R2 + (16u << 20));              // 3 MB
    u16*   W1Th = (u16*)(R2 + (19u << 20));              // 3 MB
    u16*   W1Tl = (u16*)(R2 + (22u << 20));              // 3 MB
    u16*   h1p  = (u16*)R2;                              // 64 MiB (after the above dead)
    u16*   xh     = (u16*)alloc((size_t)2048 * DIM * 2);     // 3 MB PERSISTENT
    float* TO     = (float*)alloc((size_t)1024 * HID * 4);
    float* partS  = (float*)alloc((size_t)16160 * 16 * 3 * 4);   // 3.1 MB
    float* partP  = (float*)alloc((size_t)32768 * 16 * 4 * 4);   // 8.4 MB
    u16*   W2Th   = (u16*)alloc((size_t)1024 * 1024 * 2);
    u16*   W2Tl   = (u16*)alloc((size_t)1024 * 1024 * 2);
    u16*   Wp2T   = (u16*)alloc((size_t)1024 * 1024 * 2);
    u16*   Wp1T4  = (u16*)alloc((size_t)4 * 1024 * 768 * 2);
    float* wtabS  = (float*)alloc(8 * HID * 4);
    float* wtabPt = (float*)alloc(8 * HID * 4);
    float* wtabPo = (float*)alloc(8 * HID * 4);
    float* dtab   = (float*)alloc(14 * HID * 4);
    int*   t_idx  = (int*)alloc(BATCH * NZ * 4);
    int*   o_idx  = (int*)alloc(BATCH * NZ * 4);
    int*   toks   = (int*)alloc(2048 * 4);
    (void)ws_size; (void)in_sizes; (void)n_in; (void)out_size;

    // prep: tables + all bf16 splits/transposes
    k_tables<<<dim3(4, 38), 256, 0, stream>>>(wemb, demb, Ws1, bs1, Wp1, bp1,
                                              wtabS, wtabPt, wtabPo, dtab);
    k_prep<<<32768, 256, 0, stream>>>(x, xh, xl, Ws1, W1Th, W1Tl,
                                      Ws2, W2Th, W2Tl, Wp2, Wp2T, Wp1, Wp1T4);

    // layer-1 factorization: XALL = x2d @ [Ws1_top | Ws1_mid] (3-pass split-bf16)
    k_gemm3bf<<<256, 256, 0, stream>>>(xh, xl, 768, W1Th, W1Tl, 768,
                                       XALL, 2048, 2048, 768, 16, 4);
    k_build_h1s<<<16160, 256, 0, stream>>>(XALL, wtabS, h1h, h1l);
    // span layer2 + FUSED layer3 partials (3-pass split-bf16, deterministic)
    k_span_l2<<<1024, 256, 0, stream>>>(h1h, h1l, W2Th, W2Tl, bs2, Ws3, partS, 16160);
    k_span_red<<<64, 256, 0, stream>>>(partS, bs3, out);
    k_topk<<<16, 256, 0, stream>>>(out, t_idx, o_idx, toks);
    // gathered pair layer-1: bf16 MFMA with per-lane row gather
    k_pairL1<<<256, 256, 0, stream>>>(xh, Wp1T4, TO, toks);
    k_build_h1p<<<32768, 256, 0, stream>>>(TO, t_idx, o_idx, wtabPt, wtabPo, dtab, h1p);
    // pair layer2 + FUSED layer3 partials (single-pass bf16)
    k_pair_l2<<<2048, 256, 0, stream>>>(h1p, Wp2T, bp2, Wp3, partP);
    k_pair_red<<<128, 256, 0, stream>>>(partP, bp3, out + 48480);
}

// Round 10
// 496.931 us; speedup vs baseline: 2.6304x; 1.1197x over previous
//
#include <hip/hip_runtime.h>
#include <cstdint>
#include <cstddef>

#define BATCH 8
#define SEQ   256
#define DIM   768
#define NSPAN 2020
#define HID   1024
#define NZ    64

typedef unsigned short u16;
typedef unsigned int   u32;
typedef unsigned long long u64;

typedef __bf16 bf16x8 __attribute__((ext_vector_type(8)));
typedef float  f32x4  __attribute__((ext_vector_type(4)));

__device__ __forceinline__ u16 f2bf(float f) {
    union { float f; u32 u; } x; x.f = f;
    u32 r = x.u + 0x7fffu + ((x.u >> 16) & 1u);
    return (u16)(r >> 16);
}
__device__ __forceinline__ float bf2f(u16 b) {
    union { u32 u; float f; } x; x.u = ((u32)b) << 16;
    return x.f;
}
// split v = hi + lo (both bf16); residual v-hi is exact in fp32
__device__ __forceinline__ void splitbf(float v, u16& h, u16& l) {
    h = f2bf(v);
    l = f2bf(v - bf2f(h));
}

// async global->LDS, 16B per lane; LDS dest = wave-uniform base + lane*16;
// global src may be per-lane (row gather OK) [m97/m104]
__device__ __forceinline__ void gld_lds16(const void* g, void* l) {
    __builtin_amdgcn_global_load_lds(
        (const __attribute__((address_space(1))) unsigned int*)g,
        (__attribute__((address_space(3))) unsigned int*)l, 16, 0, 0);
}

// span s -> (start, end, width); spans enumerated width-major: w=1..8, starts 0..L-w
__device__ __forceinline__ void span_decode(int s, int& start, int& end, int& w) {
    int off = 0;
#pragma unroll
    for (int wi = 1; wi <= 8; ++wi) {
        int cnt = SEQ - wi + 1;
        if (s < off + cnt) { w = wi; start = s - off; end = start + wi; return; }
        off += cnt;
    }
    w = 8; start = 0; end = 8;
}

// searchsorted(BUCKET_BINS, d, 'right') - 1
__device__ __forceinline__ int dbucket(int d) {
    int b = 0;
    b += (d >= 1);  b += (d >= 2);  b += (d >= 3);  b += (d >= 4);
    b += (d >= 5);  b += (d >= 7);  b += (d >= 8);  b += (d >= 15);
    b += (d >= 16); b += (d >= 31); b += (d >= 32); b += (d >= 63);
    b += (d >= 64);
    return b;
}

// XCD-aware deswizzle: (linear id) % 8 == by % 8 -> all column-blocks of one
// A-row-tile land on the SAME XCD (id%8 round-robin). sft = log2(nbx).
__device__ __forceinline__ void xcd_map(int L, int sft, int& bx, int& by) {
    int grp = L >> (3 + sft);
    int rem = L & ((1 << (3 + sft)) - 1);
    bx = rem >> 3;
    by = (grp << 3) | (rem & 7);
}

// ---------------------------------------------------------------------------
// Tiny per-bucket tables (width/dist embeddings only hit 14 rows).
// ---------------------------------------------------------------------------
__global__ __launch_bounds__(256) void k_tables(
    const float* __restrict__ wemb, const float* __restrict__ demb,
    const float* __restrict__ Ws1, const float* __restrict__ bs1,
    const float* __restrict__ Wp1, const float* __restrict__ bp1,
    float* __restrict__ wtabS, float* __restrict__ wtabPt,
    float* __restrict__ wtabPo, float* __restrict__ dtab)
{
    int h = blockIdx.x * 256 + threadIdx.x;   // 0..1023
    int row = blockIdx.y;                     // 0..37
    const int wb[8] = {1,2,3,4,5,5,6,7};      // width 1..8 -> bucket
    if (row < 8) {
        int bk = wb[row];
        float acc = bs1[h];
        for (int j = 0; j < 25; ++j) acc = fmaf(wemb[bk*25+j], Ws1[(size_t)(1536+j)*HID + h], acc);
        wtabS[row*HID + h] = acc;
    } else if (row < 16) {
        int bk = wb[row-8];
        float acc = 0.f;
        for (int j = 0; j < 25; ++j) acc = fmaf(wemb[bk*25+j], Wp1[(size_t)(1536+j)*HID + h], acc);
        wtabPt[(row-8)*HID + h] = acc;
    } else if (row < 24) {
        int bk = wb[row-16];
        float acc = 0.f;
        for (int j = 0; j < 25; ++j) acc = fmaf(wemb[bk*25+j], Wp1[(size_t)(3097+j)*HID + h], acc);
        wtabPo[(row-16)*HID + h] = acc;
    } else {
        int t = row - 24;                     // 0..13
        float acc = bp1[h];
        for (int j = 0; j < 25; ++j) acc = fmaf(demb[t*25+j], Wp1[(size_t)(3122+j)*HID + h], acc);
        dtab[t*HID + h] = acc;
    }
}

// ---------------------------------------------------------------------------
// Fused one-time prep (segmented flat index; boundaries multiple of 256).
// ---------------------------------------------------------------------------
__global__ __launch_bounds__(256) void k_prep(
    const float* __restrict__ x,  u16* __restrict__ xh,   u16* __restrict__ xl,
    const float* __restrict__ Ws1, u16* __restrict__ W1Th, u16* __restrict__ W1Tl,
    const float* __restrict__ Ws2, u16* __restrict__ W2Th, u16* __restrict__ W2Tl,
    const float* __restrict__ Wp2, u16* __restrict__ Wp2T,
    const float* __restrict__ Wp1, u16* __restrict__ Wp1T4)
{
    int gi = blockIdx.x * 256 + threadIdx.x;
    if (gi < 1572864) {
        int i = gi;
        u16 h, l; splitbf(x[i], h, l);
        xh[i] = h; xl[i] = l;
    } else if (gi < 3145728) {
        int i = gi - 1572864;                 // over 2048*768
        int n = i / 768, k = i - n * 768;
        float v = (n < 1024) ? Ws1[(size_t)k * HID + n]
                             : Ws1[(size_t)(768 + k) * HID + (n - 1024)];
        u16 h, l; splitbf(v, h, l);
        W1Th[i] = h; W1Tl[i] = l;
    } else if (gi < 4194304) {
        int i = gi - 3145728;                 // over 1024*1024
        int n = i >> 10, k = i & 1023;
        u16 h, l; splitbf(Ws2[(size_t)k * HID + n], h, l);
        W2Th[i] = h; W2Tl[i] = l;
    } else if (gi < 5242880) {
        int i = gi - 4194304;                 // over 1024*1024
        int n = i >> 10, k = i & 1023;
        Wp2T[i] = f2bf(Wp2[(size_t)k * HID + n]);
    } else {
        int i = gi - 5242880;                 // over 4*1024*768
        int blk = i / 786432;
        int rem = i - blk * 786432;
        int n = rem / 768, k = rem - n * 768;
        const int roff[4] = {0, 768, 1561, 2329};   // (T,p0),(T,p1),(O,p0),(O,p1)
        Wp1T4[i] = f2bf(Wp1[(size_t)(roff[blk] + k) * HID + n]);
    }
}

// ---------------------------------------------------------------------------
// Error-compensated split-bf16 MFMA GEMM: C = AhBh + AlBh + AhBl  (XALL path)
// 128x128 tile, BK=32, global_load_lds staging, XCD-aware grid.
// ---------------------------------------------------------------------------
__global__ __launch_bounds__(256) void k_gemm3bf(
    const u16* __restrict__ Ah, const u16* __restrict__ Al, int lda,
    const u16* __restrict__ BTh, const u16* __restrict__ BTl, int ldb,
    float* __restrict__ C, int ldc,
    int M, int K, int nby, int sft)
{
    int bx, by;
    xcd_map(blockIdx.x, sft, bx, by);
    if (by >= nby) return;
    __shared__ __align__(16) u16 sm[4 * 128 * 32];     // 32 KiB
    u16* sAh = sm;
    u16* sAl = sm + 4096;
    u16* sBh = sm + 8192;
    u16* sBl = sm + 12288;
    const int tid = threadIdx.x;
    const int bm = by * 128, bn = bx * 128;
    const int wave = tid >> 6, lane = tid & 63;
    const int wr = wave >> 1, wc = wave & 1;
    const int q = lane >> 4, tl = lane & 15;

    f32x4 zero = {0.f, 0.f, 0.f, 0.f};
    f32x4 acc[4][4];
#pragma unroll
    for (int i = 0; i < 4; ++i)
#pragma unroll
        for (int j = 0; j < 4; ++j) acc[i][j] = zero;

    const int srow = lane >> 2;
    const int scol = (lane & 3) * 8;
    int ra0 = bm + wave * 32 + srow;      if (ra0 >= M) ra0 = M - 1;
    int ra1 = bm + wave * 32 + 16 + srow; if (ra1 >= M) ra1 = M - 1;
    const int rb0 = bn + wave * 32 + srow;
    const int rb1 = bn + wave * 32 + 16 + srow;
    u16* dA0 = sAh + wave * 1024;  u16* dA1 = dA0 + 512;
    u16* dL0 = sAl + wave * 1024;  u16* dL1 = dL0 + 512;
    u16* dB0 = sBh + wave * 1024;  u16* dB1 = dB0 + 512;
    u16* dC0 = sBl + wave * 1024;  u16* dC1 = dC0 + 512;
    const u16* gA0 = Ah  + (size_t)ra0 * lda + scol;
    const u16* gA1 = Ah  + (size_t)ra1 * lda + scol;
    const u16* gL0 = Al  + (size_t)ra0 * lda + scol;
    const u16* gL1 = Al  + (size_t)ra1 * lda + scol;
    const u16* gB0 = BTh + (size_t)rb0 * ldb + scol;
    const u16* gB1 = BTh + (size_t)rb1 * ldb + scol;
    const u16* gC0 = BTl + (size_t)rb0 * ldb + scol;
    const u16* gC1 = BTl + (size_t)rb1 * ldb + scol;

    for (int k0 = 0; k0 < K; k0 += 32) {
        gld_lds16(gA0 + k0, dA0);
        gld_lds16(gA1 + k0, dA1);
        gld_lds16(gL0 + k0, dL0);
        gld_lds16(gL1 + k0, dL1);
        gld_lds16(gB0 + k0, dB0);
        gld_lds16(gB1 + k0, dB1);
        gld_lds16(gC0 + k0, dC0);
        gld_lds16(gC1 + k0, dC1);
        __syncthreads();
        bf16x8 ah[4], al[4], bh[4], bl[4];
#pragma unroll
        for (int t = 0; t < 4; ++t) {
            int arow = (wr*64 + t*16 + tl) * 32 + q*8;
            int brow = (wc*64 + t*16 + tl) * 32 + q*8;
            ah[t] = *(const bf16x8*)(&sAh[arow]);
            al[t] = *(const bf16x8*)(&sAl[arow]);
            bh[t] = *(const bf16x8*)(&sBh[brow]);
            bl[t] = *(const bf16x8*)(&sBl[brow]);
        }
#pragma unroll
        for (int ti = 0; ti < 4; ++ti)
#pragma unroll
            for (int tj = 0; tj < 4; ++tj) {
                acc[ti][tj] = __builtin_amdgcn_mfma_f32_16x16x32_bf16(ah[ti], bh[tj], acc[ti][tj], 0, 0, 0);
                acc[ti][tj] = __builtin_amdgcn_mfma_f32_16x16x32_bf16(al[ti], bh[tj], acc[ti][tj], 0, 0, 0);
                acc[ti][tj] = __builtin_amdgcn_mfma_f32_16x16x32_bf16(ah[ti], bl[tj], acc[ti][tj], 0, 0, 0);
            }
        __syncthreads();
    }
    // C/D layout: col = lane&15, row = (lane>>4)*4 + reg  [measured m89/m91]
#pragma unroll
    for (int ti = 0; ti < 4; ++ti) {
#pragma unroll
        for (int tj = 0; tj < 4; ++tj) {
            int gcol = bn + wc*64 + tj*16 + tl;
#pragma unroll
            for (int r = 0; r < 4; ++r) {
                int grow = bm + wr*64 + ti*16 + q*4 + r;
                if (grow >= M) continue;
                C[(size_t)grow * ldc + gcol] = acc[ti][tj][r];
            }
        }
    }
}

// ---------------------------------------------------------------------------
// Span layer-2 GEMM with FUSED layer-3 projection epilogue (deterministic).
// ---------------------------------------------------------------------------
__global__ __launch_bounds__(256) void k_span_l2(
    const u16* __restrict__ Ah, const u16* __restrict__ Al,
    const u16* __restrict__ BTh, const u16* __restrict__ BTl,
    const float* __restrict__ bs2, const float* __restrict__ Ws3,
    float* __restrict__ part, int M)
{
    int bx, by;
    xcd_map(blockIdx.x, 3, bx, by);
    if (by >= 127) return;
    __shared__ __align__(16) u16 sm[4 * 128 * 32];
    u16* sAh = sm;
    u16* sAl = sm + 4096;
    u16* sBh = sm + 8192;
    u16* sBl = sm + 12288;
    const int tid = threadIdx.x;
    const int bm = by * 128, bn = bx * 128;
    const int wave = tid >> 6, lane = tid & 63;
    const int wr = wave >> 1, wc = wave & 1;
    const int q = lane >> 4, tl = lane & 15;

    f32x4 zero = {0.f, 0.f, 0.f, 0.f};
    f32x4 acc[4][4];
#pragma unroll
    for (int i = 0; i < 4; ++i)
#pragma unroll
        for (int j = 0; j < 4; ++j) acc[i][j] = zero;

    const int srow = lane >> 2;
    const int scol = (lane & 3) * 8;
    int ra0 = bm + wave * 32 + srow;      if (ra0 >= M) ra0 = M - 1;
    int ra1 = bm + wave * 32 + 16 + srow; if (ra1 >= M) ra1 = M - 1;
    const int rb0 = bn + wave * 32 + srow;
    const int rb1 = bn + wave * 32 + 16 + srow;
    u16* dA0 = sAh + wave * 1024;  u16* dA1 = dA0 + 512;
    u16* dL0 = sAl + wave * 1024;  u16* dL1 = dL0 + 512;
    u16* dB0 = sBh + wave * 1024;  u16* dB1 = dB0 + 512;
    u16* dC0 = sBl + wave * 1024;  u16* dC1 = dC0 + 512;
    const u16* gA0 = Ah  + (size_t)ra0 * HID + scol;
    const u16* gA1 = Ah  + (size_t)ra1 * HID + scol;
    const u16* gL0 = Al  + (size_t)ra0 * HID + scol;
    const u16* gL1 = Al  + (size_t)ra1 * HID + scol;
    const u16* gB0 = BTh + (size_t)rb0 * HID + scol;
    const u16* gB1 = BTh + (size_t)rb1 * HID + scol;
    const u16* gC0 = BTl + (size_t)rb0 * HID + scol;
    const u16* gC1 = BTl + (size_t)rb1 * HID + scol;

    for (int k0 = 0; k0 < HID; k0 += 32) {
        gld_lds16(gA0 + k0, dA0);
        gld_lds16(gA1 + k0, dA1);
        gld_lds16(gL0 + k0, dL0);
        gld_lds16(gL1 + k0, dL1);
        gld_lds16(gB0 + k0, dB0);
        gld_lds16(gB1 + k0, dB1);
        gld_lds16(gC0 + k0, dC0);
        gld_lds16(gC1 + k0, dC1);
        __syncthreads();
        bf16x8 ah[4], al[4], bh[4], bl[4];
#pragma unroll
        for (int t = 0; t < 4; ++t) {
            int arow = (wr*64 + t*16 + tl) * 32 + q*8;
            int brow = (wc*64 + t*16 + tl) * 32 + q*8;
            ah[t] = *(const bf16x8*)(&sAh[arow]);
            al[t] = *(const bf16x8*)(&sAl[arow]);
            bh[t] = *(const bf16x8*)(&sBh[brow]);
            bl[t] = *(const bf16x8*)(&sBl[brow]);
        }
#pragma unroll
        for (int ti = 0; ti < 4; ++ti)
#pragma unroll
            for (int tj = 0; tj < 4; ++tj) {
                acc[ti][tj] = __builtin_amdgcn_mfma_f32_16x16x32_bf16(ah[ti], bh[tj], acc[ti][tj], 0, 0, 0);
                acc[ti][tj] = __builtin_amdgcn_mfma_f32_16x16x32_bf16(al[ti], bh[tj], acc[ti][tj], 0, 0, 0);
                acc[ti][tj] = __builtin_amdgcn_mfma_f32_16x16x32_bf16(ah[ti], bl[tj], acc[ti][tj], 0, 0, 0);
            }
        __syncthreads();
    }
    // fused L3: per row, partial dot over this wave's 64-col window
    const int slot = bx * 2 + wc;   // 0..15
#pragma unroll
    for (int ti = 0; ti < 4; ++ti) {
#pragma unroll
        for (int r = 0; r < 4; ++r) {
            int grow = bm + wr*64 + ti*16 + q*4 + r;
            float l0 = 0.f, l1 = 0.f, l2 = 0.f;
#pragma unroll
            for (int tj = 0; tj < 4; ++tj) {
                int gcol = bn + wc*64 + tj*16 + tl;
                float v = fmaxf(acc[ti][tj][r] + bs2[gcol], 0.f);
                const float* w3 = Ws3 + gcol * 3;
                l0 = fmaf(v, w3[0], l0);
                l1 = fmaf(v, w3[1], l1);
                l2 = fmaf(v, w3[2], l2);
            }
#pragma unroll
            for (int off = 8; off > 0; off >>= 1) {
                l0 += __shfl_down(l0, off, 16);
                l1 += __shfl_down(l1, off, 16);
                l2 += __shfl_down(l2, off, 16);
            }
            if (tl == 0 && grow < M) {
                float* dst = part + ((size_t)grow * 16 + slot) * 3;
                dst[0] = l0; dst[1] = l1; dst[2] = l2;
            }
        }
    }
}

// reduce 16 slots (fixed order) + softmax -> out[r*3+c]
__global__ __launch_bounds__(256) void k_span_red(
    const float* __restrict__ part, const float* __restrict__ bs3,
    float* __restrict__ out)
{
    int r = blockIdx.x * 256 + threadIdx.x;
    if (r >= 16160) return;
    const float* p = part + (size_t)r * 48;
    float s0 = bs3[0], s1 = bs3[1], s2 = bs3[2];
#pragma unroll
    for (int t = 0; t < 16; ++t) {
        s0 += p[t*3]; s1 += p[t*3+1]; s2 += p[t*3+2];
    }
    float m = fmaxf(s0, fmaxf(s1, s2));
    float e0 = expf(s0 - m), e1 = expf(s1 - m), e2 = expf(s2 - m);
    float inv = 1.f / (e0 + e1 + e2);
    float* o = out + (size_t)r * 3;
    o[0] = e0 * inv; o[1] = e1 * inv; o[2] = e2 * inv;
}

// ---------------------------------------------------------------------------
// Gathered pair layer-1, bf16 MFMA: TO[r] = xh[toks[r]]@B(p0) + xh[toks[1024+r]]@B(p1)
// ---------------------------------------------------------------------------
__global__ __launch_bounds__(256) void k_pairL1(
    const u16* __restrict__ xh, const u16* __restrict__ Wp1T4,
    float* __restrict__ TO, const int* __restrict__ toks)
{
    __shared__ __align__(16) u16 sm[2 * 64 * 32];   // A 4KB | B 4KB
    u16* sA = sm;
    u16* sB = sm + 2048;
    const int tid = threadIdx.x;
    const int bx = blockIdx.x & 15, by = blockIdx.x >> 4;
    const int bm = by * 64, bn = bx * 64;
    const int wave = tid >> 6, lane = tid & 63;
    const int wr = wave >> 1, wc = wave & 1;
    const int q = lane >> 4, tl = lane & 15;
    const bool isO = bm >= 512;

    f32x4 zero = {0.f, 0.f, 0.f, 0.f};
    f32x4 acc[2][2];
#pragma unroll
    for (int i = 0; i < 2; ++i)
#pragma unroll
        for (int j = 0; j < 2; ++j) acc[i][j] = zero;

    const int srow = tid >> 2;
    const int scol = (tid & 3) * 8;
    u16* dA = sA + wave * 512;
    u16* dB = sB + wave * 512;

#pragma unroll
    for (int p = 0; p < 2; ++p) {
        int arow = toks[bm + srow + p * 1024];    // per-lane row gather
        const u16* gA = xh + (size_t)arow * DIM + scol;
        const u16* gB = Wp1T4 + ((size_t)((isO ? 2 : 0) + p) * 1024 + bn + srow) * DIM + scol;
        for (int k0 = 0; k0 < DIM; k0 += 32) {
            gld_lds16(gA + k0, dA);
            gld_lds16(gB + k0, dB);
            __syncthreads();
            bf16x8 af[2], bf[2];
#pragma unroll
            for (int t = 0; t < 2; ++t) {
                af[t] = *(const bf16x8*)(&sA[(wr*32 + t*16 + tl) * 32 + q*8]);
                bf[t] = *(const bf16x8*)(&sB[(wc*32 + t*16 + tl) * 32 + q*8]);
            }
#pragma unroll
            for (int ti = 0; ti < 2; ++ti)
#pragma unroll
                for (int tj = 0; tj < 2; ++tj)
                    acc[ti][tj] = __builtin_amdgcn_mfma_f32_16x16x32_bf16(af[ti], bf[tj], acc[ti][tj], 0, 0, 0);
            __syncthreads();
        }
    }
#pragma unroll
    for (int ti = 0; ti < 2; ++ti) {
#pragma unroll
        for (int tj = 0; tj < 2; ++tj) {
            int gcol = bn + wc*32 + tj*16 + tl;
#pragma unroll
            for (int r = 0; r < 4; ++r) {
                int grow = bm + wr*32 + ti*16 + q*4 + r;
                TO[(size_t)grow * HID + gcol] = acc[ti][tj][r];
            }
        }
    }
}

// h1s = relu(XALL[b,start,0:1024] + XALL[b,end-1,1024:2048] + wtabS[w-1]) -> split bf16
__global__ __launch_bounds__(256) void k_build_h1s(
    const float* __restrict__ XALL, const float* __restrict__ wtabS,
    u16* __restrict__ h1h, u16* __restrict__ h1l)
{
    int r = blockIdx.x;                 // 0..16159
    int b = r / NSPAN, s = r - b * NSPAN;
    int st, en, w; span_decode(s, st, en, w);
    const float4* xs = (const float4*)(XALL + (size_t)(b*SEQ + st) * 2048);
    const float4* xe = (const float4*)(XALL + (size_t)(b*SEQ + en - 1) * 2048 + 1024);
    const float4* wt = (const float4*)(wtabS + (size_t)(w-1) * HID);
    int t = threadIdx.x;
    float4 a = xs[t], bz = xe[t], c = wt[t];
    float v0 = fmaxf(a.x + bz.x + c.x, 0.f);
    float v1 = fmaxf(a.y + bz.y + c.y, 0.f);
    float v2 = fmaxf(a.z + bz.z + c.z, 0.f);
    float v3 = fmaxf(a.w + bz.w + c.w, 0.f);
    u16 h0,l0,h1,l1,h2,l2,h3,l3;
    splitbf(v0,h0,l0); splitbf(v1,h1,l1); splitbf(v2,h2,l2); splitbf(v3,h3,l3);
    size_t base = (size_t)r * HID + t * 4;
    *(uint2*)(h1h + base) = make_uint2((u32)h0 | ((u32)h1 << 16), (u32)h2 | ((u32)h3 << 16));
    *(uint2*)(h1l + base) = make_uint2((u32)l0 | ((u32)l1 << 16), (u32)l2 | ((u32)l3 << 16));
}

// ---------------------------------------------------------------------------
// top-64 via in-LDS bitonic sort of 2048 packed u64 keys (canonical form).
// key = (fbits(prob) << 32) | (0xFFFFFFFF - s): probs >= 0 so fbits is
// order-monotone; complemented index gives jax tie-break (lowest s first)
// under descending order. Pads (s>=NSPAN) have value-bits 0 -> lose to all
// real entries. Deterministic. + fused token-rowmap build.
// ---------------------------------------------------------------------------
__global__ __launch_bounds__(256) void k_topk(
    const float* __restrict__ sp, int* __restrict__ t_idx, int* __restrict__ o_idx,
    int* __restrict__ toks)
{
    int b = blockIdx.x >> 1;
    int head = 1 + (blockIdx.x & 1);
    int* outp = (head == 1 ? t_idx : o_idx) + b * NZ;
    __shared__ u64 keys[2048];
    int tid = threadIdx.x;
#pragma unroll
    for (int ii = 0; ii < 8; ++ii) {
        int s = tid + ii * 256;
        u32 fb = 0;
        if (s < NSPAN) {
            union { float f; u32 u; } x;
            x.f = sp[((size_t)b * NSPAN + s) * 3 + head];
            fb = x.u;
        }
        keys[s] = ((u64)fb << 32) | (u64)(0xFFFFFFFFu - (u32)s);
    }
    __syncthreads();
    // canonical bitonic sort, DESCENDING overall:
    // block dir at stage k: descending iff (i & k) == 0; final k=2048 -> all desc.
    for (int k = 2; k <= 2048; k <<= 1) {
        for (int j = k >> 1; j > 0; j >>= 1) {
#pragma unroll
            for (int ii = 0; ii < 8; ++ii) {
                int i = tid + ii * 256;
                int ixj = i ^ j;
                if (ixj > i) {
                    u64 a = keys[i], c = keys[ixj];
                    bool desc = (i & k) == 0;
                    bool wrong = desc ? (a < c) : (a > c);
                    if (wrong) { keys[i] = c; keys[ixj] = a; }
                }
            }
            __syncthreads();
        }
    }
    if (tid < NZ) {
        u64 key = keys[tid];
        int fi = (int)(0xFFFFFFFFu - (u32)(key & 0xFFFFFFFFu));
        if (fi < 0 || fi >= NSPAN) fi = 0;   // paranoia
        outp[tid] = fi;
        int st, en, w; span_decode(fi, st, en, w);
        int base = (head == 1 ? 0 : 512) + b * NZ + tid;
        toks[base] = b * SEQ + st;
        toks[1024 + base] = b * SEQ + en - 1;
    }
}

// h1_pair[row] = relu(T[b,i] + O[b,j] + wtabPt + wtabPo + dtab) -> bf16
__global__ __launch_bounds__(256) void k_build_h1p(
    const float* __restrict__ TO, const int* __restrict__ t_idx, const int* __restrict__ o_idx,
    const float* __restrict__ wtabPt, const float* __restrict__ wtabPo,
    const float* __restrict__ dtab, u16* __restrict__ h1p)
{
    int row = blockIdx.x;               // b*4096 + i*64 + j
    int b = row >> 12, i = (row >> 6) & 63, j = row & 63;
    int ts = t_idx[b*64 + i], os = o_idx[b*64 + j];
    int ta, tb, wt, oc, od, wo;
    span_decode(ts, ta, tb, wt);
    span_decode(os, oc, od, wo);
    int d1 = tb - oc; d1 = d1 < 0 ? -d1 : d1;
    int d2 = ta - od; d2 = d2 < 0 ? -d2 : d2;
    int dist = d1 < d2 ? d1 : d2;
    int db = dbucket(dist);
    const float4* T4 = (const float4*)(TO + (size_t)(b*64 + i) * HID);
    const float4* O4 = (const float4*)(TO + (size_t)(512 + b*64 + j) * HID);
    const float4* P4 = (const float4*)(wtabPt + (size_t)(wt-1) * HID);
    const float4* Q4 = (const float4*)(wtabPo + (size_t)(wo-1) * HID);
    const float4* D4 = (const float4*)(dtab + (size_t)db * HID);
    int t = threadIdx.x;
    float4 a = T4[t], c = O4[t], p = P4[t], q = Q4[t], d = D4[t];
    float vx = fmaxf(a.x + c.x + p.x + q.x + d.x, 0.f);
    float vy = fmaxf(a.y + c.y + p.y + q.y + d.y, 0.f);
    float vz = fmaxf(a.z + c.z + p.z + q.z + d.z, 0.f);
    float vw = fmaxf(a.w + c.w + p.w + q.w + d.w, 0.f);
    u32 p0 = (u32)f2bf(vx) | ((u32)f2bf(vy) << 16);
    u32 p1 = (u32)f2bf(vz) | ((u32)f2bf(vw) << 16);
    *(uint2*)(h1p + (size_t)row * HID + t * 4) = make_uint2(p0, p1);
}

// pair layer2 with FUSED layer-3 projection epilogue (h2p never materialized).
__global__ __launch_bounds__(256) void k_pair_l2(
    const u16* __restrict__ Abf, const u16* __restrict__ BT,
    const float* __restrict__ bp2, const float* __restrict__ Wp3,
    float* __restrict__ part)
{
    int bx, by;
    xcd_map(blockIdx.x, 3, bx, by);
    __shared__ __align__(16) u16 sm[2 * 128 * 32];     // 16 KiB
    u16* As = sm;
    u16* Bs = sm + 4096;
    const int tid = threadIdx.x;
    const int bm = by * 128, bn = bx * 128;
    const int wave = tid >> 6, lane = tid & 63;
    const int wr = wave >> 1, wc = wave & 1;
    const int q = lane >> 4, tl = lane & 15;

    f32x4 zero = {0.f, 0.f, 0.f, 0.f};
    f32x4 acc[4][4];
#pragma unroll
    for (int i = 0; i < 4; ++i)
#pragma unroll
        for (int j = 0; j < 4; ++j) acc[i][j] = zero;

    const int srow = lane >> 2;
    const int scol = (lane & 3) * 8;
    const u16* gA0 = Abf + (size_t)(bm + wave*32 + srow) * 1024 + scol;
    const u16* gA1 = Abf + (size_t)(bm + wave*32 + 16 + srow) * 1024 + scol;
    const u16* gB0 = BT  + (size_t)(bn + wave*32 + srow) * 1024 + scol;
    const u16* gB1 = BT  + (size_t)(bn + wave*32 + 16 + srow) * 1024 + scol;
    u16* dA0 = As + wave * 1024;  u16* dA1 = dA0 + 512;
    u16* dB0 = Bs + wave * 1024;  u16* dB1 = dB0 + 512;

    for (int k0 = 0; k0 < 1024; k0 += 32) {
        gld_lds16(gA0 + k0, dA0);
        gld_lds16(gA1 + k0, dA1);
        gld_lds16(gB0 + k0, dB0);
        gld_lds16(gB1 + k0, dB1);
        __syncthreads();
        bf16x8 af[4], bf[4];
#pragma unroll
        for (int t = 0; t < 4; ++t) {
            af[t] = *(const bf16x8*)(&As[(wr*64 + t*16 + tl) * 32 + q*8]);
            bf[t] = *(const bf16x8*)(&Bs[(wc*64 + t*16 + tl) * 32 + q*8]);
        }
#pragma unroll
        for (int ti = 0; ti < 4; ++ti)
#pragma unroll
            for (int tj = 0; tj < 4; ++tj)
                acc[ti][tj] = __builtin_amdgcn_mfma_f32_16x16x32_bf16(af[ti], bf[tj], acc[ti][tj], 0, 0, 0);
        __syncthreads();
    }
    // fused L3 projection
    const int slot = bx * 2 + wc;   // 0..15
#pragma unroll
    for (int ti = 0; ti < 4; ++ti) {
#pragma unroll
        for (int r = 0; r < 4; ++r) {
            int grow = bm + wr*64 + ti*16 + q*4 + r;
            float l0 = 0.f, l1 = 0.f, l2 = 0.f, l3 = 0.f;
#pragma unroll
            for (int tj = 0; tj < 4; ++tj) {
                int gcol = bn + wc*64 + tj*16 + tl;
                float v = fmaxf(acc[ti][tj][r] + bp2[gcol], 0.f);
                const float4 w = *(const float4*)(Wp3 + gcol * 4);
                l0 = fmaf(v, w.x, l0); l1 = fmaf(v, w.y, l1);
                l2 = fmaf(v, w.z, l2); l3 = fmaf(v, w.w, l3);
            }
#pragma unroll
            for (int off = 8; off > 0; off >>= 1) {
                l0 += __shfl_down(l0, off, 16);
                l1 += __shfl_down(l1, off, 16);
                l2 += __shfl_down(l2, off, 16);
                l3 += __shfl_down(l3, off, 16);
            }
            if (tl == 0) {
                float* dst = part + ((size_t)grow * 16 + slot) * 4;
                dst[0] = l0; dst[1] = l1; dst[2] = l2; dst[3] = l3;
            }
        }
    }
}

// reduce 16 slots (fixed order) + softmax -> out[48480 + r*4 + c]
__global__ __launch_bounds__(256) void k_pair_red(
    const float* __restrict__ part, const float* __restrict__ bp3,
    float* __restrict__ out)
{
    int r = blockIdx.x * 256 + threadIdx.x;   // 32768 = 128*256 exact
    const float4* p = (const float4*)(part + (size_t)r * 64);
    float s0 = bp3[0], s1 = bp3[1], s2 = bp3[2], s3 = bp3[3];
#pragma unroll
    for (int t = 0; t < 16; ++t) {
        float4 v = p[t];
        s0 += v.x; s1 += v.y; s2 += v.z; s3 += v.w;
    }
    float m = fmaxf(fmaxf(s0, s1), fmaxf(s2, s3));
    float e0 = expf(s0 - m), e1 = expf(s1 - m), e2 = expf(s2 - m), e3 = expf(s3 - m);
    float inv = 1.f / (e0 + e1 + e2 + e3);
    float* o = out + (size_t)r * 4;
    o[0] = e0 * inv; o[1] = e1 * inv; o[2] = e2 * inv; o[3] = e3 * inv;
}

extern "C" void kernel_launch(void* const* d_in, const int* in_sizes, int n_in,
                              void* d_out, int out_size, void* d_ws, size_t ws_size,
                              hipStream_t stream)
{
    const float* x    = (const float*)d_in[0];
    const float* wemb = (const float*)d_in[1];
    const float* demb = (const float*)d_in[2];
    const float* Ws1  = (const float*)d_in[3];
    const float* bs1  = (const float*)d_in[4];
    const float* Ws2  = (const float*)d_in[5];
    const float* bs2  = (const float*)d_in[6];
    const float* Ws3  = (const float*)d_in[7];
    const float* bs3  = (const float*)d_in[8];
    const float* Wp1  = (const float*)d_in[9];
    const float* bp1  = (const float*)d_in[10];
    const float* Wp2  = (const float*)d_in[11];
    const float* bp2  = (const float*)d_in[12];
    const float* Wp3  = (const float*)d_in[13];
    const float* bp3  = (const float*)d_in[14];
    float* out = (float*)d_out;
    char* ws = (char*)d_ws;

    // ---- workspace arena, lifetime-aliased ----
    // R1 (64 MiB): h1h+h1l (dead after k_span_l2)
    // R2 (64 MiB): [XALL | xl | W1Th | W1Tl] (dead after build_h1s) -> h1p
    // xh PERSISTENT (read by k_pairL1 late).
    const size_t RSZ = (size_t)32768 * HID * 2;   // 64 MiB
    size_t off = 0;
    auto alloc = [&](size_t bytes) -> void* {
        void* p = ws + off;
        off += (bytes + 255) & ~(size_t)255;
        return p;
    };
    char* R1 = (char*)alloc(RSZ);
    char* R2 = (char*)alloc(RSZ);
    u16*   h1h  = (u16*)R1;                              // 33.1 MB
    u16*   h1l  = (u16*)(R1 + (size_t)16160 * HID * 2);  // 33.1 MB
    float* XALL = (float*)R2;                            // 16 MiB
    u16*   xl   = (u16*)(R2 + (16u << 20));              // 3 MB
    u16*   W1Th = (u16*)(R2 + (19u << 20));              // 3 MB
    u16*   W1Tl = (u16*)(R2 + (22u << 20));              // 3 MB
    u16*   h1p  = (u16*)R2;                              // 64 MiB (after the above dead)
    u16*   xh     = (u16*)alloc((size_t)2048 * DIM * 2);     // 3 MB PERSISTENT
    float* TO     = (float*)alloc((size_t)1024 * HID * 4);
    float* partS  = (float*)alloc((size_t)16160 * 16 * 3 * 4);   // 3.1 MB
    float* partP  = (float*)alloc((size_t)32768 * 16 * 4 * 4);   // 8.4 MB
    u16*   W2Th   = (u16*)alloc((size_t)1024 * 1024 * 2);
    u16*   W2Tl   = (u16*)alloc((size_t)1024 * 1024 * 2);
    u16*   Wp2T   = (u16*)alloc((size_t)1024 * 1024 * 2);
    u16*   Wp1T4  = (u16*)alloc((size_t)4 * 1024 * 768 * 2);
    float* wtabS  = (float*)alloc(8 * HID * 4);
    float* wtabPt = (float*)alloc(8 * HID * 4);
    float* wtabPo = (float*)alloc(8 * HID * 4);
    float* dtab   = (float*)alloc(14 * HID * 4);
    int*   t_idx  = (int*)alloc(BATCH * NZ * 4);
    int*   o_idx  = (int*)alloc(BATCH * NZ * 4);
    int*   toks   = (int*)alloc(2048 * 4);
    (void)ws_size; (void)in_sizes; (void)n_in; (void)out_size;

    // prep: tables + all bf16 splits/transposes
    k_tables<<<dim3(4, 38), 256, 0, stream>>>(wemb, demb, Ws1, bs1, Wp1, bp1,
                                              wtabS, wtabPt, wtabPo, dtab);
    k_prep<<<32768, 256, 0, stream>>>(x, xh, xl, Ws1, W1Th, W1Tl,
                                      Ws2, W2Th, W2Tl, Wp2, Wp2T, Wp1, Wp1T4);

    // layer-1 factorization: XALL = x2d @ [Ws1_top | Ws1_mid] (3-pass split-bf16)
    k_gemm3bf<<<256, 256, 0, stream>>>(xh, xl, 768, W1Th, W1Tl, 768,
                                       XALL, 2048, 2048, 768, 16, 4);
    k_build_h1s<<<16160, 256, 0, stream>>>(XALL, wtabS, h1h, h1l);
    // span layer2 + FUSED layer3 partials (3-pass split-bf16, deterministic)
    k_span_l2<<<1024, 256, 0, stream>>>(h1h, h1l, W2Th, W2Tl, bs2, Ws3, partS, 16160);
    k_span_red<<<64, 256, 0, stream>>>(partS, bs3, out);
    // top-64 via bitonic sort (deterministic, jax tie-break) + toks build
    k_topk<<<16, 256, 0, stream>>>(out, t_idx, o_idx, toks);
    // gathered pair layer-1: bf16 MFMA with per-lane row gather
    k_pairL1<<<256, 256, 0, stream>>>(xh, Wp1T4, TO, toks);
    k_build_h1p<<<32768, 256, 0, stream>>>(TO, t_idx, o_idx, wtabPt, wtabPo, dtab, h1p);
    // pair layer2 + FUSED layer3 partials (single-pass bf16)
    k_pair_l2<<<2048, 256, 0, stream>>>(h1p, Wp2T, bp2, Wp3, partP);
    k_pair_red<<<128, 256, 0, stream>>>(partP, bp3, out + 48480);
}

// Round 11
// 471.790 us; speedup vs baseline: 2.7706x; 1.0533x over previous
//
#include <hip/hip_runtime.h>
#include <cstdint>
#include <cstddef>

#define BATCH 8
#define SEQ   256
#define DIM   768
#define NSPAN 2020
#define HID   1024
#define NZ    64

typedef unsigned short u16;
typedef unsigned int   u32;
typedef unsigned long long u64;

typedef __bf16 bf16x8 __attribute__((ext_vector_type(8)));
typedef float  f32x4  __attribute__((ext_vector_type(4)));

__device__ __forceinline__ u16 f2bf(float f) {
    union { float f; u32 u; } x; x.f = f;
    u32 r = x.u + 0x7fffu + ((x.u >> 16) & 1u);
    return (u16)(r >> 16);
}
__device__ __forceinline__ float bf2f(u16 b) {
    union { u32 u; float f; } x; x.u = ((u32)b) << 16;
    return x.f;
}
// split v = hi + lo (both bf16); residual v-hi is exact in fp32
__device__ __forceinline__ void splitbf(float v, u16& h, u16& l) {
    h = f2bf(v);
    l = f2bf(v - bf2f(h));
}

// async global->LDS, 16B per lane; LDS dest = wave-uniform base + lane*16;
// global src may be per-lane (row gather OK) [m97/m104]
__device__ __forceinline__ void gld_lds16(const void* g, void* l) {
    __builtin_amdgcn_global_load_lds(
        (const __attribute__((address_space(1))) unsigned int*)g,
        (__attribute__((address_space(3))) unsigned int*)l, 16, 0, 0);
}

// span s -> (start, end, width); spans enumerated width-major: w=1..8, starts 0..L-w
__device__ __forceinline__ void span_decode(int s, int& start, int& end, int& w) {
    int off = 0;
#pragma unroll
    for (int wi = 1; wi <= 8; ++wi) {
        int cnt = SEQ - wi + 1;
        if (s < off + cnt) { w = wi; start = s - off; end = start + wi; return; }
        off += cnt;
    }
    w = 8; start = 0; end = 8;
}

// searchsorted(BUCKET_BINS, d, 'right') - 1
__device__ __forceinline__ int dbucket(int d) {
    int b = 0;
    b += (d >= 1);  b += (d >= 2);  b += (d >= 3);  b += (d >= 4);
    b += (d >= 5);  b += (d >= 7);  b += (d >= 8);  b += (d >= 15);
    b += (d >= 16); b += (d >= 31); b += (d >= 32); b += (d >= 63);
    b += (d >= 64);
    return b;
}

// XCD-aware deswizzle: (linear id) % 8 == by % 8 -> all column-blocks of one
// A-row-tile land on the SAME XCD (id%8 round-robin). sft = log2(nbx).
__device__ __forceinline__ void xcd_map(int L, int sft, int& bx, int& by) {
    int grp = L >> (3 + sft);
    int rem = L & ((1 << (3 + sft)) - 1);
    bx = rem >> 3;
    by = (grp << 3) | (rem & 7);
}

// ---------------------------------------------------------------------------
// k_prep: x hi/lo split (blocks 0..6143) + bucket tables (blocks 6144..6295).
// ---------------------------------------------------------------------------
__global__ __launch_bounds__(256) void k_prep(
    const float* __restrict__ x,  u16* __restrict__ xh,   u16* __restrict__ xl,
    const float* __restrict__ wemb, const float* __restrict__ demb,
    const float* __restrict__ Ws1, const float* __restrict__ bs1,
    const float* __restrict__ Wp1, const float* __restrict__ bp1,
    float* __restrict__ wtabS, float* __restrict__ wtabPt,
    float* __restrict__ wtabPo, float* __restrict__ dtab)
{
    int bid = blockIdx.x, tid = threadIdx.x;
    if (bid < 6144) {
        int i = bid * 256 + tid;         // over 2048*768
        u16 h, l; splitbf(x[i], h, l);
        xh[i] = h; xl[i] = l;
        return;
    }
    int t = bid - 6144;                  // 0..151
    int row = t >> 2;                    // 0..37
    int h = (t & 3) * 256 + tid;         // 0..1023
    const int wb[8] = {1,2,3,4,5,5,6,7}; // width 1..8 -> bucket
    if (row < 8) {
        int bk = wb[row];
        float acc = bs1[h];
        for (int j = 0; j < 25; ++j) acc = fmaf(wemb[bk*25+j], Ws1[(size_t)(1536+j)*HID + h], acc);
        wtabS[row*HID + h] = acc;
    } else if (row < 16) {
        int bk = wb[row-8];
        float acc = 0.f;
        for (int j = 0; j < 25; ++j) acc = fmaf(wemb[bk*25+j], Wp1[(size_t)(1536+j)*HID + h], acc);
        wtabPt[(row-8)*HID + h] = acc;
    } else if (row < 24) {
        int bk = wb[row-16];
        float acc = 0.f;
        for (int j = 0; j < 25; ++j) acc = fmaf(wemb[bk*25+j], Wp1[(size_t)(3097+j)*HID + h], acc);
        wtabPo[(row-16)*HID + h] = acc;
    } else {
        int tt = row - 24;               // 0..13
        float acc = bp1[h];
        for (int j = 0; j < 25; ++j) acc = fmaf(demb[tt*25+j], Wp1[(size_t)(3122+j)*HID + h], acc);
        dtab[tt*HID + h] = acc;
    }
}

// ---------------------------------------------------------------------------
// k_transpose: LDS-tiled (32x33) transpose+convert, coalesced both sides.
//   J0 [0,1536):     Ws1 two blocks -> W1Th/W1Tl [2048 n][768 k]  (hi/lo)
//   J1 [1536,2560):  Ws2 -> W2Th/W2Tl [1024][1024]                (hi/lo)
//   J2 [2560,3584):  Wp2 -> Wp2T [1024][1024]                     (bf16)
//   J3 [3584,6656):  Wp1 4 row-blocks -> Wp1T4 [4][1024 n][768 k] (bf16)
// ---------------------------------------------------------------------------
__global__ __launch_bounds__(256) void k_transpose(
    const float* __restrict__ Ws1, u16* __restrict__ W1Th, u16* __restrict__ W1Tl,
    const float* __restrict__ Ws2, u16* __restrict__ W2Th, u16* __restrict__ W2Tl,
    const float* __restrict__ Wp2, u16* __restrict__ Wp2T,
    const float* __restrict__ Wp1, u16* __restrict__ Wp1T4)
{
    __shared__ float tile[32][33];
    const int bid = blockIdx.x, tid = threadIdx.x;
    const int tr = tid >> 3;           // 0..31
    const int tc4 = (tid & 7) * 4;     // 0,4,..,28
    int job, tk, tn, blk = 0;
    if (bid < 1536)      { job = 0; tk = bid % 24; tn = bid / 24; }
    else if (bid < 2560) { job = 1; int t = bid - 1536; tk = t & 31; tn = t >> 5; }
    else if (bid < 3584) { job = 2; int t = bid - 2560; tk = t & 31; tn = t >> 5; }
    else                 { job = 3; int t = bid - 3584; blk = t / 768; int r = t - blk * 768; tk = r % 24; tn = r / 24; }
    const int k0 = tk * 32, n0 = tn * 32;

    // read src(k = k0+tr, n = n0+tc4..+3), coalesced over n
    int k = k0 + tr;
    float4 v;
    if (job == 0) {
        const float* s = (n0 < 1024) ? (Ws1 + (size_t)k * HID + n0)
                                     : (Ws1 + (size_t)(768 + k) * HID + (n0 - 1024));
        v = *(const float4*)(s + tc4);
    } else if (job == 1) {
        v = *(const float4*)(Ws2 + (size_t)k * HID + n0 + tc4);
    } else if (job == 2) {
        v = *(const float4*)(Wp2 + (size_t)k * HID + n0 + tc4);
    } else {
        const int roff[4] = {0, 768, 1561, 2329};   // (T,p0),(T,p1),(O,p0),(O,p1)
        v = *(const float4*)(Wp1 + (size_t)(roff[blk] + k) * HID + n0 + tc4);
    }
    tile[tr][tc4+0] = v.x; tile[tr][tc4+1] = v.y;
    tile[tr][tc4+2] = v.z; tile[tr][tc4+3] = v.w;
    __syncthreads();

    // write dst(n = n0+tr, k = k0+tc4..+3), coalesced over k
    int nn = n0 + tr;
    float w0 = tile[tc4+0][tr], w1 = tile[tc4+1][tr];
    float w2 = tile[tc4+2][tr], w3 = tile[tc4+3][tr];
    if (job == 0) {
        size_t d = (size_t)nn * 768 + k0 + tc4;
        u16 h0,l0,h1,l1,h2,l2,h3,l3;
        splitbf(w0,h0,l0); splitbf(w1,h1,l1); splitbf(w2,h2,l2); splitbf(w3,h3,l3);
        *(uint2*)(W1Th + d) = make_uint2((u32)h0 | ((u32)h1 << 16), (u32)h2 | ((u32)h3 << 16));
        *(uint2*)(W1Tl + d) = make_uint2((u32)l0 | ((u32)l1 << 16), (u32)l2 | ((u32)l3 << 16));
    } else if (job == 1) {
        size_t d = (size_t)nn * 1024 + k0 + tc4;
        u16 h0,l0,h1,l1,h2,l2,h3,l3;
        splitbf(w0,h0,l0); splitbf(w1,h1,l1); splitbf(w2,h2,l2); splitbf(w3,h3,l3);
        *(uint2*)(W2Th + d) = make_uint2((u32)h0 | ((u32)h1 << 16), (u32)h2 | ((u32)h3 << 16));
        *(uint2*)(W2Tl + d) = make_uint2((u32)l0 | ((u32)l1 << 16), (u32)l2 | ((u32)l3 << 16));
    } else if (job == 2) {
        size_t d = (size_t)nn * 1024 + k0 + tc4;
        *(uint2*)(Wp2T + d) = make_uint2((u32)f2bf(w0) | ((u32)f2bf(w1) << 16),
                                         (u32)f2bf(w2) | ((u32)f2bf(w3) << 16));
    } else {
        size_t d = (size_t)blk * 786432 + (size_t)nn * 768 + k0 + tc4;
        *(uint2*)(Wp1T4 + d) = make_uint2((u32)f2bf(w0) | ((u32)f2bf(w1) << 16),
                                          (u32)f2bf(w2) | ((u32)f2bf(w3) << 16));
    }
}

// ---------------------------------------------------------------------------
// Error-compensated split-bf16 MFMA GEMM: C = AhBh + AlBh + AhBl  (XALL path)
// 128x128 tile, BK=32, global_load_lds staging, XCD-aware grid.
// ---------------------------------------------------------------------------
__global__ __launch_bounds__(256) void k_gemm3bf(
    const u16* __restrict__ Ah, const u16* __restrict__ Al, int lda,
    const u16* __restrict__ BTh, const u16* __restrict__ BTl, int ldb,
    float* __restrict__ C, int ldc,
    int M, int K, int nby, int sft)
{
    int bx, by;
    xcd_map(blockIdx.x, sft, bx, by);
    if (by >= nby) return;
    __shared__ __align__(16) u16 sm[4 * 128 * 32];     // 32 KiB
    u16* sAh = sm;
    u16* sAl = sm + 4096;
    u16* sBh = sm + 8192;
    u16* sBl = sm + 12288;
    const int tid = threadIdx.x;
    const int bm = by * 128, bn = bx * 128;
    const int wave = tid >> 6, lane = tid & 63;
    const int wr = wave >> 1, wc = wave & 1;
    const int q = lane >> 4, tl = lane & 15;

    f32x4 zero = {0.f, 0.f, 0.f, 0.f};
    f32x4 acc[4][4];
#pragma unroll
    for (int i = 0; i < 4; ++i)
#pragma unroll
        for (int j = 0; j < 4; ++j) acc[i][j] = zero;

    const int srow = lane >> 2;
    const int scol = (lane & 3) * 8;
    int ra0 = bm + wave * 32 + srow;      if (ra0 >= M) ra0 = M - 1;
    int ra1 = bm + wave * 32 + 16 + srow; if (ra1 >= M) ra1 = M - 1;
    const int rb0 = bn + wave * 32 + srow;
    const int rb1 = bn + wave * 32 + 16 + srow;
    u16* dA0 = sAh + wave * 1024;  u16* dA1 = dA0 + 512;
    u16* dL0 = sAl + wave * 1024;  u16* dL1 = dL0 + 512;
    u16* dB0 = sBh + wave * 1024;  u16* dB1 = dB0 + 512;
    u16* dC0 = sBl + wave * 1024;  u16* dC1 = dC0 + 512;
    const u16* gA0 = Ah  + (size_t)ra0 * lda + scol;
    const u16* gA1 = Ah  + (size_t)ra1 * lda + scol;
    const u16* gL0 = Al  + (size_t)ra0 * lda + scol;
    const u16* gL1 = Al  + (size_t)ra1 * lda + scol;
    const u16* gB0 = BTh + (size_t)rb0 * ldb + scol;
    const u16* gB1 = BTh + (size_t)rb1 * ldb + scol;
    const u16* gC0 = BTl + (size_t)rb0 * ldb + scol;
    const u16* gC1 = BTl + (size_t)rb1 * ldb + scol;

    for (int k0 = 0; k0 < K; k0 += 32) {
        gld_lds16(gA0 + k0, dA0);
        gld_lds16(gA1 + k0, dA1);
        gld_lds16(gL0 + k0, dL0);
        gld_lds16(gL1 + k0, dL1);
        gld_lds16(gB0 + k0, dB0);
        gld_lds16(gB1 + k0, dB1);
        gld_lds16(gC0 + k0, dC0);
        gld_lds16(gC1 + k0, dC1);
        __syncthreads();
        bf16x8 ah[4], al[4], bh[4], bl[4];
#pragma unroll
        for (int t = 0; t < 4; ++t) {
            int arow = (wr*64 + t*16 + tl) * 32 + q*8;
            int brow = (wc*64 + t*16 + tl) * 32 + q*8;
            ah[t] = *(const bf16x8*)(&sAh[arow]);
            al[t] = *(const bf16x8*)(&sAl[arow]);
            bh[t] = *(const bf16x8*)(&sBh[brow]);
            bl[t] = *(const bf16x8*)(&sBl[brow]);
        }
#pragma unroll
        for (int ti = 0; ti < 4; ++ti)
#pragma unroll
            for (int tj = 0; tj < 4; ++tj) {
                acc[ti][tj] = __builtin_amdgcn_mfma_f32_16x16x32_bf16(ah[ti], bh[tj], acc[ti][tj], 0, 0, 0);
                acc[ti][tj] = __builtin_amdgcn_mfma_f32_16x16x32_bf16(al[ti], bh[tj], acc[ti][tj], 0, 0, 0);
                acc[ti][tj] = __builtin_amdgcn_mfma_f32_16x16x32_bf16(ah[ti], bl[tj], acc[ti][tj], 0, 0, 0);
            }
        __syncthreads();
    }
    // C/D layout: col = lane&15, row = (lane>>4)*4 + reg  [measured m89/m91]
#pragma unroll
    for (int ti = 0; ti < 4; ++ti) {
#pragma unroll
        for (int tj = 0; tj < 4; ++tj) {
            int gcol = bn + wc*64 + tj*16 + tl;
#pragma unroll
            for (int r = 0; r < 4; ++r) {
                int grow = bm + wr*64 + ti*16 + q*4 + r;
                if (grow >= M) continue;
                C[(size_t)grow * ldc + gcol] = acc[ti][tj][r];
            }
        }
    }
}

// ---------------------------------------------------------------------------
// Span layer-2 GEMM with FUSED layer-3 projection epilogue (deterministic).
// ---------------------------------------------------------------------------
__global__ __launch_bounds__(256) void k_span_l2(
    const u16* __restrict__ Ah, const u16* __restrict__ Al,
    const u16* __restrict__ BTh, const u16* __restrict__ BTl,
    const float* __restrict__ bs2, const float* __restrict__ Ws3,
    float* __restrict__ part, int M)
{
    int bx, by;
    xcd_map(blockIdx.x, 3, bx, by);
    if (by >= 127) return;
    __shared__ __align__(16) u16 sm[4 * 128 * 32];
    u16* sAh = sm;
    u16* sAl = sm + 4096;
    u16* sBh = sm + 8192;
    u16* sBl = sm + 12288;
    const int tid = threadIdx.x;
    const int bm = by * 128, bn = bx * 128;
    const int wave = tid >> 6, lane = tid & 63;
    const int wr = wave >> 1, wc = wave & 1;
    const int q = lane >> 4, tl = lane & 15;

    f32x4 zero = {0.f, 0.f, 0.f, 0.f};
    f32x4 acc[4][4];
#pragma unroll
    for (int i = 0; i < 4; ++i)
#pragma unroll
        for (int j = 0; j < 4; ++j) acc[i][j] = zero;

    const int srow = lane >> 2;
    const int scol = (lane & 3) * 8;
    int ra0 = bm + wave * 32 + srow;      if (ra0 >= M) ra0 = M - 1;
    int ra1 = bm + wave * 32 + 16 + srow; if (ra1 >= M) ra1 = M - 1;
    const int rb0 = bn + wave * 32 + srow;
    const int rb1 = bn + wave * 32 + 16 + srow;
    u16* dA0 = sAh + wave * 1024;  u16* dA1 = dA0 + 512;
    u16* dL0 = sAl + wave * 1024;  u16* dL1 = dL0 + 512;
    u16* dB0 = sBh + wave * 1024;  u16* dB1 = dB0 + 512;
    u16* dC0 = sBl + wave * 1024;  u16* dC1 = dC0 + 512;
    const u16* gA0 = Ah  + (size_t)ra0 * HID + scol;
    const u16* gA1 = Ah  + (size_t)ra1 * HID + scol;
    const u16* gL0 = Al  + (size_t)ra0 * HID + scol;
    const u16* gL1 = Al  + (size_t)ra1 * HID + scol;
    const u16* gB0 = BTh + (size_t)rb0 * HID + scol;
    const u16* gB1 = BTh + (size_t)rb1 * HID + scol;
    const u16* gC0 = BTl + (size_t)rb0 * HID + scol;
    const u16* gC1 = BTl + (size_t)rb1 * HID + scol;

    for (int k0 = 0; k0 < HID; k0 += 32) {
        gld_lds16(gA0 + k0, dA0);
        gld_lds16(gA1 + k0, dA1);
        gld_lds16(gL0 + k0, dL0);
        gld_lds16(gL1 + k0, dL1);
        gld_lds16(gB0 + k0, dB0);
        gld_lds16(gB1 + k0, dB1);
        gld_lds16(gC0 + k0, dC0);
        gld_lds16(gC1 + k0, dC1);
        __syncthreads();
        bf16x8 ah[4], al[4], bh[4], bl[4];
#pragma unroll
        for (int t = 0; t < 4; ++t) {
            int arow = (wr*64 + t*16 + tl) * 32 + q*8;
            int brow = (wc*64 + t*16 + tl) * 32 + q*8;
            ah[t] = *(const bf16x8*)(&sAh[arow]);
            al[t] = *(const bf16x8*)(&sAl[arow]);
            bh[t] = *(const bf16x8*)(&sBh[brow]);
            bl[t] = *(const bf16x8*)(&sBl[brow]);
        }
#pragma unroll
        for (int ti = 0; ti < 4; ++ti)
#pragma unroll
            for (int tj = 0; tj < 4; ++tj) {
                acc[ti][tj] = __builtin_amdgcn_mfma_f32_16x16x32_bf16(ah[ti], bh[tj], acc[ti][tj], 0, 0, 0);
                acc[ti][tj] = __builtin_amdgcn_mfma_f32_16x16x32_bf16(al[ti], bh[tj], acc[ti][tj], 0, 0, 0);
                acc[ti][tj] = __builtin_amdgcn_mfma_f32_16x16x32_bf16(ah[ti], bl[tj], acc[ti][tj], 0, 0, 0);
            }
        __syncthreads();
    }
    // fused L3: per row, partial dot over this wave's 64-col window
    const int slot = bx * 2 + wc;   // 0..15
#pragma unroll
    for (int ti = 0; ti < 4; ++ti) {
#pragma unroll
        for (int r = 0; r < 4; ++r) {
            int grow = bm + wr*64 + ti*16 + q*4 + r;
            float l0 = 0.f, l1 = 0.f, l2 = 0.f;
#pragma unroll
            for (int tj = 0; tj < 4; ++tj) {
                int gcol = bn + wc*64 + tj*16 + tl;
                float v = fmaxf(acc[ti][tj][r] + bs2[gcol], 0.f);
                const float* w3 = Ws3 + gcol * 3;
                l0 = fmaf(v, w3[0], l0);
                l1 = fmaf(v, w3[1], l1);
                l2 = fmaf(v, w3[2], l2);
            }
#pragma unroll
            for (int off = 8; off > 0; off >>= 1) {
                l0 += __shfl_down(l0, off, 16);
                l1 += __shfl_down(l1, off, 16);
                l2 += __shfl_down(l2, off, 16);
            }
            if (tl == 0 && grow < M) {
                float* dst = part + ((size_t)grow * 16 + slot) * 3;
                dst[0] = l0; dst[1] = l1; dst[2] = l2;
            }
        }
    }
}

// reduce 16 slots (fixed order) + softmax -> out[r*3+c]
__global__ __launch_bounds__(256) void k_span_red(
    const float* __restrict__ part, const float* __restrict__ bs3,
    float* __restrict__ out)
{
    int r = blockIdx.x * 256 + threadIdx.x;
    if (r >= 16160) return;
    const float* p = part + (size_t)r * 48;
    float s0 = bs3[0], s1 = bs3[1], s2 = bs3[2];
#pragma unroll
    for (int t = 0; t < 16; ++t) {
        s0 += p[t*3]; s1 += p[t*3+1]; s2 += p[t*3+2];
    }
    float m = fmaxf(s0, fmaxf(s1, s2));
    float e0 = expf(s0 - m), e1 = expf(s1 - m), e2 = expf(s2 - m);
    float inv = 1.f / (e0 + e1 + e2);
    float* o = out + (size_t)r * 3;
    o[0] = e0 * inv; o[1] = e1 * inv; o[2] = e2 * inv;
}

// ---------------------------------------------------------------------------
// Gathered pair layer-1, bf16 MFMA: TO[r] = xh[toks[r]]@B(p0) + xh[toks[1024+r]]@B(p1)
// ---------------------------------------------------------------------------
__global__ __launch_bounds__(256) void k_pairL1(
    const u16* __restrict__ xh, const u16* __restrict__ Wp1T4,
    float* __restrict__ TO, const int* __restrict__ toks)
{
    __shared__ __align__(16) u16 sm[2 * 64 * 32];   // A 4KB | B 4KB
    u16* sA = sm;
    u16* sB = sm + 2048;
    const int tid = threadIdx.x;
    const int bx = blockIdx.x & 15, by = blockIdx.x >> 4;
    const int bm = by * 64, bn = bx * 64;
    const int wave = tid >> 6, lane = tid & 63;
    const int wr = wave >> 1, wc = wave & 1;
    const int q = lane >> 4, tl = lane & 15;
    const bool isO = bm >= 512;

    f32x4 zero = {0.f, 0.f, 0.f, 0.f};
    f32x4 acc[2][2];
#pragma unroll
    for (int i = 0; i < 2; ++i)
#pragma unroll
        for (int j = 0; j < 2; ++j) acc[i][j] = zero;

    const int srow = tid >> 2;
    const int scol = (tid & 3) * 8;
    u16* dA = sA + wave * 512;
    u16* dB = sB + wave * 512;

#pragma unroll
    for (int p = 0; p < 2; ++p) {
        int arow = toks[bm + srow + p * 1024];    // per-lane row gather
        const u16* gA = xh + (size_t)arow * DIM + scol;
        const u16* gB = Wp1T4 + ((size_t)((isO ? 2 : 0) + p) * 1024 + bn + srow) * DIM + scol;
        for (int k0 = 0; k0 < DIM; k0 += 32) {
            gld_lds16(gA + k0, dA);
            gld_lds16(gB + k0, dB);
            __syncthreads();
            bf16x8 af[2], bf[2];
#pragma unroll
            for (int t = 0; t < 2; ++t) {
                af[t] = *(const bf16x8*)(&sA[(wr*32 + t*16 + tl) * 32 + q*8]);
                bf[t] = *(const bf16x8*)(&sB[(wc*32 + t*16 + tl) * 32 + q*8]);
            }
#pragma unroll
            for (int ti = 0; ti < 2; ++ti)
#pragma unroll
                for (int tj = 0; tj < 2; ++tj)
                    acc[ti][tj] = __builtin_amdgcn_mfma_f32_16x16x32_bf16(af[ti], bf[tj], acc[ti][tj], 0, 0, 0);
            __syncthreads();
        }
    }
#pragma unroll
    for (int ti = 0; ti < 2; ++ti) {
#pragma unroll
        for (int tj = 0; tj < 2; ++tj) {
            int gcol = bn + wc*32 + tj*16 + tl;
#pragma unroll
            for (int r = 0; r < 4; ++r) {
                int grow = bm + wr*32 + ti*16 + q*4 + r;
                TO[(size_t)grow * HID + gcol] = acc[ti][tj][r];
            }
        }
    }
}

// h1s = relu(XALL[b,start,0:1024] + XALL[b,end-1,1024:2048] + wtabS[w-1]) -> split bf16
__global__ __launch_bounds__(256) void k_build_h1s(
    const float* __restrict__ XALL, const float* __restrict__ wtabS,
    u16* __restrict__ h1h, u16* __restrict__ h1l)
{
    int r = blockIdx.x;                 // 0..16159
    int b = r / NSPAN, s = r - b * NSPAN;
    int st, en, w; span_decode(s, st, en, w);
    const float4* xs = (const float4*)(XALL + (size_t)(b*SEQ + st) * 2048);
    const float4* xe = (const float4*)(XALL + (size_t)(b*SEQ + en - 1) * 2048 + 1024);
    const float4* wt = (const float4*)(wtabS + (size_t)(w-1) * HID);
    int t = threadIdx.x;
    float4 a = xs[t], bz = xe[t], c = wt[t];
    float v0 = fmaxf(a.x + bz.x + c.x, 0.f);
    float v1 = fmaxf(a.y + bz.y + c.y, 0.f);
    float v2 = fmaxf(a.z + bz.z + c.z, 0.f);
    float v3 = fmaxf(a.w + bz.w + c.w, 0.f);
    u16 h0,l0,h1,l1,h2,l2,h3,l3;
    splitbf(v0,h0,l0); splitbf(v1,h1,l1); splitbf(v2,h2,l2); splitbf(v3,h3,l3);
    size_t base = (size_t)r * HID + t * 4;
    *(uint2*)(h1h + base) = make_uint2((u32)h0 | ((u32)h1 << 16), (u32)h2 | ((u32)h3 << 16));
    *(uint2*)(h1l + base) = make_uint2((u32)l0 | ((u32)l1 << 16), (u32)l2 | ((u32)l3 << 16));
}

// ---------------------------------------------------------------------------
// top-64 via in-LDS bitonic sort of 2048 packed u64 keys (canonical form).
// key = (fbits(prob) << 32) | (0xFFFFFFFF - s). Deterministic, jax tie-break.
// ---------------------------------------------------------------------------
__global__ __launch_bounds__(256) void k_topk(
    const float* __restrict__ sp, int* __restrict__ t_idx, int* __restrict__ o_idx,
    int* __restrict__ toks)
{
    int b = blockIdx.x >> 1;
    int head = 1 + (blockIdx.x & 1);
    int* outp = (head == 1 ? t_idx : o_idx) + b * NZ;
    __shared__ u64 keys[2048];
    int tid = threadIdx.x;
#pragma unroll
    for (int ii = 0; ii < 8; ++ii) {
        int s = tid + ii * 256;
        u32 fb = 0;
        if (s < NSPAN) {
            union { float f; u32 u; } x;
            x.f = sp[((size_t)b * NSPAN + s) * 3 + head];
            fb = x.u;
        }
        keys[s] = ((u64)fb << 32) | (u64)(0xFFFFFFFFu - (u32)s);
    }
    __syncthreads();
    for (int k = 2; k <= 2048; k <<= 1) {
        for (int j = k >> 1; j > 0; j >>= 1) {
#pragma unroll
            for (int ii = 0; ii < 8; ++ii) {
                int i = tid + ii * 256;
                int ixj = i ^ j;
                if (ixj > i) {
                    u64 a = keys[i], c = keys[ixj];
                    bool desc = (i & k) == 0;
                    bool wrong = desc ? (a < c) : (a > c);
                    if (wrong) { keys[i] = c; keys[ixj] = a; }
                }
            }
            __syncthreads();
        }
    }
    if (tid < NZ) {
        u64 key = keys[tid];
        int fi = (int)(0xFFFFFFFFu - (u32)(key & 0xFFFFFFFFu));
        if (fi < 0 || fi >= NSPAN) fi = 0;   // paranoia
        outp[tid] = fi;
        int st, en, w; span_decode(fi, st, en, w);
        int base = (head == 1 ? 0 : 512) + b * NZ + tid;
        toks[base] = b * SEQ + st;
        toks[1024 + base] = b * SEQ + en - 1;
    }
}

// h1_pair[row] = relu(T[b,i] + O[b,j] + wtabPt + wtabPo + dtab) -> bf16
__global__ __launch_bounds__(256) void k_build_h1p(
    const float* __restrict__ TO, const int* __restrict__ t_idx, const int* __restrict__ o_idx,
    const float* __restrict__ wtabPt, const float* __restrict__ wtabPo,
    const float* __restrict__ dtab, u16* __restrict__ h1p)
{
    int row = blockIdx.x;               // b*4096 + i*64 + j
    int b = row >> 12, i = (row >> 6) & 63, j = row & 63;
    int ts = t_idx[b*64 + i], os = o_idx[b*64 + j];
    int ta, tb, wt, oc, od, wo;
    span_decode(ts, ta, tb, wt);
    span_decode(os, oc, od, wo);
    int d1 = tb - oc; d1 = d1 < 0 ? -d1 : d1;
    int d2 = ta - od; d2 = d2 < 0 ? -d2 : d2;
    int dist = d1 < d2 ? d1 : d2;
    int db = dbucket(dist);
    const float4* T4 = (const float4*)(TO + (size_t)(b*64 + i) * HID);
    const float4* O4 = (const float4*)(TO + (size_t)(512 + b*64 + j) * HID);
    const float4* P4 = (const float4*)(wtabPt + (size_t)(wt-1) * HID);
    const float4* Q4 = (const float4*)(wtabPo + (size_t)(wo-1) * HID);
    const float4* D4 = (const float4*)(dtab + (size_t)db * HID);
    int t = threadIdx.x;
    float4 a = T4[t], c = O4[t], p = P4[t], q = Q4[t], d = D4[t];
    float vx = fmaxf(a.x + c.x + p.x + q.x + d.x, 0.f);
    float vy = fmaxf(a.y + c.y + p.y + q.y + d.y, 0.f);
    float vz = fmaxf(a.z + c.z + p.z + q.z + d.z, 0.f);
    float vw = fmaxf(a.w + c.w + p.w + q.w + d.w, 0.f);
    u32 p0 = (u32)f2bf(vx) | ((u32)f2bf(vy) << 16);
    u32 p1 = (u32)f2bf(vz) | ((u32)f2bf(vw) << 16);
    *(uint2*)(h1p + (size_t)row * HID + t * 4) = make_uint2(p0, p1);
}

// pair layer2 with FUSED layer-3 projection epilogue (h2p never materialized).
__global__ __launch_bounds__(256) void k_pair_l2(
    const u16* __restrict__ Abf, const u16* __restrict__ BT,
    const float* __restrict__ bp2, const float* __restrict__ Wp3,
    float* __restrict__ part)
{
    int bx, by;
    xcd_map(blockIdx.x, 3, bx, by);
    __shared__ __align__(16) u16 sm[2 * 128 * 32];     // 16 KiB
    u16* As = sm;
    u16* Bs = sm + 4096;
    const int tid = threadIdx.x;
    const int bm = by * 128, bn = bx * 128;
    const int wave = tid >> 6, lane = tid & 63;
    const int wr = wave >> 1, wc = wave & 1;
    const int q = lane >> 4, tl = lane & 15;

    f32x4 zero = {0.f, 0.f, 0.f, 0.f};
    f32x4 acc[4][4];
#pragma unroll
    for (int i = 0; i < 4; ++i)
#pragma unroll
        for (int j = 0; j < 4; ++j) acc[i][j] = zero;

    const int srow = lane >> 2;
    const int scol = (lane & 3) * 8;
    const u16* gA0 = Abf + (size_t)(bm + wave*32 + srow) * 1024 + scol;
    const u16* gA1 = Abf + (size_t)(bm + wave*32 + 16 + srow) * 1024 + scol;
    const u16* gB0 = BT  + (size_t)(bn + wave*32 + srow) * 1024 + scol;
    const u16* gB1 = BT  + (size_t)(bn + wave*32 + 16 + srow) * 1024 + scol;
    u16* dA0 = As + wave * 1024;  u16* dA1 = dA0 + 512;
    u16* dB0 = Bs + wave * 1024;  u16* dB1 = dB0 + 512;

    for (int k0 = 0; k0 < 1024; k0 += 32) {
        gld_lds16(gA0 + k0, dA0);
        gld_lds16(gA1 + k0, dA1);
        gld_lds16(gB0 + k0, dB0);
        gld_lds16(gB1 + k0, dB1);
        __syncthreads();
        bf16x8 af[4], bf[4];
#pragma unroll
        for (int t = 0; t < 4; ++t) {
            af[t] = *(const bf16x8*)(&As[(wr*64 + t*16 + tl) * 32 + q*8]);
            bf[t] = *(const bf16x8*)(&Bs[(wc*64 + t*16 + tl) * 32 + q*8]);
        }
#pragma unroll
        for (int ti = 0; ti < 4; ++ti)
#pragma unroll
            for (int tj = 0; tj < 4; ++tj)
                acc[ti][tj] = __builtin_amdgcn_mfma_f32_16x16x32_bf16(af[ti], bf[tj], acc[ti][tj], 0, 0, 0);
        __syncthreads();
    }
    // fused L3 projection
    const int slot = bx * 2 + wc;   // 0..15
#pragma unroll
    for (int ti = 0; ti < 4; ++ti) {
#pragma unroll
        for (int r = 0; r < 4; ++r) {
            int grow = bm + wr*64 + ti*16 + q*4 + r;
            float l0 = 0.f, l1 = 0.f, l2 = 0.f, l3 = 0.f;
#pragma unroll
            for (int tj = 0; tj < 4; ++tj) {
                int gcol = bn + wc*64 + tj*16 + tl;
                float v = fmaxf(acc[ti][tj][r] + bp2[gcol], 0.f);
                const float4 w = *(const float4*)(Wp3 + gcol * 4);
                l0 = fmaf(v, w.x, l0); l1 = fmaf(v, w.y, l1);
                l2 = fmaf(v, w.z, l2); l3 = fmaf(v, w.w, l3);
            }
#pragma unroll
            for (int off = 8; off > 0; off >>= 1) {
                l0 += __shfl_down(l0, off, 16);
                l1 += __shfl_down(l1, off, 16);
                l2 += __shfl_down(l2, off, 16);
                l3 += __shfl_down(l3, off, 16);
            }
            if (tl == 0) {
                float* dst = part + ((size_t)grow * 16 + slot) * 4;
                dst[0] = l0; dst[1] = l1; dst[2] = l2; dst[3] = l3;
            }
        }
    }
}

// reduce 16 slots (fixed order) + softmax -> out[48480 + r*4 + c]
__global__ __launch_bounds__(256) void k_pair_red(
    const float* __restrict__ part, const float* __restrict__ bp3,
    float* __restrict__ out)
{
    int r = blockIdx.x * 256 + threadIdx.x;   // 32768 = 128*256 exact
    const float4* p = (const float4*)(part + (size_t)r * 64);
    float s0 = bp3[0], s1 = bp3[1], s2 = bp3[2], s3 = bp3[3];
#pragma unroll
    for (int t = 0; t < 16; ++t) {
        float4 v = p[t];
        s0 += v.x; s1 += v.y; s2 += v.z; s3 += v.w;
    }
    float m = fmaxf(fmaxf(s0, s1), fmaxf(s2, s3));
    float e0 = expf(s0 - m), e1 = expf(s1 - m), e2 = expf(s2 - m), e3 = expf(s3 - m);
    float inv = 1.f / (e0 + e1 + e2 + e3);
    float* o = out + (size_t)r * 4;
    o[0] = e0 * inv; o[1] = e1 * inv; o[2] = e2 * inv; o[3] = e3 * inv;
}

extern "C" void kernel_launch(void* const* d_in, const int* in_sizes, int n_in,
                              void* d_out, int out_size, void* d_ws, size_t ws_size,
                              hipStream_t stream)
{
    const float* x    = (const float*)d_in[0];
    const float* wemb = (const float*)d_in[1];
    const float* demb = (const float*)d_in[2];
    const float* Ws1  = (const float*)d_in[3];
    const float* bs1  = (const float*)d_in[4];
    const float* Ws2  = (const float*)d_in[5];
    const float* bs2  = (const float*)d_in[6];
    const float* Ws3  = (const float*)d_in[7];
    const float* bs3  = (const float*)d_in[8];
    const float* Wp1  = (const float*)d_in[9];
    const float* bp1  = (const float*)d_in[10];
    const float* Wp2  = (const float*)d_in[11];
    const float* bp2  = (const float*)d_in[12];
    const float* Wp3  = (const float*)d_in[13];
    const float* bp3  = (const float*)d_in[14];
    float* out = (float*)d_out;
    char* ws = (char*)d_ws;

    // ---- workspace arena, lifetime-aliased ----
    // R1 (64 MiB): h1h+h1l (dead after k_span_l2)
    // R2 (64 MiB): [XALL | xl | W1Th | W1Tl] (dead after build_h1s) -> h1p
    // xh PERSISTENT (read by k_pairL1 late).
    const size_t RSZ = (size_t)32768 * HID * 2;   // 64 MiB
    size_t off = 0;
    auto alloc = [&](size_t bytes) -> void* {
        void* p = ws + off;
        off += (bytes + 255) & ~(size_t)255;
        return p;
    };
    char* R1 = (char*)alloc(RSZ);
    char* R2 = (char*)alloc(RSZ);
    u16*   h1h  = (u16*)R1;                              // 33.1 MB
    u16*   h1l  = (u16*)(R1 + (size_t)16160 * HID * 2);  // 33.1 MB
    float* XALL = (float*)R2;                            // 16 MiB
    u16*   xl   = (u16*)(R2 + (16u << 20));              // 3 MB
    u16*   W1Th = (u16*)(R2 + (19u << 20));              // 3 MB
    u16*   W1Tl = (u16*)(R2 + (22u << 20));              // 3 MB
    u16*   h1p  = (u16*)R2;                              // 64 MiB (after the above dead)
    u16*   xh     = (u16*)alloc((size_t)2048 * DIM * 2);     // 3 MB PERSISTENT
    float* TO     = (float*)alloc((size_t)1024 * HID * 4);
    float* partS  = (float*)alloc((size_t)16160 * 16 * 3 * 4);   // 3.1 MB
    float* partP  = (float*)alloc((size_t)32768 * 16 * 4 * 4);   // 8.4 MB
    u16*   W2Th   = (u16*)alloc((size_t)1024 * 1024 * 2);
    u16*   W2Tl   = (u16*)alloc((size_t)1024 * 1024 * 2);
    u16*   Wp2T   = (u16*)alloc((size_t)1024 * 1024 * 2);
    u16*   Wp1T4  = (u16*)alloc((size_t)4 * 1024 * 768 * 2);
    float* wtabS  = (float*)alloc(8 * HID * 4);
    float* wtabPt = (float*)alloc(8 * HID * 4);
    float* wtabPo = (float*)alloc(8 * HID * 4);
    float* dtab   = (float*)alloc(14 * HID * 4);
    int*   t_idx  = (int*)alloc(BATCH * NZ * 4);
    int*   o_idx  = (int*)alloc(BATCH * NZ * 4);
    int*   toks   = (int*)alloc(2048 * 4);
    (void)ws_size; (void)in_sizes; (void)n_in; (void)out_size;

    // prep: x hi/lo split + bucket tables (merged); weight transposes (LDS-tiled)
    k_prep<<<6296, 256, 0, stream>>>(x, xh, xl, wemb, demb, Ws1, bs1, Wp1, bp1,
                                     wtabS, wtabPt, wtabPo, dtab);
    k_transpose<<<6656, 256, 0, stream>>>(Ws1, W1Th, W1Tl, Ws2, W2Th, W2Tl,
                                          Wp2, Wp2T, Wp1, Wp1T4);

    // layer-1 factorization: XALL = x2d @ [Ws1_top | Ws1_mid] (3-pass split-bf16)
    k_gemm3bf<<<256, 256, 0, stream>>>(xh, xl, 768, W1Th, W1Tl, 768,
                                       XALL, 2048, 2048, 768, 16, 4);
    k_build_h1s<<<16160, 256, 0, stream>>>(XALL, wtabS, h1h, h1l);
    // span layer2 + FUSED layer3 partials (3-pass split-bf16, deterministic)
    k_span_l2<<<1024, 256, 0, stream>>>(h1h, h1l, W2Th, W2Tl, bs2, Ws3, partS, 16160);
    k_span_red<<<64, 256, 0, stream>>>(partS, bs3, out);
    // top-64 via bitonic sort (deterministic, jax tie-break) + toks build
    k_topk<<<16, 256, 0, stream>>>(out, t_idx, o_idx, toks);
    // gathered pair layer-1: bf16 MFMA with per-lane row gather
    k_pairL1<<<256, 256, 0, stream>>>(xh, Wp1T4, TO, toks);
    k_build_h1p<<<32768, 256, 0, stream>>>(TO, t_idx, o_idx, wtabPt, wtabPo, dtab, h1p);
    // pair layer2 + FUSED layer3 partials (single-pass bf16)
    k_pair_l2<<<2048, 256, 0, stream>>>(h1p, Wp2T, bp2, Wp3, partP);
    k_pair_red<<<128, 256, 0, stream>>>(partP, bp3, out + 48480);
}

// Round 12
// 469.930 us; speedup vs baseline: 2.7816x; 1.0040x over previous
//
#include <hip/hip_runtime.h>
#include <cstdint>
#include <cstddef>

#define BATCH 8
#define SEQ   256
#define DIM   768
#define NSPAN 2020
#define HID   1024
#define NZ    64

typedef unsigned short u16;
typedef unsigned int   u32;
typedef unsigned long long u64;

typedef __bf16 bf16x8 __attribute__((ext_vector_type(8)));
typedef float  f32x4  __attribute__((ext_vector_type(4)));

__device__ __forceinline__ u16 f2bf(float f) {
    union { float f; u32 u; } x; x.f = f;
    u32 r = x.u + 0x7fffu + ((x.u >> 16) & 1u);
    return (u16)(r >> 16);
}
__device__ __forceinline__ float bf2f(u16 b) {
    union { u32 u; float f; } x; x.u = ((u32)b) << 16;
    return x.f;
}
// split v = hi + lo (both bf16); residual v-hi is exact in fp32
__device__ __forceinline__ void splitbf(float v, u16& h, u16& l) {
    h = f2bf(v);
    l = f2bf(v - bf2f(h));
}

// async global->LDS, 16B per lane; LDS dest = wave-uniform base + lane*16;
// global src may be per-lane (row gather OK) [m97/m104]
__device__ __forceinline__ void gld_lds16(const void* g, void* l) {
    __builtin_amdgcn_global_load_lds(
        (const __attribute__((address_space(1))) unsigned int*)g,
        (__attribute__((address_space(3))) unsigned int*)l, 16, 0, 0);
}

// span s -> (start, end, width); spans enumerated width-major: w=1..8, starts 0..L-w
__device__ __forceinline__ void span_decode(int s, int& start, int& end, int& w) {
    int off = 0;
#pragma unroll
    for (int wi = 1; wi <= 8; ++wi) {
        int cnt = SEQ - wi + 1;
        if (s < off + cnt) { w = wi; start = s - off; end = start + wi; return; }
        off += cnt;
    }
    w = 8; start = 0; end = 8;
}

// searchsorted(BUCKET_BINS, d, 'right') - 1
__device__ __forceinline__ int dbucket(int d) {
    int b = 0;
    b += (d >= 1);  b += (d >= 2);  b += (d >= 3);  b += (d >= 4);
    b += (d >= 5);  b += (d >= 7);  b += (d >= 8);  b += (d >= 15);
    b += (d >= 16); b += (d >= 31); b += (d >= 32); b += (d >= 63);
    b += (d >= 64);
    return b;
}

// XCD-aware deswizzle: (linear id) % 8 == by % 8 -> all column-blocks of one
// A-row-tile land on the SAME XCD (id%8 round-robin). sft = log2(nbx).
__device__ __forceinline__ void xcd_map(int L, int sft, int& bx, int& by) {
    int grp = L >> (3 + sft);
    int rem = L & ((1 << (3 + sft)) - 1);
    bx = rem >> 3;
    by = (grp << 3) | (rem & 7);
}

// ---------------------------------------------------------------------------
// k_prep (fused): x hi/lo split | bucket tables | all weight transposes.
//   bid [0,6144):       x -> xh/xl
//   bid [6144,6296):    bucket tables (38 rows x 4 col-chunks)
//   bid [6296,12952):   LDS-tiled 32x33 transpose+convert jobs:
//     J0 [0,1536):     Ws1 two blocks -> W1Th/W1Tl [2048 n][768 k]  (hi/lo)
//     J1 [1536,2560):  Ws2 -> W2Th/W2Tl [1024][1024]                (hi/lo)
//     J2 [2560,3584):  Wp2 -> Wp2T [1024][1024]                     (bf16)
//     J3 [3584,6656):  Wp1 4 row-blocks -> Wp1T4 [4][1024][768]     (bf16)
// ---------------------------------------------------------------------------
__global__ __launch_bounds__(256) void k_prep(
    const float* __restrict__ x,  u16* __restrict__ xh,   u16* __restrict__ xl,
    const float* __restrict__ wemb, const float* __restrict__ demb,
    const float* __restrict__ bs1, const float* __restrict__ bp1,
    float* __restrict__ wtabS, float* __restrict__ wtabPt,
    float* __restrict__ wtabPo, float* __restrict__ dtab,
    const float* __restrict__ Ws1, u16* __restrict__ W1Th, u16* __restrict__ W1Tl,
    const float* __restrict__ Ws2, u16* __restrict__ W2Th, u16* __restrict__ W2Tl,
    const float* __restrict__ Wp2, u16* __restrict__ Wp2T,
    const float* __restrict__ Wp1, u16* __restrict__ Wp1T4)
{
    __shared__ float tile[32][33];
    const int bid = blockIdx.x, tid = threadIdx.x;
    if (bid < 6144) {
        int i = bid * 256 + tid;         // over 2048*768
        u16 h, l; splitbf(x[i], h, l);
        xh[i] = h; xl[i] = l;
        return;
    }
    if (bid < 6296) {
        int t = bid - 6144;              // 0..151
        int row = t >> 2;                // 0..37
        int h = (t & 3) * 256 + tid;     // 0..1023
        const int wb[8] = {1,2,3,4,5,5,6,7};
        if (row < 8) {
            int bk = wb[row];
            float acc = bs1[h];
            for (int j = 0; j < 25; ++j) acc = fmaf(wemb[bk*25+j], Ws1[(size_t)(1536+j)*HID + h], acc);
            wtabS[row*HID + h] = acc;
        } else if (row < 16) {
            int bk = wb[row-8];
            float acc = 0.f;
            for (int j = 0; j < 25; ++j) acc = fmaf(wemb[bk*25+j], Wp1[(size_t)(1536+j)*HID + h], acc);
            wtabPt[(row-8)*HID + h] = acc;
        } else if (row < 24) {
            int bk = wb[row-16];
            float acc = 0.f;
            for (int j = 0; j < 25; ++j) acc = fmaf(wemb[bk*25+j], Wp1[(size_t)(3097+j)*HID + h], acc);
            wtabPo[(row-16)*HID + h] = acc;
        } else {
            int tt = row - 24;           // 0..13
            float acc = bp1[h];
            for (int j = 0; j < 25; ++j) acc = fmaf(demb[tt*25+j], Wp1[(size_t)(3122+j)*HID + h], acc);
            dtab[tt*HID + h] = acc;
        }
        return;
    }
    // transpose jobs
    const int tb = bid - 6296;           // 0..6655
    const int tr = tid >> 3;             // 0..31
    const int tc4 = (tid & 7) * 4;       // 0,4,..,28
    int job, tk, tn, blk = 0;
    if (tb < 1536)      { job = 0; tk = tb % 24; tn = tb / 24; }
    else if (tb < 2560) { job = 1; int t = tb - 1536; tk = t & 31; tn = t >> 5; }
    else if (tb < 3584) { job = 2; int t = tb - 2560; tk = t & 31; tn = t >> 5; }
    else                { job = 3; int t = tb - 3584; blk = t / 768; int r = t - blk * 768; tk = r % 24; tn = r / 24; }
    const int k0 = tk * 32, n0 = tn * 32;

    int k = k0 + tr;
    float4 v;
    if (job == 0) {
        const float* s = (n0 < 1024) ? (Ws1 + (size_t)k * HID + n0)
                                     : (Ws1 + (size_t)(768 + k) * HID + (n0 - 1024));
        v = *(const float4*)(s + tc4);
    } else if (job == 1) {
        v = *(const float4*)(Ws2 + (size_t)k * HID + n0 + tc4);
    } else if (job == 2) {
        v = *(const float4*)(Wp2 + (size_t)k * HID + n0 + tc4);
    } else {
        const int roff[4] = {0, 768, 1561, 2329};   // (T,p0),(T,p1),(O,p0),(O,p1)
        v = *(const float4*)(Wp1 + (size_t)(roff[blk] + k) * HID + n0 + tc4);
    }
    tile[tr][tc4+0] = v.x; tile[tr][tc4+1] = v.y;
    tile[tr][tc4+2] = v.z; tile[tr][tc4+3] = v.w;
    __syncthreads();

    int nn = n0 + tr;
    float w0 = tile[tc4+0][tr], w1 = tile[tc4+1][tr];
    float w2 = tile[tc4+2][tr], w3 = tile[tc4+3][tr];
    if (job == 0) {
        size_t d = (size_t)nn * 768 + k0 + tc4;
        u16 h0,l0,h1,l1,h2,l2,h3,l3;
        splitbf(w0,h0,l0); splitbf(w1,h1,l1); splitbf(w2,h2,l2); splitbf(w3,h3,l3);
        *(uint2*)(W1Th + d) = make_uint2((u32)h0 | ((u32)h1 << 16), (u32)h2 | ((u32)h3 << 16));
        *(uint2*)(W1Tl + d) = make_uint2((u32)l0 | ((u32)l1 << 16), (u32)l2 | ((u32)l3 << 16));
    } else if (job == 1) {
        size_t d = (size_t)nn * 1024 + k0 + tc4;
        u16 h0,l0,h1,l1,h2,l2,h3,l3;
        splitbf(w0,h0,l0); splitbf(w1,h1,l1); splitbf(w2,h2,l2); splitbf(w3,h3,l3);
        *(uint2*)(W2Th + d) = make_uint2((u32)h0 | ((u32)h1 << 16), (u32)h2 | ((u32)h3 << 16));
        *(uint2*)(W2Tl + d) = make_uint2((u32)l0 | ((u32)l1 << 16), (u32)l2 | ((u32)l3 << 16));
    } else if (job == 2) {
        size_t d = (size_t)nn * 1024 + k0 + tc4;
        *(uint2*)(Wp2T + d) = make_uint2((u32)f2bf(w0) | ((u32)f2bf(w1) << 16),
                                         (u32)f2bf(w2) | ((u32)f2bf(w3) << 16));
    } else {
        size_t d = (size_t)blk * 786432 + (size_t)nn * 768 + k0 + tc4;
        *(uint2*)(Wp1T4 + d) = make_uint2((u32)f2bf(w0) | ((u32)f2bf(w1) << 16),
                                          (u32)f2bf(w2) | ((u32)f2bf(w3) << 16));
    }
}

// ---------------------------------------------------------------------------
// Error-compensated split-bf16 MFMA GEMM: C = AhBh + AlBh + AhBl  (XALL path)
// 128x128 tile, BK=32, global_load_lds staging, XCD-aware grid.
// ---------------------------------------------------------------------------
__global__ __launch_bounds__(256) void k_gemm3bf(
    const u16* __restrict__ Ah, const u16* __restrict__ Al, int lda,
    const u16* __restrict__ BTh, const u16* __restrict__ BTl, int ldb,
    float* __restrict__ C, int ldc,
    int M, int K, int nby, int sft)
{
    int bx, by;
    xcd_map(blockIdx.x, sft, bx, by);
    if (by >= nby) return;
    __shared__ __align__(16) u16 sm[4 * 128 * 32];     // 32 KiB
    u16* sAh = sm;
    u16* sAl = sm + 4096;
    u16* sBh = sm + 8192;
    u16* sBl = sm + 12288;
    const int tid = threadIdx.x;
    const int bm = by * 128, bn = bx * 128;
    const int wave = tid >> 6, lane = tid & 63;
    const int wr = wave >> 1, wc = wave & 1;
    const int q = lane >> 4, tl = lane & 15;

    f32x4 zero = {0.f, 0.f, 0.f, 0.f};
    f32x4 acc[4][4];
#pragma unroll
    for (int i = 0; i < 4; ++i)
#pragma unroll
        for (int j = 0; j < 4; ++j) acc[i][j] = zero;

    const int srow = lane >> 2;
    const int scol = (lane & 3) * 8;
    int ra0 = bm + wave * 32 + srow;      if (ra0 >= M) ra0 = M - 1;
    int ra1 = bm + wave * 32 + 16 + srow; if (ra1 >= M) ra1 = M - 1;
    const int rb0 = bn + wave * 32 + srow;
    const int rb1 = bn + wave * 32 + 16 + srow;
    u16* dA0 = sAh + wave * 1024;  u16* dA1 = dA0 + 512;
    u16* dL0 = sAl + wave * 1024;  u16* dL1 = dL0 + 512;
    u16* dB0 = sBh + wave * 1024;  u16* dB1 = dB0 + 512;
    u16* dC0 = sBl + wave * 1024;  u16* dC1 = dC0 + 512;
    const u16* gA0 = Ah  + (size_t)ra0 * lda + scol;
    const u16* gA1 = Ah  + (size_t)ra1 * lda + scol;
    const u16* gL0 = Al  + (size_t)ra0 * lda + scol;
    const u16* gL1 = Al  + (size_t)ra1 * lda + scol;
    const u16* gB0 = BTh + (size_t)rb0 * ldb + scol;
    const u16* gB1 = BTh + (size_t)rb1 * ldb + scol;
    const u16* gC0 = BTl + (size_t)rb0 * ldb + scol;
    const u16* gC1 = BTl + (size_t)rb1 * ldb + scol;

    for (int k0 = 0; k0 < K; k0 += 32) {
        gld_lds16(gA0 + k0, dA0);
        gld_lds16(gA1 + k0, dA1);
        gld_lds16(gL0 + k0, dL0);
        gld_lds16(gL1 + k0, dL1);
        gld_lds16(gB0 + k0, dB0);
        gld_lds16(gB1 + k0, dB1);
        gld_lds16(gC0 + k0, dC0);
        gld_lds16(gC1 + k0, dC1);
        __syncthreads();
        bf16x8 ah[4], al[4], bh[4], bl[4];
#pragma unroll
        for (int t = 0; t < 4; ++t) {
            int arow = (wr*64 + t*16 + tl) * 32 + q*8;
            int brow = (wc*64 + t*16 + tl) * 32 + q*8;
            ah[t] = *(const bf16x8*)(&sAh[arow]);
            al[t] = *(const bf16x8*)(&sAl[arow]);
            bh[t] = *(const bf16x8*)(&sBh[brow]);
            bl[t] = *(const bf16x8*)(&sBl[brow]);
        }
#pragma unroll
        for (int ti = 0; ti < 4; ++ti)
#pragma unroll
            for (int tj = 0; tj < 4; ++tj) {
                acc[ti][tj] = __builtin_amdgcn_mfma_f32_16x16x32_bf16(ah[ti], bh[tj], acc[ti][tj], 0, 0, 0);
                acc[ti][tj] = __builtin_amdgcn_mfma_f32_16x16x32_bf16(al[ti], bh[tj], acc[ti][tj], 0, 0, 0);
                acc[ti][tj] = __builtin_amdgcn_mfma_f32_16x16x32_bf16(ah[ti], bl[tj], acc[ti][tj], 0, 0, 0);
            }
        __syncthreads();
    }
    // C/D layout: col = lane&15, row = (lane>>4)*4 + reg  [measured m89/m91]
#pragma unroll
    for (int ti = 0; ti < 4; ++ti) {
#pragma unroll
        for (int tj = 0; tj < 4; ++tj) {
            int gcol = bn + wc*64 + tj*16 + tl;
#pragma unroll
            for (int r = 0; r < 4; ++r) {
                int grow = bm + wr*64 + ti*16 + q*4 + r;
                if (grow >= M) continue;
                C[(size_t)grow * ldc + gcol] = acc[ti][tj][r];
            }
        }
    }
}

// ---------------------------------------------------------------------------
// Span layer-2 GEMM with FUSED layer-3 projection epilogue (deterministic).
// ---------------------------------------------------------------------------
__global__ __launch_bounds__(256) void k_span_l2(
    const u16* __restrict__ Ah, const u16* __restrict__ Al,
    const u16* __restrict__ BTh, const u16* __restrict__ BTl,
    const float* __restrict__ bs2, const float* __restrict__ Ws3,
    float* __restrict__ part, int M)
{
    int bx, by;
    xcd_map(blockIdx.x, 3, bx, by);
    if (by >= 127) return;
    __shared__ __align__(16) u16 sm[4 * 128 * 32];
    u16* sAh = sm;
    u16* sAl = sm + 4096;
    u16* sBh = sm + 8192;
    u16* sBl = sm + 12288;
    const int tid = threadIdx.x;
    const int bm = by * 128, bn = bx * 128;
    const int wave = tid >> 6, lane = tid & 63;
    const int wr = wave >> 1, wc = wave & 1;
    const int q = lane >> 4, tl = lane & 15;

    f32x4 zero = {0.f, 0.f, 0.f, 0.f};
    f32x4 acc[4][4];
#pragma unroll
    for (int i = 0; i < 4; ++i)
#pragma unroll
        for (int j = 0; j < 4; ++j) acc[i][j] = zero;

    const int srow = lane >> 2;
    const int scol = (lane & 3) * 8;
    int ra0 = bm + wave * 32 + srow;      if (ra0 >= M) ra0 = M - 1;
    int ra1 = bm + wave * 32 + 16 + srow; if (ra1 >= M) ra1 = M - 1;
    const int rb0 = bn + wave * 32 + srow;
    const int rb1 = bn + wave * 32 + 16 + srow;
    u16* dA0 = sAh + wave * 1024;  u16* dA1 = dA0 + 512;
    u16* dL0 = sAl + wave * 1024;  u16* dL1 = dL0 + 512;
    u16* dB0 = sBh + wave * 1024;  u16* dB1 = dB0 + 512;
    u16* dC0 = sBl + wave * 1024;  u16* dC1 = dC0 + 512;
    const u16* gA0 = Ah  + (size_t)ra0 * HID + scol;
    const u16* gA1 = Ah  + (size_t)ra1 * HID + scol;
    const u16* gL0 = Al  + (size_t)ra0 * HID + scol;
    const u16* gL1 = Al  + (size_t)ra1 * HID + scol;
    const u16* gB0 = BTh + (size_t)rb0 * HID + scol;
    const u16* gB1 = BTh + (size_t)rb1 * HID + scol;
    const u16* gC0 = BTl + (size_t)rb0 * HID + scol;
    const u16* gC1 = BTl + (size_t)rb1 * HID + scol;

    for (int k0 = 0; k0 < HID; k0 += 32) {
        gld_lds16(gA0 + k0, dA0);
        gld_lds16(gA1 + k0, dA1);
        gld_lds16(gL0 + k0, dL0);
        gld_lds16(gL1 + k0, dL1);
        gld_lds16(gB0 + k0, dB0);
        gld_lds16(gB1 + k0, dB1);
        gld_lds16(gC0 + k0, dC0);
        gld_lds16(gC1 + k0, dC1);
        __syncthreads();
        bf16x8 ah[4], al[4], bh[4], bl[4];
#pragma unroll
        for (int t = 0; t < 4; ++t) {
            int arow = (wr*64 + t*16 + tl) * 32 + q*8;
            int brow = (wc*64 + t*16 + tl) * 32 + q*8;
            ah[t] = *(const bf16x8*)(&sAh[arow]);
            al[t] = *(const bf16x8*)(&sAl[arow]);
            bh[t] = *(const bf16x8*)(&sBh[brow]);
            bl[t] = *(const bf16x8*)(&sBl[brow]);
        }
#pragma unroll
        for (int ti = 0; ti < 4; ++ti)
#pragma unroll
            for (int tj = 0; tj < 4; ++tj) {
                acc[ti][tj] = __builtin_amdgcn_mfma_f32_16x16x32_bf16(ah[ti], bh[tj], acc[ti][tj], 0, 0, 0);
                acc[ti][tj] = __builtin_amdgcn_mfma_f32_16x16x32_bf16(al[ti], bh[tj], acc[ti][tj], 0, 0, 0);
                acc[ti][tj] = __builtin_amdgcn_mfma_f32_16x16x32_bf16(ah[ti], bl[tj], acc[ti][tj], 0, 0, 0);
            }
        __syncthreads();
    }
    // fused L3: per row, partial dot over this wave's 64-col window
    const int slot = bx * 2 + wc;   // 0..15
#pragma unroll
    for (int ti = 0; ti < 4; ++ti) {
#pragma unroll
        for (int r = 0; r < 4; ++r) {
            int grow = bm + wr*64 + ti*16 + q*4 + r;
            float l0 = 0.f, l1 = 0.f, l2 = 0.f;
#pragma unroll
            for (int tj = 0; tj < 4; ++tj) {
                int gcol = bn + wc*64 + tj*16 + tl;
                float v = fmaxf(acc[ti][tj][r] + bs2[gcol], 0.f);
                const float* w3 = Ws3 + gcol * 3;
                l0 = fmaf(v, w3[0], l0);
                l1 = fmaf(v, w3[1], l1);
                l2 = fmaf(v, w3[2], l2);
            }
#pragma unroll
            for (int off = 8; off > 0; off >>= 1) {
                l0 += __shfl_down(l0, off, 16);
                l1 += __shfl_down(l1, off, 16);
                l2 += __shfl_down(l2, off, 16);
            }
            if (tl == 0 && grow < M) {
                float* dst = part + ((size_t)grow * 16 + slot) * 3;
                dst[0] = l0; dst[1] = l1; dst[2] = l2;
            }
        }
    }
}

// ---------------------------------------------------------------------------
// Gathered pair layer-1, split-K over p: TO2[p][r] = xh[toks[r + p*1024]]@B(p)
// 64x64 tiles, 512 blocks (p,by,bx), bf16 MFMA, per-lane row gather.
// ---------------------------------------------------------------------------
__global__ __launch_bounds__(256) void k_pairL1(
    const u16* __restrict__ xh, const u16* __restrict__ Wp1T4,
    float* __restrict__ TO2, const int* __restrict__ toks)
{
    __shared__ __align__(16) u16 sm[2 * 64 * 32];   // A 4KB | B 4KB
    u16* sA = sm;
    u16* sB = sm + 2048;
    const int tid = threadIdx.x;
    const int bid = blockIdx.x;
    const int p = bid >> 8;                  // 0/1
    const int bx = bid & 15, by = (bid >> 4) & 15;
    const int bm = by * 64, bn = bx * 64;
    const int wave = tid >> 6, lane = tid & 63;
    const int wr = wave >> 1, wc = wave & 1;
    const int q = lane >> 4, tl = lane & 15;
    const bool isO = bm >= 512;

    f32x4 zero = {0.f, 0.f, 0.f, 0.f};
    f32x4 acc[2][2];
#pragma unroll
    for (int i = 0; i < 2; ++i)
#pragma unroll
        for (int j = 0; j < 2; ++j) acc[i][j] = zero;

    const int srow = tid >> 2;
    const int scol = (tid & 3) * 8;
    u16* dA = sA + wave * 512;
    u16* dB = sB + wave * 512;

    int arow = toks[bm + srow + p * 1024];    // per-lane row gather
    const u16* gA = xh + (size_t)arow * DIM + scol;
    const u16* gB = Wp1T4 + ((size_t)((isO ? 2 : 0) + p) * 1024 + bn + srow) * DIM + scol;
    for (int k0 = 0; k0 < DIM; k0 += 32) {
        gld_lds16(gA + k0, dA);
        gld_lds16(gB + k0, dB);
        __syncthreads();
        bf16x8 af[2], bf[2];
#pragma unroll
        for (int t = 0; t < 2; ++t) {
            af[t] = *(const bf16x8*)(&sA[(wr*32 + t*16 + tl) * 32 + q*8]);
            bf[t] = *(const bf16x8*)(&sB[(wc*32 + t*16 + tl) * 32 + q*8]);
        }
#pragma unroll
        for (int ti = 0; ti < 2; ++ti)
#pragma unroll
            for (int tj = 0; tj < 2; ++tj)
                acc[ti][tj] = __builtin_amdgcn_mfma_f32_16x16x32_bf16(af[ti], bf[tj], acc[ti][tj], 0, 0, 0);
        __syncthreads();
    }
    float* dstb = TO2 + (size_t)p * 1024 * HID;
#pragma unroll
    for (int ti = 0; ti < 2; ++ti) {
#pragma unroll
        for (int tj = 0; tj < 2; ++tj) {
            int gcol = bn + wc*32 + tj*16 + tl;
#pragma unroll
            for (int r = 0; r < 4; ++r) {
                int grow = bm + wr*32 + ti*16 + q*4 + r;
                dstb[(size_t)grow * HID + gcol] = acc[ti][tj][r];
            }
        }
    }
}

// h1s = relu(XALL[b,start,0:1024] + XALL[b,end-1,1024:2048] + wtabS[w-1]) -> split bf16
__global__ __launch_bounds__(256) void k_build_h1s(
    const float* __restrict__ XALL, const float* __restrict__ wtabS,
    u16* __restrict__ h1h, u16* __restrict__ h1l)
{
    int r = blockIdx.x;                 // 0..16159
    int b = r / NSPAN, s = r - b * NSPAN;
    int st, en, w; span_decode(s, st, en, w);
    const float4* xs = (const float4*)(XALL + (size_t)(b*SEQ + st) * 2048);
    const float4* xe = (const float4*)(XALL + (size_t)(b*SEQ + en - 1) * 2048 + 1024);
    const float4* wt = (const float4*)(wtabS + (size_t)(w-1) * HID);
    int t = threadIdx.x;
    float4 a = xs[t], bz = xe[t], c = wt[t];
    float v0 = fmaxf(a.x + bz.x + c.x, 0.f);
    float v1 = fmaxf(a.y + bz.y + c.y, 0.f);
    float v2 = fmaxf(a.z + bz.z + c.z, 0.f);
    float v3 = fmaxf(a.w + bz.w + c.w, 0.f);
    u16 h0,l0,h1,l1,h2,l2,h3,l3;
    splitbf(v0,h0,l0); splitbf(v1,h1,l1); splitbf(v2,h2,l2); splitbf(v3,h3,l3);
    size_t base = (size_t)r * HID + t * 4;
    *(uint2*)(h1h + base) = make_uint2((u32)h0 | ((u32)h1 << 16), (u32)h2 | ((u32)h3 << 16));
    *(uint2*)(h1l + base) = make_uint2((u32)l0 | ((u32)l1 << 16), (u32)l2 | ((u32)l3 << 16));
}

// ---------------------------------------------------------------------------
// k_topk (fused with span reduce+softmax): reduces partS (fixed order, same
// bit pattern as the old k_span_red), writes out[] (twin blocks write
// identical data - benign), packs keys, bitonic-sorts 2048 u64 keys,
// emits top-64 indices + token rowmaps. Deterministic, jax tie-break.
// ---------------------------------------------------------------------------
__global__ __launch_bounds__(256) void k_topk(
    const float* __restrict__ partS, const float* __restrict__ bs3,
    float* __restrict__ out, int* __restrict__ t_idx, int* __restrict__ o_idx,
    int* __restrict__ toks)
{
    int b = blockIdx.x >> 1;
    int head = 1 + (blockIdx.x & 1);
    int* outp = (head == 1 ? t_idx : o_idx) + b * NZ;
    __shared__ u64 keys[2048];
    int tid = threadIdx.x;
#pragma unroll
    for (int ii = 0; ii < 8; ++ii) {
        int s = tid + ii * 256;          // 0..2047
        u32 fb = 0;
        if (s < NSPAN) {
            const float* p = partS + (size_t)(b * NSPAN + s) * 48;
            float s0 = bs3[0], s1 = bs3[1], s2 = bs3[2];
#pragma unroll
            for (int t = 0; t < 16; ++t) {
                s0 += p[t*3]; s1 += p[t*3+1]; s2 += p[t*3+2];
            }
            float m = fmaxf(s0, fmaxf(s1, s2));
            float e0 = expf(s0 - m), e1 = expf(s1 - m), e2 = expf(s2 - m);
            float inv = 1.f / (e0 + e1 + e2);
            float p0 = e0 * inv, p1 = e1 * inv, p2 = e2 * inv;
            float* o = out + (size_t)(b * NSPAN + s) * 3;
            o[0] = p0; o[1] = p1; o[2] = p2;
            union { float f; u32 u; } x;
            x.f = (head == 1) ? p1 : p2;
            fb = x.u;
        }
        keys[s] = ((u64)fb << 32) | (u64)(0xFFFFFFFFu - (u32)s);
    }
    __syncthreads();
    // canonical bitonic sort, DESCENDING overall
    for (int k = 2; k <= 2048; k <<= 1) {
        for (int j = k >> 1; j > 0; j >>= 1) {
#pragma unroll
            for (int ii = 0; ii < 8; ++ii) {
                int i = tid + ii * 256;
                int ixj = i ^ j;
                if (ixj > i) {
                    u64 a = keys[i], c = keys[ixj];
                    bool desc = (i & k) == 0;
                    bool wrong = desc ? (a < c) : (a > c);
                    if (wrong) { keys[i] = c; keys[ixj] = a; }
                }
            }
            __syncthreads();
        }
    }
    if (tid < NZ) {
        u64 key = keys[tid];
        int fi = (int)(0xFFFFFFFFu - (u32)(key & 0xFFFFFFFFu));
        if (fi < 0 || fi >= NSPAN) fi = 0;   // paranoia
        outp[tid] = fi;
        int st, en, w; span_decode(fi, st, en, w);
        int base = (head == 1 ? 0 : 512) + b * NZ + tid;
        toks[base] = b * SEQ + st;
        toks[1024 + base] = b * SEQ + en - 1;
    }
}

// h1_pair[row] = relu(TO2[0][.]+TO2[1][.] (T) + (O) + wtabPt + wtabPo + dtab) -> bf16
__global__ __launch_bounds__(256) void k_build_h1p(
    const float* __restrict__ TO2, const int* __restrict__ t_idx, const int* __restrict__ o_idx,
    const float* __restrict__ wtabPt, const float* __restrict__ wtabPo,
    const float* __restrict__ dtab, u16* __restrict__ h1p)
{
    int row = blockIdx.x;               // b*4096 + i*64 + j
    int b = row >> 12, i = (row >> 6) & 63, j = row & 63;
    int ts = t_idx[b*64 + i], os = o_idx[b*64 + j];
    int ta, tb, wt, oc, od, wo;
    span_decode(ts, ta, tb, wt);
    span_decode(os, oc, od, wo);
    int d1 = tb - oc; d1 = d1 < 0 ? -d1 : d1;
    int d2 = ta - od; d2 = d2 < 0 ? -d2 : d2;
    int dist = d1 < d2 ? d1 : d2;
    int db = dbucket(dist);
    const size_t PS = (size_t)1024 * HID;
    const float4* T0 = (const float4*)(TO2 + (size_t)(b*64 + i) * HID);
    const float4* T1 = (const float4*)(TO2 + PS + (size_t)(b*64 + i) * HID);
    const float4* O0 = (const float4*)(TO2 + (size_t)(512 + b*64 + j) * HID);
    const float4* O1 = (const float4*)(TO2 + PS + (size_t)(512 + b*64 + j) * HID);
    const float4* P4 = (const float4*)(wtabPt + (size_t)(wt-1) * HID);
    const float4* Q4 = (const float4*)(wtabPo + (size_t)(wo-1) * HID);
    const float4* D4 = (const float4*)(dtab + (size_t)db * HID);
    int t = threadIdx.x;
    float4 a0 = T0[t], a1 = T1[t], c0 = O0[t], c1 = O1[t];
    float4 p = P4[t], q = Q4[t], d = D4[t];
    float vx = fmaxf(a0.x + a1.x + c0.x + c1.x + p.x + q.x + d.x, 0.f);
    float vy = fmaxf(a0.y + a1.y + c0.y + c1.y + p.y + q.y + d.y, 0.f);
    float vz = fmaxf(a0.z + a1.z + c0.z + c1.z + p.z + q.z + d.z, 0.f);
    float vw = fmaxf(a0.w + a1.w + c0.w + c1.w + p.w + q.w + d.w, 0.f);
    u32 p0 = (u32)f2bf(vx) | ((u32)f2bf(vy) << 16);
    u32 p1 = (u32)f2bf(vz) | ((u32)f2bf(vw) << 16);
    *(uint2*)(h1p + (size_t)row * HID + t * 4) = make_uint2(p0, p1);
}

// pair layer2 with FUSED layer-3 projection epilogue (h2p never materialized).
__global__ __launch_bounds__(256) void k_pair_l2(
    const u16* __restrict__ Abf, const u16* __restrict__ BT,
    const float* __restrict__ bp2, const float* __restrict__ Wp3,
    float* __restrict__ part)
{
    int bx, by;
    xcd_map(blockIdx.x, 3, bx, by);
    __shared__ __align__(16) u16 sm[2 * 128 * 32];     // 16 KiB
    u16* As = sm;
    u16* Bs = sm + 4096;
    const int tid = threadIdx.x;
    const int bm = by * 128, bn = bx * 128;
    const int wave = tid >> 6, lane = tid & 63;
    const int wr = wave >> 1, wc = wave & 1;
    const int q = lane >> 4, tl = lane & 15;

    f32x4 zero = {0.f, 0.f, 0.f, 0.f};
    f32x4 acc[4][4];
#pragma unroll
    for (int i = 0; i < 4; ++i)
#pragma unroll
        for (int j = 0; j < 4; ++j) acc[i][j] = zero;

    const int srow = lane >> 2;
    const int scol = (lane & 3) * 8;
    const u16* gA0 = Abf + (size_t)(bm + wave*32 + srow) * 1024 + scol;
    const u16* gA1 = Abf + (size_t)(bm + wave*32 + 16 + srow) * 1024 + scol;
    const u16* gB0 = BT  + (size_t)(bn + wave*32 + srow) * 1024 + scol;
    const u16* gB1 = BT  + (size_t)(bn + wave*32 + 16 + srow) * 1024 + scol;
    u16* dA0 = As + wave * 1024;  u16* dA1 = dA0 + 512;
    u16* dB0 = Bs + wave * 1024;  u16* dB1 = dB0 + 512;

    for (int k0 = 0; k0 < 1024; k0 += 32) {
        gld_lds16(gA0 + k0, dA0);
        gld_lds16(gA1 + k0, dA1);
        gld_lds16(gB0 + k0, dB0);
        gld_lds16(gB1 + k0, dB1);
        __syncthreads();
        bf16x8 af[4], bf[4];
#pragma unroll
        for (int t = 0; t < 4; ++t) {
            af[t] = *(const bf16x8*)(&As[(wr*64 + t*16 + tl) * 32 + q*8]);
            bf[t] = *(const bf16x8*)(&Bs[(wc*64 + t*16 + tl) * 32 + q*8]);
        }
#pragma unroll
        for (int ti = 0; ti < 4; ++ti)
#pragma unroll
            for (int tj = 0; tj < 4; ++tj)
                acc[ti][tj] = __builtin_amdgcn_mfma_f32_16x16x32_bf16(af[ti], bf[tj], acc[ti][tj], 0, 0, 0);
        __syncthreads();
    }
    // fused L3 projection
    const int slot = bx * 2 + wc;   // 0..15
#pragma unroll
    for (int ti = 0; ti < 4; ++ti) {
#pragma unroll
        for (int r = 0; r < 4; ++r) {
            int grow = bm + wr*64 + ti*16 + q*4 + r;
            float l0 = 0.f, l1 = 0.f, l2 = 0.f, l3 = 0.f;
#pragma unroll
            for (int tj = 0; tj < 4; ++tj) {
                int gcol = bn + wc*64 + tj*16 + tl;
                float v = fmaxf(acc[ti][tj][r] + bp2[gcol], 0.f);
                const float4 w = *(const float4*)(Wp3 + gcol * 4);
                l0 = fmaf(v, w.x, l0); l1 = fmaf(v, w.y, l1);
                l2 = fmaf(v, w.z, l2); l3 = fmaf(v, w.w, l3);
            }
#pragma unroll
            for (int off = 8; off > 0; off >>= 1) {
                l0 += __shfl_down(l0, off, 16);
                l1 += __shfl_down(l1, off, 16);
                l2 += __shfl_down(l2, off, 16);
                l3 += __shfl_down(l3, off, 16);
            }
            if (tl == 0) {
                float* dst = part + ((size_t)grow * 16 + slot) * 4;
                dst[0] = l0; dst[1] = l1; dst[2] = l2; dst[3] = l3;
            }
        }
    }
}

// reduce 16 slots (fixed order) + softmax -> out[48480 + r*4 + c]
__global__ __launch_bounds__(256) void k_pair_red(
    const float* __restrict__ part, const float* __restrict__ bp3,
    float* __restrict__ out)
{
    int r = blockIdx.x * 256 + threadIdx.x;   // 32768 = 128*256 exact
    const float4* p = (const float4*)(part + (size_t)r * 64);
    float s0 = bp3[0], s1 = bp3[1], s2 = bp3[2], s3 = bp3[3];
#pragma unroll
    for (int t = 0; t < 16; ++t) {
        float4 v = p[t];
        s0 += v.x; s1 += v.y; s2 += v.z; s3 += v.w;
    }
    float m = fmaxf(fmaxf(s0, s1), fmaxf(s2, s3));
    float e0 = expf(s0 - m), e1 = expf(s1 - m), e2 = expf(s2 - m), e3 = expf(s3 - m);
    float inv = 1.f / (e0 + e1 + e2 + e3);
    float* o = out + (size_t)r * 4;
    o[0] = e0 * inv; o[1] = e1 * inv; o[2] = e2 * inv; o[3] = e3 * inv;
}

extern "C" void kernel_launch(void* const* d_in, const int* in_sizes, int n_in,
                              void* d_out, int out_size, void* d_ws, size_t ws_size,
                              hipStream_t stream)
{
    const float* x    = (const float*)d_in[0];
    const float* wemb = (const float*)d_in[1];
    const float* demb = (const float*)d_in[2];
    const float* Ws1  = (const float*)d_in[3];
    const float* bs1  = (const float*)d_in[4];
    const float* Ws2  = (const float*)d_in[5];
    const float* bs2  = (const float*)d_in[6];
    const float* Ws3  = (const float*)d_in[7];
    const float* bs3  = (const float*)d_in[8];
    const float* Wp1  = (const float*)d_in[9];
    const float* bp1  = (const float*)d_in[10];
    const float* Wp2  = (const float*)d_in[11];
    const float* bp2  = (const float*)d_in[12];
    const float* Wp3  = (const float*)d_in[13];
    const float* bp3  = (const float*)d_in[14];
    float* out = (float*)d_out;
    char* ws = (char*)d_ws;

    // ---- workspace arena, lifetime-aliased (~162 MB) ----
    // R1 (64 MiB): h1h+h1l (dead after k_span_l2)
    // R2 (64 MiB): [XALL | xl | W1Th | W1Tl] (dead after build_h1s) -> h1p
    // xh PERSISTENT (read by k_pairL1 late).
    const size_t RSZ = (size_t)32768 * HID * 2;   // 64 MiB
    size_t off = 0;
    auto alloc = [&](size_t bytes) -> void* {
        void* p = ws + off;
        off += (bytes + 255) & ~(size_t)255;
        return p;
    };
    char* R1 = (char*)alloc(RSZ);
    char* R2 = (char*)alloc(RSZ);
    u16*   h1h  = (u16*)R1;                              // 33.1 MB
    u16*   h1l  = (u16*)(R1 + (size_t)16160 * HID * 2);  // 33.1 MB
    float* XALL = (float*)R2;                            // 16 MiB
    u16*   xl   = (u16*)(R2 + (16u << 20));              // 3 MB
    u16*   W1Th = (u16*)(R2 + (19u << 20));              // 3 MB
    u16*   W1Tl = (u16*)(R2 + (22u << 20));              // 3 MB
    u16*   h1p  = (u16*)R2;                              // 64 MiB (after the above dead)
    u16*   xh     = (u16*)alloc((size_t)2048 * DIM * 2);     // 3 MB PERSISTENT
    float* TO2    = (float*)alloc((size_t)2 * 1024 * HID * 4);   // 8 MB (split-K partials)
    float* partS  = (float*)alloc((size_t)16160 * 16 * 3 * 4);   // 3.1 MB
    float* partP  = (float*)alloc((size_t)32768 * 16 * 4 * 4);   // 8.4 MB
    u16*   W2Th   = (u16*)alloc((size_t)1024 * 1024 * 2);
    u16*   W2Tl   = (u16*)alloc((size_t)1024 * 1024 * 2);
    u16*   Wp2T   = (u16*)alloc((size_t)1024 * 1024 * 2);
    u16*   Wp1T4  = (u16*)alloc((size_t)4 * 1024 * 768 * 2);
    float* wtabS  = (float*)alloc(8 * HID * 4);
    float* wtabPt = (float*)alloc(8 * HID * 4);
    float* wtabPo = (float*)alloc(8 * HID * 4);
    float* dtab   = (float*)alloc(14 * HID * 4);
    int*   t_idx  = (int*)alloc(BATCH * NZ * 4);
    int*   o_idx  = (int*)alloc(BATCH * NZ * 4);
    int*   toks   = (int*)alloc(2048 * 4);
    (void)ws_size; (void)in_sizes; (void)n_in; (void)out_size;

    // prep (fused): x split + tables + all weight transposes
    k_prep<<<12952, 256, 0, stream>>>(x, xh, xl, wemb, demb, bs1, bp1,
                                      wtabS, wtabPt, wtabPo, dtab,
                                      Ws1, W1Th, W1Tl, Ws2, W2Th, W2Tl,
                                      Wp2, Wp2T, Wp1, Wp1T4);

    // layer-1 factorization: XALL = x2d @ [Ws1_top | Ws1_mid] (3-pass split-bf16)
    k_gemm3bf<<<256, 256, 0, stream>>>(xh, xl, 768, W1Th, W1Tl, 768,
                                       XALL, 2048, 2048, 768, 16, 4);
    k_build_h1s<<<16160, 256, 0, stream>>>(XALL, wtabS, h1h, h1l);
    // span layer2 + FUSED layer3 partials (3-pass split-bf16, deterministic)
    k_span_l2<<<1024, 256, 0, stream>>>(h1h, h1l, W2Th, W2Tl, bs2, Ws3, partS, 16160);
    // fused reduce+softmax+topk+toks (twin blocks write identical out rows)
    k_topk<<<16, 256, 0, stream>>>(partS, bs3, out, t_idx, o_idx, toks);
    // gathered pair layer-1: split-K bf16 MFMA (512 blocks, 2/CU)
    k_pairL1<<<512, 256, 0, stream>>>(xh, Wp1T4, TO2, toks);
    k_build_h1p<<<32768, 256, 0, stream>>>(TO2, t_idx, o_idx, wtabPt, wtabPo, dtab, h1p);
    // pair layer2 + FUSED layer3 partials (single-pass bf16)
    k_pair_l2<<<2048, 256, 0, stream>>>(h1p, Wp2T, bp2, Wp3, partP);
    k_pair_red<<<128, 256, 0, stream>>>(partP, bp3, out + 48480);
}